// Round 15
// baseline (486.281 us; speedup 1.0000x reference)
//
#include <hip/hip_runtime.h>
#include <hip/hip_bf16.h>

// ---------------------------------------------------------------------------
// mv3Dunet_down_text_cmsa forward. Round 15: cross-attention ported to MFMA
// (scores GEMM + dual-softmax epilogue -> PV GEMMs -> fused projection GEMM
// with residuals), replacing the 90us fp32 attrow pair. CMSA/conv unchanged.
// ---------------------------------------------------------------------------

using bf16x8 = __attribute__((ext_vector_type(8))) short;
using f32x4  = __attribute__((ext_vector_type(4))) float;

typedef const __attribute__((address_space(1))) void gas_void;
typedef __attribute__((address_space(3))) void las_void;

__device__ __forceinline__ unsigned short f2bf(float f) {
    unsigned int u = __float_as_uint(f);
    u += 0x7FFFu + ((u >> 16) & 1u);
    return (unsigned short)(u >> 16);
}

// ---------------- zero helper ----------------
__global__ void k_zero4(float4* __restrict__ p, int n4) {
    int i = blockIdx.x * 256 + threadIdx.x;
    if (i < n4) p[i] = (float4){0.f, 0.f, 0.f, 0.f};
}

// ---------------- X -> chunk-major bf16: xt[b][g][208][72] ----------------
__global__ void k_xt_c(const float* __restrict__ x, unsigned short* __restrict__ xt,
                       int IC, int G) {
    int b = blockIdx.y;
    int tot = G * 208 * 36;
    int idx = blockIdx.x * 256 + threadIdx.x;
    if (idx >= tot) return;
    int g = idx / (208 * 36); int r = idx - g * 208 * 36;
    int s = r / 36, cp = r - s * 36;
    int cc = cp * 2;
    int ic = g * 64 + cc;
    unsigned int lo = 0, hi = 0;
    if (s < 196 && cc < 64 && ic < IC)         lo = f2bf(x[((size_t)b * IC + ic) * 196 + s]);
    if (s < 196 && cc + 1 < 64 && ic + 1 < IC) hi = f2bf(x[((size_t)b * IC + ic + 1) * 196 + s]);
    ((unsigned int*)xt)[(size_t)b * tot + idx] = lo | (hi << 16);
}

// ---------------- weight pack: w[oc][ic][27] f32 -> wp[t][oc][ic] bf16 ------
__global__ void k_wpack(const float* __restrict__ w, unsigned short* __restrict__ wp,
                        int IC) {
    int nc = IC >> 3;
    int idx = blockIdx.x * 256 + threadIdx.x;
    if (idx >= 27 * 128 * nc) return;
    int c = idx % nc; int r = idx / nc; int oc = r & 127; int t = r >> 7;
    const float* ws = w + ((size_t)oc * IC + c * 8) * 27 + t;
    unsigned int o0 = f2bf(ws[0])   | ((unsigned int)f2bf(ws[27])  << 16);
    unsigned int o1 = f2bf(ws[54])  | ((unsigned int)f2bf(ws[81])  << 16);
    unsigned int o2 = f2bf(ws[108]) | ((unsigned int)f2bf(ws[135]) << 16);
    unsigned int o3 = f2bf(ws[162]) | ((unsigned int)f2bf(ws[189]) << 16);
    uint4 v; v.x = o0; v.y = o1; v.z = o2; v.w = o3;
    ((uint4*)wp)[idx] = v;
}

// ---------------- pack 173x173 f32 -> [176][192] bf16 zero-padded -----------
__global__ void k_w173(const float* __restrict__ w, unsigned short* __restrict__ wb) {
    int idx = blockIdx.x * 256 + threadIdx.x;
    if (idx >= 176 * 192) return;
    int oc = idx / 192, c = idx - oc * 192;
    wb[idx] = (oc < 173 && c < 173) ? f2bf(w[(size_t)oc * 173 + c]) : (unsigned short)0;
}

// ---------------- pack Wcat[208][448]: [wA | pad | wB | pad] ----------------
__global__ void k_wcat(const float* __restrict__ wA, const float* __restrict__ wB,
                       unsigned short* __restrict__ outw) {
    int idx = blockIdx.x * 256 + threadIdx.x;
    if (idx >= 208 * 448) return;
    int n = idx / 448, k = idx - n * 448;
    unsigned short v = 0;
    if (n < 196) {
        if (k < 196) v = f2bf(wA[(size_t)n * 196 + k]);
        else if (k >= 224 && k < 420) v = f2bf(wB[(size_t)n * 196 + (k - 224)]);
    }
    outw[idx] = v;
}

// ---------------- MFMA conv (validated) ----------------
template <int IC, int G, int NT, int NH>
__global__ __launch_bounds__(256, 3) void k_convchunk4(
    const unsigned short* __restrict__ xt, const unsigned short* __restrict__ wp,
    float* __restrict__ part) {
    __shared__ unsigned short xs[208 * 72];
    __shared__ char bbuf[2][NT * 2048];
    const int tid = threadIdx.x;
    const int bx = blockIdx.x, b = blockIdx.y;
    const int mh = bx & 1;
    const int nh = (bx >> 1) % NH;
    const int g  = (bx >> 1) / NH;
    const int w = tid >> 6, l = tid & 63;

    {
        const bf16x8* s8 = (const bf16x8*)(xt + ((size_t)b * G + g) * (208 * 72));
        bf16x8* d8 = (bf16x8*)xs;
        for (int c = tid; c < 208 * 72 / 8; c += 256) d8[c] = s8[c];
    }

    const char* wslice = (const char*)wp +
                         ((size_t)(nh * NT * 16) * IC + (size_t)g * 64) * 2;
    auto stageB = [&](int t) {
        char* dst = &bbuf[t & 1][w * (NT * 512)];
        const char* wt_ = wslice + (size_t)t * 128 * IC * 2;
#pragma unroll
        for (int c = 0; c < NT / 2; ++c) {
            int q = w * (NT * 512) + c * 1024 + l * 16;
            int row = q >> 7, col = q & 127;
            int scol = col ^ ((row & 7) << 4);
            gas_void* src = (gas_void*)(wt_ + (size_t)row * IC * 2 + scol);
            __builtin_amdgcn_global_load_lds(src, (las_void*)(dst + c * 1024),
                                             16, 0, 0);
        }
    };

    const int lane = tid & 63;
    const int a = lane & 15, kg = lane >> 4;

    int md[2], mhh[2], mw[2];
#pragma unroll
    for (int i = 0; i < 2; ++i) {
        int m = (mh * 8 + (tid >> 6) * 2 + i) * 16 + a;
        md[i] = m / 49; int rr = m - md[i] * 49;
        mhh[i] = rr / 7; mw[i] = rr - mhh[i] * 7;
    }

    f32x4 acc[2][NT];
#pragma unroll
    for (int i = 0; i < 2; ++i)
#pragma unroll
        for (int nt = 0; nt < NT; ++nt) acc[i][nt] = (f32x4){0.f, 0.f, 0.f, 0.f};

    const bf16x8 zv = {0, 0, 0, 0, 0, 0, 0, 0};

    stageB(0);
    __syncthreads();

    for (int t = 0; t < 27; ++t) {
        if (t < 26) stageB(t + 1);
        const int kd = t / 9, kh = (t / 3) % 3, kw = t % 3;
        int rsrc[2]; bool ok[2];
#pragma unroll
        for (int i = 0; i < 2; ++i) {
            int d2 = md[i] + kd - 1, h2 = mhh[i] + kh - 1, w2 = mw[i] + kw - 1;
            ok[i] = ((unsigned)d2 < 4u) & ((unsigned)h2 < 7u) & ((unsigned)w2 < 7u);
            rsrc[i] = ok[i] ? (d2 * 49 + h2 * 7 + w2) : 0;
        }
        bf16x8 A[2][2];
#pragma unroll
        for (int kk = 0; kk < 2; ++kk)
#pragma unroll
            for (int i = 0; i < 2; ++i) {
                bf16x8 v = *(const bf16x8*)(xs + rsrc[i] * 72 + kk * 32 + kg * 8);
                A[kk][i] = ok[i] ? v : zv;
            }
        const char* bb = &bbuf[t & 1][0];
#pragma unroll
        for (int kk = 0; kk < 2; ++kk)
#pragma unroll
            for (int nt = 0; nt < NT; ++nt) {
                int row = nt * 16 + a;
                int cb = (kk * 64 + kg * 16) ^ ((row & 7) << 4);
                bf16x8 B = *(const bf16x8*)(bb + row * 128 + cb);
#pragma unroll
                for (int i = 0; i < 2; ++i)
                    acc[i][nt] = __builtin_amdgcn_mfma_f32_16x16x32_bf16(
                        A[kk][i], B, acc[i][nt], 0, 0, 0);
            }
        __syncthreads();
    }

    float* dst = part + ((size_t)g * 32 + b) * (128 * 196);
#pragma unroll
    for (int i = 0; i < 2; ++i) {
        int m0 = (mh * 8 + (tid >> 6) * 2 + i) * 16 + kg * 4;
        if (m0 < 196) {
#pragma unroll
            for (int nt = 0; nt < NT; ++nt) {
                int oc = nh * NT * 16 + nt * 16 + a;
                *(f32x4*)(dst + (size_t)oc * 196 + m0) = acc[i][nt];
            }
        }
    }
}

template <int G>
__global__ void k_reduceG(const float* __restrict__ part, float* __restrict__ y, int n) {
    int i = blockIdx.x * blockDim.x + threadIdx.x;
    if (i < n) {
        float s = 0.f;
#pragma unroll
        for (int g = 0; g < G; ++g) s += part[(size_t)g * n + i];
        y[i] = s;
    }
}

// ---------------- CMSA batched MFMA GEMM (validated r14) ----------------
template <int MROWS, int MTILES, int KP, int KK, int EPI>
__global__ __launch_bounds__(256, 2) void k_bgemm(
    const unsigned short* __restrict__ Ab, size_t ABS,
    const unsigned short* __restrict__ Bb, size_t BBS,
    const float* __restrict__ bias,
    unsigned short* __restrict__ p0, unsigned short* __restrict__ p1,
    const float* __restrict__ resid, float* __restrict__ outf) {
    constexpr int KPS = KP + 8;
    __shared__ unsigned short xsA[64 * KPS];
    __shared__ char bbuf[2][208 * 64];
    const int tid = threadIdx.x, bx = blockIdx.x, b = blockIdx.y;
    const int wv = tid >> 6, lane = tid & 63, a = lane & 15, kg = lane >> 4;

    const unsigned short* Abase = Ab + (size_t)b * ABS;
    {
        const int rowu = KP / 2;
        for (int i = tid; i < 64 * rowu; i += 256) {
            int r = i / rowu, cu = i - r * rowu;
            int gr = bx * 64 + r; if (gr > MROWS - 1) gr = MROWS - 1;
            unsigned int v = ((const unsigned int*)(Abase + (size_t)gr * KP))[cu];
            *(unsigned int*)&xsA[r * KPS + cu * 2] = v;
        }
    }
    const char* Bbase = (const char*)(Bb + (size_t)b * BBS);
    auto stageB = [&](int kk) {
        char* dst0 = &bbuf[kk & 1][0];
#pragma unroll
        for (int c = 0; c < 4; ++c) {
            int idx = tid + c * 256;
            if (idx < 832) {
                int row = idx >> 2, u = idx & 3;
                gas_void* src = (gas_void*)(Bbase + (size_t)row * (KP * 2) +
                                            kk * 64 + u * 16);
                __builtin_amdgcn_global_load_lds(src, (las_void*)(dst0 + (size_t)idx * 16),
                                                 16, 0, 0);
            }
        }
    };

    int mt = bx * 4 + wv; if (mt > MTILES - 1) mt = MTILES - 1;
    const int arow = mt * 16 + a - bx * 64;

    f32x4 acc[13];
#pragma unroll
    for (int nt = 0; nt < 13; ++nt) acc[nt] = (f32x4){0.f, 0.f, 0.f, 0.f};

    stageB(0);
    __syncthreads();
    for (int kk = 0; kk < KK; ++kk) {
        if (kk + 1 < KK) stageB(kk + 1);
        bf16x8 Af = *(const bf16x8*)&xsA[arow * KPS + kk * 32 + kg * 8];
        const char* bb = &bbuf[kk & 1][0];
#pragma unroll
        for (int nt = 0; nt < 13; ++nt) {
            int brow = nt * 16 + a;
            bf16x8 Bf = *(const bf16x8*)(bb + brow * 64 + kg * 16);
            acc[nt] = __builtin_amdgcn_mfma_f32_16x16x32_bf16(Af, Bf, acc[nt], 0, 0, 0);
        }
        __syncthreads();
    }

    const int mbase = mt * 16 + kg * 4;
    if (EPI == 0) {
#pragma unroll
        for (int nt = 0; nt < 13; ++nt) {
            int col = nt * 16 + a;
            if (col < 196) {
#pragma unroll
                for (int j = 0; j < 4; ++j) {
                    int row = mbase + j;
                    if (row < 173) {
                        unsigned short h = f2bf(fmaxf(acc[nt][j] + bias[row], 0.f));
                        p0[((size_t)b * 176 + row) * 224 + col] = h;
                        p1[((size_t)b * 208 + col) * 192 + row] = h;
                    }
                }
            }
        }
    } else if (EPI == 1) {
#pragma unroll
        for (int j = 0; j < 4; ++j) {
            int row = mbase + j;
            float m = -3.4e38f;
#pragma unroll
            for (int nt = 0; nt < 13; ++nt) {
                int col = nt * 16 + a;
                float s = (col < 196) ? acc[nt][j] : -3.4e38f;
                m = fmaxf(m, s);
            }
            for (int msk = 1; msk < 16; msk <<= 1) m = fmaxf(m, __shfl_xor(m, msk));
            float e[13]; float sum = 0.f;
#pragma unroll
            for (int nt = 0; nt < 13; ++nt) {
                int col = nt * 16 + a;
                float v = (col < 196) ? expf(acc[nt][j] - m) : 0.f;
                e[nt] = v; sum += v;
            }
            for (int msk = 1; msk < 16; msk <<= 1) sum += __shfl_xor(sum, msk);
            float inv = 1.f / sum;
            if (row < 196) {
#pragma unroll
                for (int nt = 0; nt < 13; ++nt) {
                    int col = nt * 16 + a;
                    p0[((size_t)b * 208 + row) * 224 + col] = f2bf(e[nt] * inv);
                }
            }
        }
    } else if (EPI == 2) {
#pragma unroll
        for (int nt = 0; nt < 13; ++nt) {
            int col = nt * 16 + a;
#pragma unroll
            for (int j = 0; j < 4; ++j) {
                int row = mbase + j;
                if (row < 173)
                    p0[((size_t)b * 208 + col) * 192 + row] = f2bf(acc[nt][j]);
            }
        }
    } else {
#pragma unroll
        for (int nt = 0; nt < 13; ++nt) {
            int col = nt * 16 + a;
            if (col < 196) {
#pragma unroll
                for (int j = 0; j < 4; ++j) {
                    int row = mbase + j;
                    if (row < 173) {
                        size_t rr = ((size_t)b * 173 + row) * 196 + col;
                        outf[rr] = fmaxf(acc[nt][j] + bias[row], 0.f) + resid[rr];
                    }
                }
            }
        }
    }
}

// ---------------- attention batched MFMA GEMM ----------------
// EPI 5: dual-segment softmax (cols 0..127 / 128..172) -> P bf16 [rows][192]
// EPI 6: plain bf16 write, col<196, to p0 + row*p0rs
// EPI 4: + biasA[col]+biasB[col]+lnres+res2 -> feat fp32 + ftb bf16
template <int MROWS, int MTILES, int KPA, int KPB, int AOFF, int KK, int EPI, int STAGEA>
__global__ __launch_bounds__(256, 2) void k_agemm(
    const unsigned short* __restrict__ Ab, size_t ABS,
    const unsigned short* __restrict__ Bb, size_t BBS,
    const float* __restrict__ biasA, const float* __restrict__ biasB,
    const float* __restrict__ lnres, const float* __restrict__ res2,
    unsigned short* __restrict__ p0, size_t p0rs, size_t p0bs,
    float* __restrict__ feat, unsigned short* __restrict__ ftb, int cbase) {
    constexpr int KPS = KPA + 8;
    __shared__ unsigned short xsA[STAGEA ? 64 * KPS : 64];
    __shared__ char bbuf[2][208 * 64];
    const int tid = threadIdx.x, bx = blockIdx.x, b = blockIdx.y;
    const int wv = tid >> 6, lane = tid & 63, a = lane & 15, kg = lane >> 4;

    const unsigned short* Abase = Ab + (size_t)b * ABS;
    if (STAGEA) {
        const int rowu = KPA / 2;
        for (int i = tid; i < 64 * rowu; i += 256) {
            int r = i / rowu, cu = i - r * rowu;
            int gr = bx * 64 + r; if (gr > MROWS - 1) gr = MROWS - 1;
            unsigned int v = ((const unsigned int*)(Abase + (size_t)gr * KPA))[cu];
            *(unsigned int*)&xsA[r * KPS + cu * 2] = v;
        }
    }
    const char* Bbase = (const char*)(Bb + (size_t)b * BBS);
    auto stageB = [&](int kk) {
        char* dst0 = &bbuf[kk & 1][0];
#pragma unroll
        for (int c = 0; c < 4; ++c) {
            int idx = tid + c * 256;
            if (idx < 832) {
                int row = idx >> 2, u = idx & 3;
                gas_void* src = (gas_void*)(Bbase + (size_t)row * (KPB * 2) +
                                            kk * 64 + u * 16);
                __builtin_amdgcn_global_load_lds(src, (las_void*)(dst0 + (size_t)idx * 16),
                                                 16, 0, 0);
            }
        }
    };

    int mt = bx * 4 + wv; if (mt > MTILES - 1) mt = MTILES - 1;

    f32x4 acc[13];
#pragma unroll
    for (int nt = 0; nt < 13; ++nt) acc[nt] = (f32x4){0.f, 0.f, 0.f, 0.f};

    stageB(0);
    __syncthreads();
    for (int kk = 0; kk < KK; ++kk) {
        if (kk + 1 < KK) stageB(kk + 1);
        bf16x8 Af;
        if (STAGEA) {
            int arow = mt * 16 + a - bx * 64;
            Af = *(const bf16x8*)&xsA[arow * KPS + AOFF + kk * 32 + kg * 8];
        } else {
            int gr = mt * 16 + a; if (gr > MROWS - 1) gr = MROWS - 1;
            Af = *(const bf16x8*)(Abase + (size_t)gr * KPA + AOFF + kk * 32 + kg * 8);
        }
        const char* bb = &bbuf[kk & 1][0];
#pragma unroll
        for (int nt = 0; nt < 13; ++nt) {
            int brow = nt * 16 + a;
            bf16x8 Bf = *(const bf16x8*)(bb + brow * 64 + kg * 16);
            acc[nt] = __builtin_amdgcn_mfma_f32_16x16x32_bf16(Af, Bf, acc[nt], 0, 0, 0);
        }
        __syncthreads();
    }

    const int mbase = mt * 16 + kg * 4;
    if (EPI == 5) {
#pragma unroll
        for (int j = 0; j < 4; ++j) {
            int row = mbase + j;
            float mA = -3.4e38f, mB = -3.4e38f;
#pragma unroll
            for (int nt = 0; nt < 8; ++nt) mA = fmaxf(mA, acc[nt][j]);
#pragma unroll
            for (int nt = 8; nt < 13; ++nt) {
                int col = nt * 16 + a;
                float s = (col < 173) ? acc[nt][j] : -3.4e38f;
                mB = fmaxf(mB, s);
            }
            for (int msk = 1; msk < 16; msk <<= 1) {
                mA = fmaxf(mA, __shfl_xor(mA, msk));
                mB = fmaxf(mB, __shfl_xor(mB, msk));
            }
            float eA[8], eB[5];
            float sA = 0.f, sB = 0.f;
#pragma unroll
            for (int nt = 0; nt < 8; ++nt) { eA[nt] = expf(acc[nt][j] - mA); sA += eA[nt]; }
#pragma unroll
            for (int nt = 8; nt < 13; ++nt) {
                int col = nt * 16 + a;
                float v = (col < 173) ? expf(acc[nt][j] - mB) : 0.f;
                eB[nt - 8] = v; sB += v;
            }
            for (int msk = 1; msk < 16; msk <<= 1) {
                sA += __shfl_xor(sA, msk);
                sB += __shfl_xor(sB, msk);
            }
            float iA = 1.f / sA, iB = 1.f / sB;
            if (row < MROWS) {
#pragma unroll
                for (int nt = 0; nt < 12; ++nt) {
                    int col = nt * 16 + a;
                    float v = (nt < 8) ? eA[nt] * iA
                                       : ((col < 173) ? eB[nt - 8] * iB : 0.f);
                    p0[(size_t)b * p0bs + (size_t)row * p0rs + col] = f2bf(v);
                }
            }
        }
    } else if (EPI == 6) {
#pragma unroll
        for (int nt = 0; nt < 13; ++nt) {
            int col = nt * 16 + a;
            if (col < 196) {
#pragma unroll
                for (int j = 0; j < 4; ++j) {
                    int row = mbase + j;
                    if (row < MROWS)
                        p0[(size_t)b * p0bs + (size_t)row * p0rs + col] = f2bf(acc[nt][j]);
                }
            }
        }
    } else {  // EPI == 4
#pragma unroll
        for (int nt = 0; nt < 13; ++nt) {
            int col = nt * 16 + a;
            if (col < 196) {
#pragma unroll
                for (int j = 0; j < 4; ++j) {
                    int row = mbase + j;
                    if (row < MROWS) {
                        size_t rr = ((size_t)b * MROWS + row) * 196 + col;
                        float v = acc[nt][j] + biasA[col] + biasB[col] +
                                  lnres[rr] + res2[rr];
                        feat[((size_t)b * 173 + cbase + row) * 196 + col] = v;
                        ftb[((size_t)(b * 208 + col)) * 192 + cbase + row] = f2bf(v);
                    }
                }
            }
        }
    }
}

// ---------------- rowsum for finale ----------------
__global__ void k_rowsum(const float* __restrict__ cms, float* __restrict__ rs) {
    int oc = blockIdx.x, b = blockIdx.y;
    int lane = threadIdx.x;
    const float* p = cms + ((size_t)b * 173 + oc) * 196;
    float s = 0.f;
    for (int j = lane; j < 196; j += 64) s += p[j];
    for (int sh = 32; sh; sh >>= 1) s += __shfl_xor(s, sh);
    if (lane == 0) rs[(size_t)b * 173 + oc] = s;
}

// ---------------- transpose of 4 [196,196] matrices ----------------
struct P8 { const float* p[4]; };
__global__ void k_transpose4(P8 ws_in, float* __restrict__ wt) {
    int i = blockIdx.x, m = blockIdx.y;
    const float* w = ws_in.p[m];
    float* o = wt + (size_t)m * 38416;
    for (int t = threadIdx.x; t < 196; t += blockDim.x)
        o[(size_t)i * 196 + t] = w[(size_t)t * 196 + i];
}

// ---------------- BN ----------------
__global__ void k_bn_stats(const float* __restrict__ y, float* __restrict__ stats,
                           int C) {
    int ch = blockIdx.x; int tid = threadIdx.x;
    float s = 0.f, s2 = 0.f;
    for (int b = 0; b < 32; ++b) {
        const float* p = &y[(size_t)(b * C + ch) * 196];
        for (int i = tid; i < 196; i += 256) { float v = p[i]; s += v; s2 += v * v; }
    }
    __shared__ float r1[4], r2[4];
    for (int sh = 32; sh; sh >>= 1) { s += __shfl_xor(s, sh); s2 += __shfl_xor(s2, sh); }
    if ((tid & 63) == 0) { r1[tid >> 6] = s; r2[tid >> 6] = s2; }
    __syncthreads();
    if (tid == 0) {
        float S = r1[0] + r1[1] + r1[2] + r1[3];
        float S2 = r2[0] + r2[1] + r2[2] + r2[3];
        float m = S / 6272.f;
        float v = S2 / 6272.f - m * m;
        stats[2 * ch] = m;
        stats[2 * ch + 1] = rsqrtf(v + 1e-5f);
    }
}

__global__ void k_bn_apply_relu(float* __restrict__ y, const float* __restrict__ stats,
                                const float* __restrict__ g, const float* __restrict__ be,
                                float* __restrict__ fT, unsigned short* __restrict__ xtc,
                                int C) {
    int idx = blockIdx.x;
    int ch = idx % C, b = idx / C;
    int s = threadIdx.x;
    if (s < 196) {
        float m = stats[2 * ch], r = stats[2 * ch + 1];
        float v = y[(size_t)idx * 196 + s];
        float o = fmaxf((v - m) * r * g[ch] + be[ch], 0.f);
        y[(size_t)idx * 196 + s] = o;
        if (fT) fT[((size_t)b * 196 + s) * C + ch] = o;
        if (xtc) {
            int G = C >> 6, gch = ch >> 6, cc = ch & 63;
            xtc[(((size_t)b * G + gch) * 208 + s) * 72 + cc] = f2bf(o);
        }
    }
}

// ---------------- catnum ----------------
__global__ void k_catnum(const float* __restrict__ inp, int A,
                         const float* __restrict__ w, const float* __restrict__ bias,
                         const float* __restrict__ g, const float* __restrict__ be,
                         float* __restrict__ outv) {
    int j = blockIdx.x;
    int lane = threadIdx.x;
    float v = 0.f;
    if (lane < 32) {
        v = bias[j];
        for (int k = 0; k < A; ++k) v += inp[lane * A + k] * w[j * A + k];
    }
    float s = (lane < 32) ? v : 0.f;
    float s2 = (lane < 32) ? v * v : 0.f;
    for (int m = 16; m; m >>= 1) { s += __shfl_xor(s, m, 32); s2 += __shfl_xor(s2, m, 32); }
    if (lane < 32) {
        float mean = s / 32.f;
        float var = s2 / 32.f - mean * mean;
        float rstd = rsqrtf(var + 1e-5f);
        float t = (v - mean) * rstd * g[j] + be[j];
        t = t / (1.f + expf(-t));
        outv[lane * 196 + j] = t;
    }
}

__global__ void k_textbuild(const float* __restrict__ toh, const float* __restrict__ tnm,
                            float* __restrict__ text, float* __restrict__ textT) {
    int idx = blockIdx.x;
    int b = idx / 45, c = idx - b * 45;
    int s = threadIdx.x;
    if (s < 196) {
        float v = (c < 30) ? toh[b * 196 + s] : tnm[b * 196 + s];
        text[(size_t)idx * 196 + s] = v;
        textT[((size_t)b * 196 + s) * 45 + c] = v;
    }
}

// ---------------- GCN dist (multi-row) ----------------
template <int C, int ROWS>
__global__ void k_gcn_dist_t(const float* __restrict__ f, const float* __restrict__ fT,
                             float* __restrict__ dist) {
    __shared__ float fi[ROWS][196];
    const int i0 = blockIdx.x * ROWS, b = blockIdx.y;
    const int tid = threadIdx.x;
    for (int idx = tid; idx < ROWS * 196; idx += 256) {
        int r = idx / 196, n = idx - r * 196;
        fi[r][n] = f[((size_t)(b * C + i0 + r)) * 196 + n];
    }
    __syncthreads();
    if (tid < C) {
        const float* ft = fT + (size_t)b * 196 * C + tid;
        float a[ROWS];
#pragma unroll
        for (int r = 0; r < ROWS; ++r) a[r] = 0.f;
#pragma unroll 4
        for (int n = 0; n < 196; ++n) {
            float v = ft[(size_t)n * C];
#pragma unroll
            for (int r = 0; r < ROWS; ++r) a[r] += fabsf(fi[r][n] - v);
        }
#pragma unroll
        for (int r = 0; r < ROWS; ++r)
            dist[((size_t)(b * C + i0 + r)) * C + tid] = expf(-a[r]);
    }
}

// ---------------- GCN spmm+fin (multi-row) ----------------
template <int C, int ROWS>
__global__ void k_gcn_spmmfin_t(const float* __restrict__ dist, const float* __restrict__ f,
                                const float* __restrict__ wt, const float* __restrict__ bias,
                                float* __restrict__ outp) {
    __shared__ float ds[ROWS][C];
    __shared__ float ts[ROWS][196];
    const int i0 = blockIdx.x * ROWS, b = blockIdx.y;
    const int tid = threadIdx.x;
    for (int idx = tid; idx < ROWS * C; idx += 256) {
        int r = idx / C, j = idx - r * C;
        ds[r][j] = dist[((size_t)(b * C + i0 + r)) * C + j];
    }
    __syncthreads();
    if (tid < 196) {
        float a[ROWS];
#pragma unroll
        for (int r = 0; r < ROWS; ++r) a[r] = 0.f;
#pragma unroll 4
        for (int j = 0; j < C; ++j) {
            float v = f[((size_t)b * C + j) * 196 + tid];
#pragma unroll
            for (int r = 0; r < ROWS; ++r) a[r] += ds[r][j] * v;
        }
#pragma unroll
        for (int r = 0; r < ROWS; ++r) ts[r][tid] = a[r];
    }
    __syncthreads();
    if (tid < 196) {
        float a[ROWS];
        float bi = bias[tid];
#pragma unroll
        for (int r = 0; r < ROWS; ++r) a[r] = bi;
#pragma unroll 4
        for (int n = 0; n < 196; ++n) {
            float wv = wt[(size_t)n * 196 + tid];
#pragma unroll
            for (int r = 0; r < ROWS; ++r) a[r] += ts[r][n] * wv;
        }
#pragma unroll
        for (int r = 0; r < ROWS; ++r) {
            size_t rr = ((size_t)(b * C + i0 + r)) * 196 + tid;
            outp[rr] = fmaxf(a[r], 0.f) + f[rr];
        }
    }
}

// ---------------- LN + relu(linear), emits Kcat + transposed bf16 ----------
template <int R, int ROWS, int KOFF, int TS>
__global__ void k_lnlin2(const float* __restrict__ x, const float* __restrict__ g,
                         const float* __restrict__ be, const float* __restrict__ eT,
                         const float* __restrict__ eb, float* __restrict__ lnout,
                         unsigned short* __restrict__ kcat,
                         unsigned short* __restrict__ tbuf) {
    __shared__ float ls[ROWS][196];
    const int i0 = blockIdx.x * ROWS, b = blockIdx.y;
    const int tid = threadIdx.x;
    const int wv = tid >> 6, lane = tid & 63;
    for (int idx = tid; idx < ROWS * 196; idx += 256) {
        int r = idx / 196, n = idx - r * 196;
        ls[r][n] = x[((size_t)(b * R + i0 + r)) * 196 + n];
    }
    __syncthreads();
    for (int k = 0;; ++k) {
        int r = wv + 4 * k;
        if (r >= ROWS) break;
        float s = 0.f, s2 = 0.f;
        for (int j = lane; j < 196; j += 64) { float v = ls[r][j]; s += v; s2 += v * v; }
        for (int sh = 32; sh; sh >>= 1) { s += __shfl_xor(s, sh); s2 += __shfl_xor(s2, sh); }
        float mean = s / 196.f;
        float var = s2 / 196.f - mean * mean;
        float rstd = rsqrtf(var + 1e-6f);
        size_t rowo = ((size_t)(b * R + i0 + r)) * 196;
        for (int j = lane; j < 196; j += 64) {
            float l = (ls[r][j] - mean) * rstd * g[j] + be[j];
            ls[r][j] = l;
            lnout[rowo + j] = l;
        }
    }
    __syncthreads();
    if (tid < 196) {
        float a[ROWS];
        float bi = eb[tid];
#pragma unroll
        for (int r = 0; r < ROWS; ++r) a[r] = bi;
#pragma unroll 4
        for (int n = 0; n < 196; ++n) {
            float ev = eT[(size_t)n * 196 + tid];
#pragma unroll
            for (int r = 0; r < ROWS; ++r) a[r] += ls[r][n] * ev;
        }
#pragma unroll
        for (int r = 0; r < ROWS; ++r) {
            unsigned short h = f2bf(fmaxf(a[r], 0.f));
            kcat[((size_t)(b * 208 + KOFF + i0 + r)) * 224 + tid] = h;
            tbuf[((size_t)(b * 208 + tid)) * TS + (i0 + r)] = h;
        }
    }
}

// ---------------- final classifier ----------------
__global__ void k_finale(const float* __restrict__ toh, const float* __restrict__ tnm,
                         const float* __restrict__ rowsum, const float* __restrict__ cls_w,
                         const float* __restrict__ cls_b, float* __restrict__ out) {
    int b = blockIdx.x;
    __shared__ float r1[4], r2[4];
    int tid = threadIdx.x;
    float a = (tid < 196) ? toh[b * 196 + tid] : 0.f;
    float c = (tid < 196) ? tnm[b * 196 + tid] : 0.f;
    for (int sh = 32; sh; sh >>= 1) { a += __shfl_xor(a, sh); c += __shfl_xor(c, sh); }
    if ((tid & 63) == 0) { r1[tid >> 6] = a; r2[tid >> 6] = c; }
    __syncthreads();
    if (tid < 2) {
        float soh = r1[0] + r1[1] + r1[2] + r1[3];
        float snm = r2[0] + r2[1] + r2[2] + r2[3];
        const float* wrow = &cls_w[tid * 218];
        float acc = cls_b[tid];
        float w1 = 0.f, w2 = 0.f;
        for (int k = 0; k < 30; ++k) w1 += wrow[k];
        for (int k = 30; k < 45; ++k) w2 += wrow[k];
        acc += soh * w1 + snm * w2;
        for (int k = 0; k < 173; ++k) acc += wrow[45 + k] * rowsum[(size_t)b * 173 + k];
        out[b * 2 + tid] = acc;
    }
}

// ---------------------------------------------------------------------------
extern "C" void kernel_launch(void* const* d_in, const int* in_sizes, int n_in,
                              void* d_out, int out_size, void* d_ws, size_t ws_size,
                              hipStream_t stream) {
    const float* x      = (const float*)d_in[0];
    const float* oneHot = (const float*)d_in[1];
    const float* num    = (const float*)d_in[2];
    const float* c1_w1  = (const float*)d_in[3];
    const float* c1_g1  = (const float*)d_in[5];
    const float* c1_be1 = (const float*)d_in[6];
    const float* c1_w2  = (const float*)d_in[7];
    const float* c1_g2  = (const float*)d_in[9];
    const float* c1_be2 = (const float*)d_in[10];
    const float* oh_w   = (const float*)d_in[11];
    const float* oh_b   = (const float*)d_in[12];
    const float* oh_g   = (const float*)d_in[13];
    const float* oh_be  = (const float*)d_in[14];
    const float* nm_w   = (const float*)d_in[15];
    const float* nm_b   = (const float*)d_in[16];
    const float* nm_g   = (const float*)d_in[17];
    const float* nm_be  = (const float*)d_in[18];
    const float* gm1_w  = (const float*)d_in[19];
    const float* gm1_b  = (const float*)d_in[20];
    const float* gm2_w  = (const float*)d_in[21];
    const float* gm2_b  = (const float*)d_in[22];
    const float* ln1_g  = (const float*)d_in[23];
    const float* ln1_b  = (const float*)d_in[24];
    const float* ln2_g  = (const float*)d_in[25];
    const float* ln2_b  = (const float*)d_in[26];
    const float* e1_w   = (const float*)d_in[27];
    const float* e1_b   = (const float*)d_in[28];
    const float* e2_w   = (const float*)d_in[29];
    const float* e2_b   = (const float*)d_in[30];
    const float* f1_w   = (const float*)d_in[31];
    const float* f1_b   = (const float*)d_in[32];
    const float* f2_w   = (const float*)d_in[33];
    const float* f2_b   = (const float*)d_in[34];
    const float* f3_w   = (const float*)d_in[35];
    const float* f3_b   = (const float*)d_in[36];
    const float* f4_w   = (const float*)d_in[37];
    const float* f4_b   = (const float*)d_in[38];
    const float* cm_w   = (const float*)d_in[39];
    const float* cm_b   = (const float*)d_in[40];
    const float* cmf_w  = (const float*)d_in[41];
    const float* cmf_b  = (const float*)d_in[42];
    const float* cls_w  = (const float*)d_in[43];
    const float* cls_b  = (const float*)d_in[44];
    float* out = (float*)d_out;
    float* W = (float*)d_ws;

    const size_t L = 802816;
    const size_t T = 282240;
    const size_t F3 = 1085056;
    // ---- layout (floats); live ranges annotated ----
    const size_t o_A    = 0;                  // conv1 out
    const size_t o_B    = L;                  // conv2 out -> ln1 (lnres img)
    const size_t o_C    = 2 * L;              // c5f post-gcn (res2 img)
    const size_t o_part = 3 * L;              // conv partials [3L, 8L), conv only
    const size_t o_Kcat = 3 * L;              // bf16 [32][208][224] = 745,472 fl
    const size_t o_iqT  = o_Kcat + 745472;    // bf16 [32][208][128] = 425,984 fl
    const size_t o_t1   = 4 * L + T;          // text f (dead after gcn txt)
    const size_t o_t3   = 4 * L + 2 * T;      // txf post-gcn (res2 txt)
    const size_t o_ln2  = 4 * L + 3 * T;      // ln2 (lnres txt)
    const size_t o_toh  = 4 * L + 4 * T;
    const size_t o_tnm  = o_toh + 6272;
    const size_t o_st   = o_tnm + 6272;
    const size_t o_wT   = o_st + 1024;        // 4 transposed 196x196
    const size_t o_feat = o_wT + 8 * 38416;
    const size_t o_q    = o_feat + F3;        // Fimg (attn) -> cms out (CMSA)
    const size_t o_Fimg = o_q;                // bf16 [32][128][448] = 917,504 fl
    const size_t o_dd   = o_q + F3;           // 6,831,232
    const size_t o_d1   = o_dd;
    const size_t o_d2   = o_dd + 524288;
    const size_t o_tqT  = o_dd;               // bf16 [32][208][64] = 212,992 fl
    const size_t o_wcI  = o_dd + 212992;      // bf16 [208][448] = 46,592 fl
    const size_t o_wcT  = o_wcI + 46592;
    const size_t o_pbf  = o_dd;               // CMSA P (after attn)
    const size_t o_rs   = o_dd;               // rowsum (after pbf dead)
    const size_t o_qbf  = o_dd + 745472;      // 7,576,704: Ftxt (attn) -> qbf (CMSA)
    const size_t o_Ftxt = o_qbf;              // bf16 [32][48][448] = 344,064 fl
    const size_t o_wcm  = o_qbf + 630784;     // 8,207,488
    const size_t o_wcmf = o_wcm + 16896;
    const size_t o_ftb  = o_wcmf + 16896;     // 8,241,280 (638,976)
    const size_t o_tr   = o_ftb + 638976;     // 8,880,256: fT twins -> P -> qtb/feab
    const size_t o_Pimg = o_tr;               // bf16 [32][128][192] = 393,216 fl
    const size_t o_Ptxt = o_tr + 393216;      // bf16 [32][48][192]  = 147,456 fl
    const size_t o_qtb  = o_tr;
    const size_t o_feab = o_qtb + 638976;     // ends 10,158,208 (40.6 MB)
    // conv scratch (dead after conv2), overlays o_dd..9,282,688:
    const size_t o_xt1 = o_dd;
    const size_t o_xt2 = o_xt1 + 1198080;
    const size_t o_wp1 = o_xt2 + 479232;
    const size_t o_wp2 = o_wp1 + 552960;

    float* part = W + o_part;
    unsigned short* xt1 = (unsigned short*)(W + o_xt1);
    unsigned short* xt2 = (unsigned short*)(W + o_xt2);
    unsigned short* wp1 = (unsigned short*)(W + o_wp1);
    unsigned short* wp2 = (unsigned short*)(W + o_wp2);
    unsigned short* kcatb = (unsigned short*)(W + o_Kcat);
    unsigned short* iqTb = (unsigned short*)(W + o_iqT);
    unsigned short* tqTb = (unsigned short*)(W + o_tqT);
    unsigned short* wcatI = (unsigned short*)(W + o_wcI);
    unsigned short* wcatT = (unsigned short*)(W + o_wcT);
    unsigned short* Fimg = (unsigned short*)(W + o_Fimg);
    unsigned short* Ftxt = (unsigned short*)(W + o_Ftxt);
    unsigned short* Pimg = (unsigned short*)(W + o_Pimg);
    unsigned short* Ptxt = (unsigned short*)(W + o_Ptxt);
    unsigned short* ftb = (unsigned short*)(W + o_ftb);
    unsigned short* qtb = (unsigned short*)(W + o_qtb);
    unsigned short* feab = (unsigned short*)(W + o_feab);
    unsigned short* qbf = (unsigned short*)(W + o_qbf);
    unsigned short* wcmb = (unsigned short*)(W + o_wcm);
    unsigned short* wcmfb = (unsigned short*)(W + o_wcmf);
    unsigned short* pbf = (unsigned short*)(W + o_pbf);
    float* gm1T = W + o_wT + 0 * 38416;
    float* gm2T = W + o_wT + 1 * 38416;
    float* e1T  = W + o_wT + 2 * 38416;
    float* e2T  = W + o_wT + 3 * 38416;

    // ---- conv prep ----
    k_wpack<<<(27 * 128 * 40 + 255) / 256, 256, 0, stream>>>(c1_w1, wp1, 320);
    k_wpack<<<(27 * 128 * 16 + 255) / 256, 256, 0, stream>>>(c1_w2, wp2, 128);
    k_xt_c<<<dim3((5 * 208 * 36 + 255) / 256, 32), 256, 0, stream>>>(x, xt1, 320, 5);

    // ---- conv1 ----
    k_convchunk4<320, 5, 4, 2><<<dim3(20, 32), 256, 0, stream>>>(xt1, wp1, part);
    k_reduceG<5><<<3136, 256, 0, stream>>>(part, W + o_A, 802816);
    k_bn_stats<<<128, 256, 0, stream>>>(W + o_A, W + o_st, 128);
    k_bn_apply_relu<<<4096, 256, 0, stream>>>(W + o_A, W + o_st, c1_g1, c1_be1,
                                              nullptr, xt2, 128);

    // ---- conv2 (BN emits fTimg at o_tr) ----
    k_convchunk4<128, 2, 2, 4><<<dim3(16, 32), 256, 0, stream>>>(xt2, wp2, part);
    k_reduceG<2><<<3136, 256, 0, stream>>>(part, W + o_B, 802816);
    k_bn_stats<<<128, 256, 0, stream>>>(W + o_B, W + o_st + 512, 128);
    k_bn_apply_relu<<<4096, 256, 0, stream>>>(W + o_B, W + o_st + 512, c1_g2, c1_be2,
                                              W + o_tr, nullptr, 128);

    // ---- conv scratch dead: CMSA weight packs + zero ftb ----
    k_w173<<<(176 * 192 + 255) / 256, 256, 0, stream>>>(cm_w, wcmb);
    k_w173<<<(176 * 192 + 255) / 256, 256, 0, stream>>>(cmf_w, wcmfb);
    k_zero4<<<(638976 / 4 + 255) / 256, 256, 0, stream>>>((float4*)(W + o_ftb), 638976 / 4);

    // ---- weight transposes (gm1,gm2,e1,e2 only) ----
    P8 p8;
    p8.p[0] = gm1_w; p8.p[1] = gm2_w; p8.p[2] = e1_w; p8.p[3] = e2_w;
    k_transpose4<<<dim3(196, 4), 256, 0, stream>>>(p8, W + o_wT);

    // ---- catnum / text (fTtxt at o_tr+L) ----
    k_catnum<<<196, 64, 0, stream>>>(oneHot, 24, oh_w, oh_b, oh_g, oh_be, W + o_toh);
    k_catnum<<<196, 64, 0, stream>>>(num, 11, nm_w, nm_b, nm_g, nm_be, W + o_tnm);
    k_textbuild<<<32 * 45, 256, 0, stream>>>(W + o_toh, W + o_tnm, W + o_t1, W + o_tr + L);

    // ---- GCN img / txt ----
    k_gcn_dist_t<128, 4><<<dim3(32, 32), 256, 0, stream>>>(W + o_B, W + o_tr, W + o_d1);
    k_gcn_spmmfin_t<128, 4><<<dim3(32, 32), 256, 0, stream>>>(W + o_d1, W + o_B, gm1T,
                                                              gm1_b, W + o_C);
    k_gcn_dist_t<45, 3><<<dim3(15, 32), 256, 0, stream>>>(W + o_t1, W + o_tr + L, W + o_d2);
    k_gcn_spmmfin_t<45, 3><<<dim3(15, 32), 256, 0, stream>>>(W + o_d2, W + o_t1, gm2T,
                                                             gm2_b, W + o_t3);

    // ---- dists + t1 dead: attention buffer prep ----
    k_zero4<<<(1171456 / 4 + 255) / 256, 256, 0, stream>>>((float4*)(W + o_Kcat),
                                                           1171456 / 4);   // Kcat+iqT
    k_zero4<<<(212992 / 4 + 255) / 256, 256, 0, stream>>>((float4*)(W + o_tqT),
                                                          212992 / 4);
    k_zero4<<<(917504 / 4 + 255) / 256, 256, 0, stream>>>((float4*)(W + o_Fimg),
                                                          917504 / 4);
    k_zero4<<<(344064 / 4 + 255) / 256, 256, 0, stream>>>((float4*)(W + o_Ftxt),
                                                          344064 / 4);
    k_wcat<<<(208 * 448 + 255) / 256, 256, 0, stream>>>(f1_w, f3_w, wcatI);
    k_wcat<<<(208 * 448 + 255) / 256, 256, 0, stream>>>(f4_w, f2_w, wcatT);

    // ---- LN + q projections -> Kcat/iqT/tqT bf16 ----
    k_lnlin2<128, 4, 0, 128><<<dim3(32, 32), 256, 0, stream>>>(
        W + o_C, ln1_g, ln1_b, e1T, e1_b, W + o_B, kcatb, iqTb);
    k_lnlin2<45, 3, 128, 64><<<dim3(15, 32), 256, 0, stream>>>(
        W + o_t3, ln2_g, ln2_b, e2T, e2_b, W + o_ln2, kcatb, tqTb);

    // ---- attention GEMM 1: scores + dual softmax -> P ----
    k_agemm<128, 8, 224, 224, 0, 7, 5, 1><<<dim3(2, 32), 256, 0, stream>>>(
        kcatb, (size_t)208 * 224, kcatb, (size_t)208 * 224,
        nullptr, nullptr, nullptr, nullptr, Pimg, 192, (size_t)128 * 192,
        nullptr, nullptr, 0);
    k_agemm<45, 3, 224, 224, 0, 7, 5, 1><<<dim3(1, 32), 256, 0, stream>>>(
        kcatb + 128 * 224, (size_t)208 * 224, kcatb, (size_t)208 * 224,
        nullptr, nullptr, nullptr, nullptr, Ptxt, 192, (size_t)48 * 192,
        nullptr, nullptr, 0);

    // ---- attention GEMM 2: PV halves -> F ----
    k_agemm<128, 8, 192, 128, 0, 4, 6, 1><<<dim3(2, 32), 256, 0, stream>>>(
        Pimg, (size_t)128 * 192, iqTb, (size_t)208 * 128,
        nullptr, nullptr, nullptr, nullptr, Fimg, 448, (size_t)128 * 448,
        nullptr, nullptr, 0);
    k_agemm<128, 8, 192, 64, 128, 2, 6, 1><<<dim3(2, 32), 256, 0, stream>>>(
        Pimg, (size_t)128 * 192, tqTb, (size_t)208 * 64,
        nullptr, nullptr, nullptr, nullptr, Fimg + 224, 448, (size_t)128 * 448,
        nullptr, nullptr, 0);
    k_agemm<45, 3, 192, 128, 0, 4, 6, 1><<<dim3(1, 32), 256, 0, stream>>>(
        Ptxt, (size_t)48 * 192, iqTb, (size_t)208 * 128,
        nullptr, nullptr, nullptr, nullptr, Ftxt, 448, (size_t)48 * 448,
        nullptr, nullptr, 0);
    k_agemm<45, 3, 192, 64, 128, 2, 6, 1><<<dim3(1, 32), 256, 0, stream>>>(
        Ptxt, (size_t)48 * 192, tqTb, (size_t)208 * 64,
        nullptr, nullptr, nullptr, nullptr, Ftxt + 224, 448, (size_t)48 * 448,
        nullptr, nullptr, 0);

    // ---- attention GEMM 3: projection + residuals -> feat + ftb ----
    k_agemm<128, 8, 448, 448, 0, 14, 4, 0><<<dim3(2, 32), 256, 0, stream>>>(
        Fimg, (size_t)128 * 448, wcatI, 0,
        f1_b, f3_b, W + o_B, W + o_C, nullptr, 0, 0, W + o_feat, ftb, 0);
    k_agemm<45, 3, 448, 448, 0, 14, 4, 0><<<dim3(1, 32), 256, 0, stream>>>(
        Ftxt, (size_t)48 * 448, wcatT, 0,
        f2_b, f4_b, W + o_ln2, W + o_t3, nullptr, 0, 0, W + o_feat, ftb, 128);

    // ---- attention buffers dead: CMSA prep ----
    k_zero4<<<(1277952 / 4 + 255) / 256, 256, 0, stream>>>((float4*)(W + o_qtb),
                                                           1277952 / 4);
    k_zero4<<<(630784 / 4 + 255) / 256, 256, 0, stream>>>((float4*)(W + o_qbf),
                                                          630784 / 4);
    k_zero4<<<(745472 / 4 + 255) / 256, 256, 0, stream>>>((float4*)(W + o_pbf),
                                                          745472 / 4);

    // ---- CMSA via MFMA GEMMs ----
    k_bgemm<176, 11, 192, 6, 0><<<dim3(3, 32), 256, 0, stream>>>(
        wcmb, 0, ftb, (size_t)208 * 192, cm_b, qbf, qtb, nullptr, nullptr);
    k_bgemm<208, 13, 192, 6, 1><<<dim3(4, 32), 256, 0, stream>>>(
        qtb, (size_t)208 * 192, qtb, (size_t)208 * 192, nullptr, pbf, nullptr,
        nullptr, nullptr);
    k_bgemm<176, 11, 224, 7, 2><<<dim3(3, 32), 256, 0, stream>>>(
        qbf, (size_t)176 * 224, pbf, (size_t)208 * 224, nullptr, feab, nullptr,
        nullptr, nullptr);
    k_bgemm<176, 11, 192, 6, 3><<<dim3(3, 32), 256, 0, stream>>>(
        wcmfb, 0, feab, (size_t)208 * 192, cmf_b, nullptr, nullptr,
        W + o_feat, W + o_q);

    // ---- rowsum + final classifier ----
    k_rowsum<<<dim3(173, 32), 64, 0, stream>>>(W + o_q, W + o_rs);
    k_finale<<<32, 256, 0, stream>>>(W + o_toh, W + o_tnm, W + o_rs, cls_w, cls_b, out);
}

// Round 16
// 449.337 us; speedup vs baseline: 1.0822x; 1.0822x over previous
//
#include <hip/hip_runtime.h>
#include <hip/hip_bf16.h>

// ---------------------------------------------------------------------------
// mv3Dunet_down_text_cmsa forward. Round 16: r15 regression fixed — N-split
// (NS=2) GEMMs for 2x grid occupancy, PV halves merged into one kernel per
// modality (self-zeroing pads), 3 zero launches eliminated.
// ---------------------------------------------------------------------------

using bf16x8 = __attribute__((ext_vector_type(8))) short;
using f32x4  = __attribute__((ext_vector_type(4))) float;

typedef const __attribute__((address_space(1))) void gas_void;
typedef __attribute__((address_space(3))) void las_void;

__device__ __forceinline__ unsigned short f2bf(float f) {
    unsigned int u = __float_as_uint(f);
    u += 0x7FFFu + ((u >> 16) & 1u);
    return (unsigned short)(u >> 16);
}

// ---------------- zero helper ----------------
__global__ void k_zero4(float4* __restrict__ p, int n4) {
    int i = blockIdx.x * 256 + threadIdx.x;
    if (i < n4) p[i] = (float4){0.f, 0.f, 0.f, 0.f};
}

// ---------------- X -> chunk-major bf16: xt[b][g][208][72] ----------------
__global__ void k_xt_c(const float* __restrict__ x, unsigned short* __restrict__ xt,
                       int IC, int G) {
    int b = blockIdx.y;
    int tot = G * 208 * 36;
    int idx = blockIdx.x * 256 + threadIdx.x;
    if (idx >= tot) return;
    int g = idx / (208 * 36); int r = idx - g * 208 * 36;
    int s = r / 36, cp = r - s * 36;
    int cc = cp * 2;
    int ic = g * 64 + cc;
    unsigned int lo = 0, hi = 0;
    if (s < 196 && cc < 64 && ic < IC)         lo = f2bf(x[((size_t)b * IC + ic) * 196 + s]);
    if (s < 196 && cc + 1 < 64 && ic + 1 < IC) hi = f2bf(x[((size_t)b * IC + ic + 1) * 196 + s]);
    ((unsigned int*)xt)[(size_t)b * tot + idx] = lo | (hi << 16);
}

// ---------------- weight pack: w[oc][ic][27] f32 -> wp[t][oc][ic] bf16 ------
__global__ void k_wpack(const float* __restrict__ w, unsigned short* __restrict__ wp,
                        int IC) {
    int nc = IC >> 3;
    int idx = blockIdx.x * 256 + threadIdx.x;
    if (idx >= 27 * 128 * nc) return;
    int c = idx % nc; int r = idx / nc; int oc = r & 127; int t = r >> 7;
    const float* ws = w + ((size_t)oc * IC + c * 8) * 27 + t;
    unsigned int o0 = f2bf(ws[0])   | ((unsigned int)f2bf(ws[27])  << 16);
    unsigned int o1 = f2bf(ws[54])  | ((unsigned int)f2bf(ws[81])  << 16);
    unsigned int o2 = f2bf(ws[108]) | ((unsigned int)f2bf(ws[135]) << 16);
    unsigned int o3 = f2bf(ws[162]) | ((unsigned int)f2bf(ws[189]) << 16);
    uint4 v; v.x = o0; v.y = o1; v.z = o2; v.w = o3;
    ((uint4*)wp)[idx] = v;
}

// ---------------- pack 173x173 f32 -> [176][192] bf16 zero-padded -----------
__global__ void k_w173(const float* __restrict__ w, unsigned short* __restrict__ wb) {
    int idx = blockIdx.x * 256 + threadIdx.x;
    if (idx >= 176 * 192) return;
    int oc = idx / 192, c = idx - oc * 192;
    wb[idx] = (oc < 173 && c < 173) ? f2bf(w[(size_t)oc * 173 + c]) : (unsigned short)0;
}

// ---------------- pack Wcat[208][448]: [wA | pad | wB | pad] ----------------
__global__ void k_wcat(const float* __restrict__ wA, const float* __restrict__ wB,
                       unsigned short* __restrict__ outw) {
    int idx = blockIdx.x * 256 + threadIdx.x;
    if (idx >= 208 * 448) return;
    int n = idx / 448, k = idx - n * 448;
    unsigned short v = 0;
    if (n < 196) {
        if (k < 196) v = f2bf(wA[(size_t)n * 196 + k]);
        else if (k >= 224 && k < 420) v = f2bf(wB[(size_t)n * 196 + (k - 224)]);
    }
    outw[idx] = v;
}

// ---------------- MFMA conv (validated) ----------------
template <int IC, int G, int NT, int NH>
__global__ __launch_bounds__(256, 3) void k_convchunk4(
    const unsigned short* __restrict__ xt, const unsigned short* __restrict__ wp,
    float* __restrict__ part) {
    __shared__ unsigned short xs[208 * 72];
    __shared__ char bbuf[2][NT * 2048];
    const int tid = threadIdx.x;
    const int bx = blockIdx.x, b = blockIdx.y;
    const int mh = bx & 1;
    const int nh = (bx >> 1) % NH;
    const int g  = (bx >> 1) / NH;
    const int w = tid >> 6, l = tid & 63;

    {
        const bf16x8* s8 = (const bf16x8*)(xt + ((size_t)b * G + g) * (208 * 72));
        bf16x8* d8 = (bf16x8*)xs;
        for (int c = tid; c < 208 * 72 / 8; c += 256) d8[c] = s8[c];
    }

    const char* wslice = (const char*)wp +
                         ((size_t)(nh * NT * 16) * IC + (size_t)g * 64) * 2;
    auto stageB = [&](int t) {
        char* dst = &bbuf[t & 1][w * (NT * 512)];
        const char* wt_ = wslice + (size_t)t * 128 * IC * 2;
#pragma unroll
        for (int c = 0; c < NT / 2; ++c) {
            int q = w * (NT * 512) + c * 1024 + l * 16;
            int row = q >> 7, col = q & 127;
            int scol = col ^ ((row & 7) << 4);
            gas_void* src = (gas_void*)(wt_ + (size_t)row * IC * 2 + scol);
            __builtin_amdgcn_global_load_lds(src, (las_void*)(dst + c * 1024),
                                             16, 0, 0);
        }
    };

    const int lane = tid & 63;
    const int a = lane & 15, kg = lane >> 4;

    int md[2], mhh[2], mw[2];
#pragma unroll
    for (int i = 0; i < 2; ++i) {
        int m = (mh * 8 + (tid >> 6) * 2 + i) * 16 + a;
        md[i] = m / 49; int rr = m - md[i] * 49;
        mhh[i] = rr / 7; mw[i] = rr - mhh[i] * 7;
    }

    f32x4 acc[2][NT];
#pragma unroll
    for (int i = 0; i < 2; ++i)
#pragma unroll
        for (int nt = 0; nt < NT; ++nt) acc[i][nt] = (f32x4){0.f, 0.f, 0.f, 0.f};

    const bf16x8 zv = {0, 0, 0, 0, 0, 0, 0, 0};

    stageB(0);
    __syncthreads();

    for (int t = 0; t < 27; ++t) {
        if (t < 26) stageB(t + 1);
        const int kd = t / 9, kh = (t / 3) % 3, kw = t % 3;
        int rsrc[2]; bool ok[2];
#pragma unroll
        for (int i = 0; i < 2; ++i) {
            int d2 = md[i] + kd - 1, h2 = mhh[i] + kh - 1, w2 = mw[i] + kw - 1;
            ok[i] = ((unsigned)d2 < 4u) & ((unsigned)h2 < 7u) & ((unsigned)w2 < 7u);
            rsrc[i] = ok[i] ? (d2 * 49 + h2 * 7 + w2) : 0;
        }
        bf16x8 A[2][2];
#pragma unroll
        for (int kk = 0; kk < 2; ++kk)
#pragma unroll
            for (int i = 0; i < 2; ++i) {
                bf16x8 v = *(const bf16x8*)(xs + rsrc[i] * 72 + kk * 32 + kg * 8);
                A[kk][i] = ok[i] ? v : zv;
            }
        const char* bb = &bbuf[t & 1][0];
#pragma unroll
        for (int kk = 0; kk < 2; ++kk)
#pragma unroll
            for (int nt = 0; nt < NT; ++nt) {
                int row = nt * 16 + a;
                int cb = (kk * 64 + kg * 16) ^ ((row & 7) << 4);
                bf16x8 B = *(const bf16x8*)(bb + row * 128 + cb);
#pragma unroll
                for (int i = 0; i < 2; ++i)
                    acc[i][nt] = __builtin_amdgcn_mfma_f32_16x16x32_bf16(
                        A[kk][i], B, acc[i][nt], 0, 0, 0);
            }
        __syncthreads();
    }

    float* dst = part + ((size_t)g * 32 + b) * (128 * 196);
#pragma unroll
    for (int i = 0; i < 2; ++i) {
        int m0 = (mh * 8 + (tid >> 6) * 2 + i) * 16 + kg * 4;
        if (m0 < 196) {
#pragma unroll
            for (int nt = 0; nt < NT; ++nt) {
                int oc = nh * NT * 16 + nt * 16 + a;
                *(f32x4*)(dst + (size_t)oc * 196 + m0) = acc[i][nt];
            }
        }
    }
}

template <int G>
__global__ void k_reduceG(const float* __restrict__ part, float* __restrict__ y, int n) {
    int i = blockIdx.x * blockDim.x + threadIdx.x;
    if (i < n) {
        float s = 0.f;
#pragma unroll
        for (int g = 0; g < G; ++g) s += part[(size_t)g * n + i];
        y[i] = s;
    }
}

// ---------------- CMSA batched MFMA GEMM, N-split ----------------
template <int MROWS, int MTILES, int KP, int KK, int EPI, int NS>
__global__ __launch_bounds__(256, 2) void k_bgemm(
    const unsigned short* __restrict__ Ab, size_t ABS,
    const unsigned short* __restrict__ Bb, size_t BBS,
    const float* __restrict__ bias,
    unsigned short* __restrict__ p0, unsigned short* __restrict__ p1,
    const float* __restrict__ resid, float* __restrict__ outf) {
    constexpr int KPS = KP + 8;
    __shared__ unsigned short xsA[64 * KPS];
    __shared__ char bbuf[2][208 * 64];
    const int tid = threadIdx.x, bx = blockIdx.x, b = blockIdx.y;
    const int wv = tid >> 6, lane = tid & 63, a = lane & 15, kg = lane >> 4;
    const int nh = bx % NS, mg = bx / NS;
    const int NT0 = (NS == 1) ? 0 : nh * 7;
    const int NTN = (NS == 1) ? 13 : ((nh == 0) ? 7 : 6);

    const unsigned short* Abase = Ab + (size_t)b * ABS;
    {
        const int rowu = KP / 2;
        for (int i = tid; i < 64 * rowu; i += 256) {
            int r = i / rowu, cu = i - r * rowu;
            int gr = mg * 64 + r; if (gr > MROWS - 1) gr = MROWS - 1;
            unsigned int v = ((const unsigned int*)(Abase + (size_t)gr * KP))[cu];
            *(unsigned int*)&xsA[r * KPS + cu * 2] = v;
        }
    }
    const char* Bbase = (const char*)(Bb + (size_t)b * BBS);
    auto stageB = [&](int kk) {
        char* dst0 = &bbuf[kk & 1][0];
        const int cnt = NTN * 64;
#pragma unroll
        for (int c = 0; c < 4; ++c) {
            int idx = tid + c * 256;
            if (idx < cnt) {
                int lrow = idx >> 2, u = idx & 3;
                int grow = NT0 * 16 + lrow;
                gas_void* src = (gas_void*)(Bbase + (size_t)grow * (KP * 2) +
                                            kk * 64 + u * 16);
                __builtin_amdgcn_global_load_lds(src, (las_void*)(dst0 + (size_t)idx * 16),
                                                 16, 0, 0);
            }
        }
    };

    int mt = mg * 4 + wv; if (mt > MTILES - 1) mt = MTILES - 1;
    const int arow = mt * 16 + a - mg * 64;

    f32x4 acc[13];
#pragma unroll
    for (int nt = 0; nt < 13; ++nt) acc[nt] = (f32x4){0.f, 0.f, 0.f, 0.f};

    stageB(0);
    __syncthreads();
    for (int kk = 0; kk < KK; ++kk) {
        if (kk + 1 < KK) stageB(kk + 1);
        bf16x8 Af = *(const bf16x8*)&xsA[arow * KPS + kk * 32 + kg * 8];
        const char* bb = &bbuf[kk & 1][0];
#pragma unroll
        for (int nt = 0; nt < 13; ++nt) {
            if (nt >= NT0 && nt < NT0 + NTN) {
                bf16x8 Bf = *(const bf16x8*)(bb + ((nt - NT0) * 16 + a) * 64 + kg * 16);
                acc[nt] = __builtin_amdgcn_mfma_f32_16x16x32_bf16(Af, Bf, acc[nt], 0, 0, 0);
            }
        }
        __syncthreads();
    }

    const int mbase = mt * 16 + kg * 4;
    if (EPI == 0) {
#pragma unroll
        for (int nt = 0; nt < 13; ++nt) {
            if (nt < NT0 || nt >= NT0 + NTN) continue;
            int col = nt * 16 + a;
            if (col < 196) {
#pragma unroll
                for (int j = 0; j < 4; ++j) {
                    int row = mbase + j;
                    if (row < 173) {
                        unsigned short h = f2bf(fmaxf(acc[nt][j] + bias[row], 0.f));
                        p0[((size_t)b * 176 + row) * 224 + col] = h;
                        p1[((size_t)b * 208 + col) * 192 + row] = h;
                    }
                }
            }
        }
    } else if (EPI == 1) {
#pragma unroll
        for (int j = 0; j < 4; ++j) {
            int row = mbase + j;
            float m = -3.4e38f;
#pragma unroll
            for (int nt = 0; nt < 13; ++nt) {
                int col = nt * 16 + a;
                float s = (col < 196) ? acc[nt][j] : -3.4e38f;
                m = fmaxf(m, s);
            }
            for (int msk = 1; msk < 16; msk <<= 1) m = fmaxf(m, __shfl_xor(m, msk));
            float e[13]; float sum = 0.f;
#pragma unroll
            for (int nt = 0; nt < 13; ++nt) {
                int col = nt * 16 + a;
                float v = (col < 196) ? expf(acc[nt][j] - m) : 0.f;
                e[nt] = v; sum += v;
            }
            for (int msk = 1; msk < 16; msk <<= 1) sum += __shfl_xor(sum, msk);
            float inv = 1.f / sum;
            if (row < 196) {
#pragma unroll
                for (int nt = 0; nt < 13; ++nt) {
                    int col = nt * 16 + a;
                    p0[((size_t)b * 208 + row) * 224 + col] = f2bf(e[nt] * inv);
                }
            }
        }
    } else if (EPI == 2) {
#pragma unroll
        for (int nt = 0; nt < 13; ++nt) {
            if (nt < NT0 || nt >= NT0 + NTN) continue;
            int col = nt * 16 + a;
#pragma unroll
            for (int j = 0; j < 4; ++j) {
                int row = mbase + j;
                if (row < 173)
                    p0[((size_t)b * 208 + col) * 192 + row] = f2bf(acc[nt][j]);
            }
        }
    } else {
#pragma unroll
        for (int nt = 0; nt < 13; ++nt) {
            if (nt < NT0 || nt >= NT0 + NTN) continue;
            int col = nt * 16 + a;
            if (col < 196) {
#pragma unroll
                for (int j = 0; j < 4; ++j) {
                    int row = mbase + j;
                    if (row < 173) {
                        size_t rr = ((size_t)b * 173 + row) * 196 + col;
                        outf[rr] = fmaxf(acc[nt][j] + bias[row], 0.f) + resid[rr];
                    }
                }
            }
        }
    }
}

// ---------------- attention GEMM (scores EPI5 / proj EPI4), N-split --------
template <int MROWS, int MTILES, int KPA, int KPB, int KK, int EPI, int STAGEA, int NS>
__global__ __launch_bounds__(256, 2) void k_agemm(
    const unsigned short* __restrict__ Ab, size_t ABS,
    const unsigned short* __restrict__ Bb, size_t BBS,
    const float* __restrict__ biasA, const float* __restrict__ biasB,
    const float* __restrict__ lnres, const float* __restrict__ res2,
    unsigned short* __restrict__ p0, size_t p0rs, size_t p0bs,
    float* __restrict__ feat, unsigned short* __restrict__ ftb, int cbase) {
    constexpr int KPS = KPA + 8;
    __shared__ unsigned short xsA[STAGEA ? 64 * KPS : 64];
    __shared__ char bbuf[2][208 * 64];
    const int tid = threadIdx.x, bx = blockIdx.x, b = blockIdx.y;
    const int wv = tid >> 6, lane = tid & 63, a = lane & 15, kg = lane >> 4;
    const int nh = bx % NS, mg = bx / NS;
    const int NT0 = (NS == 1) ? 0 : nh * 7;
    const int NTN = (NS == 1) ? 13 : ((nh == 0) ? 7 : 6);

    const unsigned short* Abase = Ab + (size_t)b * ABS;
    if (STAGEA) {
        const int rowu = KPA / 2;
        for (int i = tid; i < 64 * rowu; i += 256) {
            int r = i / rowu, cu = i - r * rowu;
            int gr = mg * 64 + r; if (gr > MROWS - 1) gr = MROWS - 1;
            unsigned int v = ((const unsigned int*)(Abase + (size_t)gr * KPA))[cu];
            *(unsigned int*)&xsA[r * KPS + cu * 2] = v;
        }
    }
    const char* Bbase = (const char*)(Bb + (size_t)b * BBS);
    auto stageB = [&](int kk) {
        char* dst0 = &bbuf[kk & 1][0];
        const int cnt = NTN * 64;
#pragma unroll
        for (int c = 0; c < 4; ++c) {
            int idx = tid + c * 256;
            if (idx < cnt) {
                int lrow = idx >> 2, u = idx & 3;
                int grow = NT0 * 16 + lrow;
                gas_void* src = (gas_void*)(Bbase + (size_t)grow * (KPB * 2) +
                                            kk * 64 + u * 16);
                __builtin_amdgcn_global_load_lds(src, (las_void*)(dst0 + (size_t)idx * 16),
                                                 16, 0, 0);
            }
        }
    };

    int mt = mg * 4 + wv; if (mt > MTILES - 1) mt = MTILES - 1;

    f32x4 acc[13];
#pragma unroll
    for (int nt = 0; nt < 13; ++nt) acc[nt] = (f32x4){0.f, 0.f, 0.f, 0.f};

    stageB(0);
    __syncthreads();
    for (int kk = 0; kk < KK; ++kk) {
        if (kk + 1 < KK) stageB(kk + 1);
        bf16x8 Af;
        if (STAGEA) {
            int arow = mt * 16 + a - mg * 64;
            Af = *(const bf16x8*)&xsA[arow * KPS + kk * 32 + kg * 8];
        } else {
            int gr = mt * 16 + a; if (gr > MROWS - 1) gr = MROWS - 1;
            Af = *(const bf16x8*)(Abase + (size_t)gr * KPA + kk * 32 + kg * 8);
        }
        const char* bb = &bbuf[kk & 1][0];
#pragma unroll
        for (int nt = 0; nt < 13; ++nt) {
            if (nt >= NT0 && nt < NT0 + NTN) {
                bf16x8 Bf = *(const bf16x8*)(bb + ((nt - NT0) * 16 + a) * 64 + kg * 16);
                acc[nt] = __builtin_amdgcn_mfma_f32_16x16x32_bf16(Af, Bf, acc[nt], 0, 0, 0);
            }
        }
        __syncthreads();
    }

    const int mbase = mt * 16 + kg * 4;
    if (EPI == 5) {
#pragma unroll
        for (int j = 0; j < 4; ++j) {
            int row = mbase + j;
            float mA = -3.4e38f, mB = -3.4e38f;
#pragma unroll
            for (int nt = 0; nt < 8; ++nt) mA = fmaxf(mA, acc[nt][j]);
#pragma unroll
            for (int nt = 8; nt < 13; ++nt) {
                int col = nt * 16 + a;
                float s = (col < 173) ? acc[nt][j] : -3.4e38f;
                mB = fmaxf(mB, s);
            }
            for (int msk = 1; msk < 16; msk <<= 1) {
                mA = fmaxf(mA, __shfl_xor(mA, msk));
                mB = fmaxf(mB, __shfl_xor(mB, msk));
            }
            float eA[8], eB[5];
            float sA = 0.f, sB = 0.f;
#pragma unroll
            for (int nt = 0; nt < 8; ++nt) { eA[nt] = expf(acc[nt][j] - mA); sA += eA[nt]; }
#pragma unroll
            for (int nt = 8; nt < 13; ++nt) {
                int col = nt * 16 + a;
                float v = (col < 173) ? expf(acc[nt][j] - mB) : 0.f;
                eB[nt - 8] = v; sB += v;
            }
            for (int msk = 1; msk < 16; msk <<= 1) {
                sA += __shfl_xor(sA, msk);
                sB += __shfl_xor(sB, msk);
            }
            float iA = 1.f / sA, iB = 1.f / sB;
            if (row < MROWS) {
#pragma unroll
                for (int nt = 0; nt < 12; ++nt) {
                    int col = nt * 16 + a;
                    float v = (nt < 8) ? eA[nt] * iA
                                       : ((col < 173) ? eB[nt - 8] * iB : 0.f);
                    p0[(size_t)b * p0bs + (size_t)row * p0rs + col] = f2bf(v);
                }
            }
        }
    } else {  // EPI == 4
#pragma unroll
        for (int nt = 0; nt < 13; ++nt) {
            if (nt < NT0 || nt >= NT0 + NTN) continue;
            int col = nt * 16 + a;
            if (col < 196) {
#pragma unroll
                for (int j = 0; j < 4; ++j) {
                    int row = mbase + j;
                    if (row < MROWS) {
                        size_t rr = ((size_t)b * MROWS + row) * 196 + col;
                        float v = acc[nt][j] + biasA[col] + biasB[col] +
                                  lnres[rr] + res2[rr];
                        feat[((size_t)b * 173 + cbase + row) * 196 + col] = v;
                        ftb[((size_t)(b * 208 + col)) * 192 + cbase + row] = f2bf(v);
                    }
                }
            }
        }
    }
}

// ---------------- PV merged kernel: F = [P_A*V1 | P_B*V2], self-zero pads ---
template <int MROWS, int MTILES, int NS>
__global__ __launch_bounds__(256, 2) void k_pv(
    const unsigned short* __restrict__ P, size_t Pbs,
    const unsigned short* __restrict__ V1, size_t V1bs,
    const unsigned short* __restrict__ V2, size_t V2bs,
    unsigned short* __restrict__ F, size_t Fbs) {
    constexpr int KPS = 200;
    __shared__ unsigned short xsA[64 * KPS];
    __shared__ char bbuf[2][208 * 64];
    const int tid = threadIdx.x, bx = blockIdx.x, b = blockIdx.y;
    const int wv = tid >> 6, lane = tid & 63, a = lane & 15, kg = lane >> 4;
    const int nh = bx % NS, mg = bx / NS;
    const int NT0 = (NS == 1) ? 0 : nh * 7;
    const int NTN = (NS == 1) ? 13 : ((nh == 0) ? 7 : 6);

    const unsigned short* Abase = P + (size_t)b * Pbs;
    {
        for (int i = tid; i < 64 * 96; i += 256) {
            int r = i / 96, cu = i - r * 96;
            int gr = mg * 64 + r; if (gr > MROWS - 1) gr = MROWS - 1;
            unsigned int v = ((const unsigned int*)(Abase + (size_t)gr * 192))[cu];
            *(unsigned int*)&xsA[r * KPS + cu * 2] = v;
        }
    }
    int mt = mg * 4 + wv; if (mt > MTILES - 1) mt = MTILES - 1;
    const int arow = mt * 16 + a - mg * 64;
    const int mbase = mt * 16 + kg * 4;

    auto run = [&](const unsigned short* Vb, size_t Vbs_, int KPB, int KK,
                   int AOFFe, int outoff) {
        f32x4 acc[13];
#pragma unroll
        for (int nt = 0; nt < 13; ++nt) acc[nt] = (f32x4){0.f, 0.f, 0.f, 0.f};
        const char* Bbase = (const char*)(Vb + (size_t)b * Vbs_);
        auto stageB = [&](int kk) {
            char* dst0 = &bbuf[kk & 1][0];
            const int cnt = NTN * 64;
#pragma unroll
            for (int c = 0; c < 4; ++c) {
                int idx = tid + c * 256;
                if (idx < cnt) {
                    int lrow = idx >> 2, u = idx & 3;
                    int grow = NT0 * 16 + lrow;
                    gas_void* src = (gas_void*)(Bbase + (size_t)grow * (KPB * 2) +
                                                kk * 64 + u * 16);
                    __builtin_amdgcn_global_load_lds(src,
                        (las_void*)(dst0 + (size_t)idx * 16), 16, 0, 0);
                }
            }
        };
        stageB(0);
        __syncthreads();
        for (int kk = 0; kk < KK; ++kk) {
            if (kk + 1 < KK) stageB(kk + 1);
            bf16x8 Af = *(const bf16x8*)&xsA[arow * KPS + AOFFe + kk * 32 + kg * 8];
            const char* bb = &bbuf[kk & 1][0];
#pragma unroll
            for (int nt = 0; nt < 13; ++nt) {
                if (nt >= NT0 && nt < NT0 + NTN) {
                    bf16x8 Bf = *(const bf16x8*)(bb + ((nt - NT0) * 16 + a) * 64 + kg * 16);
                    acc[nt] = __builtin_amdgcn_mfma_f32_16x16x32_bf16(Af, Bf, acc[nt], 0, 0, 0);
                }
            }
            __syncthreads();
        }
        // epilogue: owned tiles + (last nh) tile-13 zeros; zero pads col>=196
#pragma unroll
        for (int nt = 0; nt < 13; ++nt) {
            if (nt < NT0 || nt >= NT0 + NTN) continue;
            int col = nt * 16 + a;
#pragma unroll
            for (int j = 0; j < 4; ++j) {
                int row = mbase + j;
                if (row < MROWS) {
                    unsigned short h = (col < 196) ? f2bf(acc[nt][j]) : (unsigned short)0;
                    F[(size_t)b * Fbs + (size_t)row * 448 + outoff + col] = h;
                }
            }
        }
        if (nh == NS - 1) {
            int col = 208 + a;
#pragma unroll
            for (int j = 0; j < 4; ++j) {
                int row = mbase + j;
                if (row < MROWS)
                    F[(size_t)b * Fbs + (size_t)row * 448 + outoff + col] = 0;
            }
        }
    };
    run(V1, V1bs, 128, 4, 0, 0);
    run(V2, V2bs, 64, 2, 128, 224);
}

// ---------------- rowsum for finale ----------------
__global__ void k_rowsum(const float* __restrict__ cms, float* __restrict__ rs) {
    int oc = blockIdx.x, b = blockIdx.y;
    int lane = threadIdx.x;
    const float* p = cms + ((size_t)b * 173 + oc) * 196;
    float s = 0.f;
    for (int j = lane; j < 196; j += 64) s += p[j];
    for (int sh = 32; sh; sh >>= 1) s += __shfl_xor(s, sh);
    if (lane == 0) rs[(size_t)b * 173 + oc] = s;
}

// ---------------- transpose of 4 [196,196] matrices ----------------
struct P8 { const float* p[4]; };
__global__ void k_transpose4(P8 ws_in, float* __restrict__ wt) {
    int i = blockIdx.x, m = blockIdx.y;
    const float* w = ws_in.p[m];
    float* o = wt + (size_t)m * 38416;
    for (int t = threadIdx.x; t < 196; t += blockDim.x)
        o[(size_t)i * 196 + t] = w[(size_t)t * 196 + i];
}

// ---------------- BN ----------------
__global__ void k_bn_stats(const float* __restrict__ y, float* __restrict__ stats,
                           int C) {
    int ch = blockIdx.x; int tid = threadIdx.x;
    float s = 0.f, s2 = 0.f;
    for (int b = 0; b < 32; ++b) {
        const float* p = &y[(size_t)(b * C + ch) * 196];
        for (int i = tid; i < 196; i += 256) { float v = p[i]; s += v; s2 += v * v; }
    }
    __shared__ float r1[4], r2[4];
    for (int sh = 32; sh; sh >>= 1) { s += __shfl_xor(s, sh); s2 += __shfl_xor(s2, sh); }
    if ((tid & 63) == 0) { r1[tid >> 6] = s; r2[tid >> 6] = s2; }
    __syncthreads();
    if (tid == 0) {
        float S = r1[0] + r1[1] + r1[2] + r1[3];
        float S2 = r2[0] + r2[1] + r2[2] + r2[3];
        float m = S / 6272.f;
        float v = S2 / 6272.f - m * m;
        stats[2 * ch] = m;
        stats[2 * ch + 1] = rsqrtf(v + 1e-5f);
    }
}

__global__ void k_bn_apply_relu(float* __restrict__ y, const float* __restrict__ stats,
                                const float* __restrict__ g, const float* __restrict__ be,
                                float* __restrict__ fT, unsigned short* __restrict__ xtc,
                                int C) {
    int idx = blockIdx.x;
    int ch = idx % C, b = idx / C;
    int s = threadIdx.x;
    if (s < 196) {
        float m = stats[2 * ch], r = stats[2 * ch + 1];
        float v = y[(size_t)idx * 196 + s];
        float o = fmaxf((v - m) * r * g[ch] + be[ch], 0.f);
        y[(size_t)idx * 196 + s] = o;
        if (fT) fT[((size_t)b * 196 + s) * C + ch] = o;
        if (xtc) {
            int G = C >> 6, gch = ch >> 6, cc = ch & 63;
            xtc[(((size_t)b * G + gch) * 208 + s) * 72 + cc] = f2bf(o);
        }
    }
}

// ---------------- catnum ----------------
__global__ void k_catnum(const float* __restrict__ inp, int A,
                         const float* __restrict__ w, const float* __restrict__ bias,
                         const float* __restrict__ g, const float* __restrict__ be,
                         float* __restrict__ outv) {
    int j = blockIdx.x;
    int lane = threadIdx.x;
    float v = 0.f;
    if (lane < 32) {
        v = bias[j];
        for (int k = 0; k < A; ++k) v += inp[lane * A + k] * w[j * A + k];
    }
    float s = (lane < 32) ? v : 0.f;
    float s2 = (lane < 32) ? v * v : 0.f;
    for (int m = 16; m; m >>= 1) { s += __shfl_xor(s, m, 32); s2 += __shfl_xor(s2, m, 32); }
    if (lane < 32) {
        float mean = s / 32.f;
        float var = s2 / 32.f - mean * mean;
        float rstd = rsqrtf(var + 1e-5f);
        float t = (v - mean) * rstd * g[j] + be[j];
        t = t / (1.f + expf(-t));
        outv[lane * 196 + j] = t;
    }
}

__global__ void k_textbuild(const float* __restrict__ toh, const float* __restrict__ tnm,
                            float* __restrict__ text, float* __restrict__ textT) {
    int idx = blockIdx.x;
    int b = idx / 45, c = idx - b * 45;
    int s = threadIdx.x;
    if (s < 196) {
        float v = (c < 30) ? toh[b * 196 + s] : tnm[b * 196 + s];
        text[(size_t)idx * 196 + s] = v;
        textT[((size_t)b * 196 + s) * 45 + c] = v;
    }
}

// ---------------- GCN dist (multi-row) ----------------
template <int C, int ROWS>
__global__ void k_gcn_dist_t(const float* __restrict__ f, const float* __restrict__ fT,
                             float* __restrict__ dist) {
    __shared__ float fi[ROWS][196];
    const int i0 = blockIdx.x * ROWS, b = blockIdx.y;
    const int tid = threadIdx.x;
    for (int idx = tid; idx < ROWS * 196; idx += 256) {
        int r = idx / 196, n = idx - r * 196;
        fi[r][n] = f[((size_t)(b * C + i0 + r)) * 196 + n];
    }
    __syncthreads();
    if (tid < C) {
        const float* ft = fT + (size_t)b * 196 * C + tid;
        float a[ROWS];
#pragma unroll
        for (int r = 0; r < ROWS; ++r) a[r] = 0.f;
#pragma unroll 4
        for (int n = 0; n < 196; ++n) {
            float v = ft[(size_t)n * C];
#pragma unroll
            for (int r = 0; r < ROWS; ++r) a[r] += fabsf(fi[r][n] - v);
        }
#pragma unroll
        for (int r = 0; r < ROWS; ++r)
            dist[((size_t)(b * C + i0 + r)) * C + tid] = expf(-a[r]);
    }
}

// ---------------- GCN spmm+fin (multi-row) ----------------
template <int C, int ROWS>
__global__ void k_gcn_spmmfin_t(const float* __restrict__ dist, const float* __restrict__ f,
                                const float* __restrict__ wt, const float* __restrict__ bias,
                                float* __restrict__ outp) {
    __shared__ float ds[ROWS][C];
    __shared__ float ts[ROWS][196];
    const int i0 = blockIdx.x * ROWS, b = blockIdx.y;
    const int tid = threadIdx.x;
    for (int idx = tid; idx < ROWS * C; idx += 256) {
        int r = idx / C, j = idx - r * C;
        ds[r][j] = dist[((size_t)(b * C + i0 + r)) * C + j];
    }
    __syncthreads();
    if (tid < 196) {
        float a[ROWS];
#pragma unroll
        for (int r = 0; r < ROWS; ++r) a[r] = 0.f;
#pragma unroll 4
        for (int j = 0; j < C; ++j) {
            float v = f[((size_t)b * C + j) * 196 + tid];
#pragma unroll
            for (int r = 0; r < ROWS; ++r) a[r] += ds[r][j] * v;
        }
#pragma unroll
        for (int r = 0; r < ROWS; ++r) ts[r][tid] = a[r];
    }
    __syncthreads();
    if (tid < 196) {
        float a[ROWS];
        float bi = bias[tid];
#pragma unroll
        for (int r = 0; r < ROWS; ++r) a[r] = bi;
#pragma unroll 4
        for (int n = 0; n < 196; ++n) {
            float wv = wt[(size_t)n * 196 + tid];
#pragma unroll
            for (int r = 0; r < ROWS; ++r) a[r] += ts[r][n] * wv;
        }
#pragma unroll
        for (int r = 0; r < ROWS; ++r) {
            size_t rr = ((size_t)(b * C + i0 + r)) * 196 + tid;
            outp[rr] = fmaxf(a[r], 0.f) + f[rr];
        }
    }
}

// ---------------- LN + relu(linear), emits Kcat (pad-zeroed) + transposed ---
template <int R, int ROWS, int KOFF, int TS>
__global__ void k_lnlin2(const float* __restrict__ x, const float* __restrict__ g,
                         const float* __restrict__ be, const float* __restrict__ eT,
                         const float* __restrict__ eb, float* __restrict__ lnout,
                         unsigned short* __restrict__ kcat,
                         unsigned short* __restrict__ tbuf) {
    __shared__ float ls[ROWS][196];
    const int i0 = blockIdx.x * ROWS, b = blockIdx.y;
    const int tid = threadIdx.x;
    const int wv = tid >> 6, lane = tid & 63;
    for (int idx = tid; idx < ROWS * 196; idx += 256) {
        int r = idx / 196, n = idx - r * 196;
        ls[r][n] = x[((size_t)(b * R + i0 + r)) * 196 + n];
    }
    __syncthreads();
    for (int k = 0;; ++k) {
        int r = wv + 4 * k;
        if (r >= ROWS) break;
        float s = 0.f, s2 = 0.f;
        for (int j = lane; j < 196; j += 64) { float v = ls[r][j]; s += v; s2 += v * v; }
        for (int sh = 32; sh; sh >>= 1) { s += __shfl_xor(s, sh); s2 += __shfl_xor(s2, sh); }
        float mean = s / 196.f;
        float var = s2 / 196.f - mean * mean;
        float rstd = rsqrtf(var + 1e-6f);
        size_t rowo = ((size_t)(b * R + i0 + r)) * 196;
        for (int j = lane; j < 196; j += 64) {
            float l = (ls[r][j] - mean) * rstd * g[j] + be[j];
            ls[r][j] = l;
            lnout[rowo + j] = l;
        }
    }
    __syncthreads();
    if (tid < 224) {
        float a[ROWS];
        if (tid < 196) {
            float bi = eb[tid];
#pragma unroll
            for (int r = 0; r < ROWS; ++r) a[r] = bi;
#pragma unroll 4
            for (int n = 0; n < 196; ++n) {
                float ev = eT[(size_t)n * 196 + tid];
#pragma unroll
                for (int r = 0; r < ROWS; ++r) a[r] += ls[r][n] * ev;
            }
        }
#pragma unroll
        for (int r = 0; r < ROWS; ++r) {
            unsigned short h = 0;
            if (tid < 196) h = f2bf(fmaxf(a[r], 0.f));
            kcat[((size_t)(b * 208 + KOFF + i0 + r)) * 224 + tid] = h;
            if (tid < 196) tbuf[((size_t)(b * 208 + tid)) * TS + (i0 + r)] = h;
        }
    }
}

// ---------------- final classifier ----------------
__global__ void k_finale(const float* __restrict__ toh, const float* __restrict__ tnm,
                         const float* __restrict__ rowsum, const float* __restrict__ cls_w,
                         const float* __restrict__ cls_b, float* __restrict__ out) {
    int b = blockIdx.x;
    __shared__ float r1[4], r2[4];
    int tid = threadIdx.x;
    float a = (tid < 196) ? toh[b * 196 + tid] : 0.f;
    float c = (tid < 196) ? tnm[b * 196 + tid] : 0.f;
    for (int sh = 32; sh; sh >>= 1) { a += __shfl_xor(a, sh); c += __shfl_xor(c, sh); }
    if ((tid & 63) == 0) { r1[tid >> 6] = a; r2[tid >> 6] = c; }
    __syncthreads();
    if (tid < 2) {
        float soh = r1[0] + r1[1] + r1[2] + r1[3];
        float snm = r2[0] + r2[1] + r2[2] + r2[3];
        const float* wrow = &cls_w[tid * 218];
        float acc = cls_b[tid];
        float w1 = 0.f, w2 = 0.f;
        for (int k = 0; k < 30; ++k) w1 += wrow[k];
        for (int k = 30; k < 45; ++k) w2 += wrow[k];
        acc += soh * w1 + snm * w2;
        for (int k = 0; k < 173; ++k) acc += wrow[45 + k] * rowsum[(size_t)b * 173 + k];
        out[b * 2 + tid] = acc;
    }
}

// ---------------------------------------------------------------------------
extern "C" void kernel_launch(void* const* d_in, const int* in_sizes, int n_in,
                              void* d_out, int out_size, void* d_ws, size_t ws_size,
                              hipStream_t stream) {
    const float* x      = (const float*)d_in[0];
    const float* oneHot = (const float*)d_in[1];
    const float* num    = (const float*)d_in[2];
    const float* c1_w1  = (const float*)d_in[3];
    const float* c1_g1  = (const float*)d_in[5];
    const float* c1_be1 = (const float*)d_in[6];
    const float* c1_w2  = (const float*)d_in[7];
    const float* c1_g2  = (const float*)d_in[9];
    const float* c1_be2 = (const float*)d_in[10];
    const float* oh_w   = (const float*)d_in[11];
    const float* oh_b   = (const float*)d_in[12];
    const float* oh_g   = (const float*)d_in[13];
    const float* oh_be  = (const float*)d_in[14];
    const float* nm_w   = (const float*)d_in[15];
    const float* nm_b   = (const float*)d_in[16];
    const float* nm_g   = (const float*)d_in[17];
    const float* nm_be  = (const float*)d_in[18];
    const float* gm1_w  = (const float*)d_in[19];
    const float* gm1_b  = (const float*)d_in[20];
    const float* gm2_w  = (const float*)d_in[21];
    const float* gm2_b  = (const float*)d_in[22];
    const float* ln1_g  = (const float*)d_in[23];
    const float* ln1_b  = (const float*)d_in[24];
    const float* ln2_g  = (const float*)d_in[25];
    const float* ln2_b  = (const float*)d_in[26];
    const float* e1_w   = (const float*)d_in[27];
    const float* e1_b   = (const float*)d_in[28];
    const float* e2_w   = (const float*)d_in[29];
    const float* e2_b   = (const float*)d_in[30];
    const float* f1_w   = (const float*)d_in[31];
    const float* f1_b   = (const float*)d_in[32];
    const float* f2_w   = (const float*)d_in[33];
    const float* f2_b   = (const float*)d_in[34];
    const float* f3_w   = (const float*)d_in[35];
    const float* f3_b   = (const float*)d_in[36];
    const float* f4_w   = (const float*)d_in[37];
    const float* f4_b   = (const float*)d_in[38];
    const float* cm_w   = (const float*)d_in[39];
    const float* cm_b   = (const float*)d_in[40];
    const float* cmf_w  = (const float*)d_in[41];
    const float* cmf_b  = (const float*)d_in[42];
    const float* cls_w  = (const float*)d_in[43];
    const float* cls_b  = (const float*)d_in[44];
    float* out = (float*)d_out;
    float* W = (float*)d_ws;

    const size_t L = 802816;
    const size_t T = 282240;
    const size_t F3 = 1085056;
    // ---- layout (floats); live ranges as in r15 (verified) ----
    const size_t o_A    = 0;
    const size_t o_B    = L;
    const size_t o_C    = 2 * L;
    const size_t o_part = 3 * L;
    const size_t o_Kcat = 3 * L;              // bf16 [32][208][224]
    const size_t o_iqT  = o_Kcat + 745472;    // bf16 [32][208][128]
    const size_t o_t1   = 4 * L + T;
    const size_t o_t3   = 4 * L + 2 * T;
    const size_t o_ln2  = 4 * L + 3 * T;
    const size_t o_toh  = 4 * L + 4 * T;
    const size_t o_tnm  = o_toh + 6272;
    const size_t o_st   = o_tnm + 6272;
    const size_t o_wT   = o_st + 1024;
    const size_t o_feat = o_wT + 8 * 38416;
    const size_t o_q    = o_feat + F3;
    const size_t o_Fimg = o_q;                // bf16 [32][128][448]
    const size_t o_dd   = o_q + F3;
    const size_t o_d1   = o_dd;
    const size_t o_d2   = o_dd + 524288;
    const size_t o_tqT  = o_dd;               // bf16 [32][208][64]
    const size_t o_wcI  = o_dd + 212992;
    const size_t o_wcT  = o_wcI + 46592;
    const size_t o_pbf  = o_dd;
    const size_t o_rs   = o_dd;
    const size_t o_qbf  = o_dd + 745472;
    const size_t o_Ftxt = o_qbf;              // bf16 [32][48][448]
    const size_t o_wcm  = o_qbf + 630784;
    const size_t o_wcmf = o_wcm + 16896;
    const size_t o_ftb  = o_wcmf + 16896;
    const size_t o_tr   = o_ftb + 638976;
    const size_t o_Pimg = o_tr;
    const size_t o_Ptxt = o_tr + 393216;
    const size_t o_qtb  = o_tr;
    const size_t o_feab = o_qtb + 638976;
    const size_t o_xt1 = o_dd;
    const size_t o_xt2 = o_xt1 + 1198080;
    const size_t o_wp1 = o_xt2 + 479232;
    const size_t o_wp2 = o_wp1 + 552960;

    float* part = W + o_part;
    unsigned short* xt1 = (unsigned short*)(W + o_xt1);
    unsigned short* xt2 = (unsigned short*)(W + o_xt2);
    unsigned short* wp1 = (unsigned short*)(W + o_wp1);
    unsigned short* wp2 = (unsigned short*)(W + o_wp2);
    unsigned short* kcatb = (unsigned short*)(W + o_Kcat);
    unsigned short* iqTb = (unsigned short*)(W + o_iqT);
    unsigned short* tqTb = (unsigned short*)(W + o_tqT);
    unsigned short* wcatI = (unsigned short*)(W + o_wcI);
    unsigned short* wcatT = (unsigned short*)(W + o_wcT);
    unsigned short* Fimg = (unsigned short*)(W + o_Fimg);
    unsigned short* Ftxt = (unsigned short*)(W + o_Ftxt);
    unsigned short* Pimg = (unsigned short*)(W + o_Pimg);
    unsigned short* Ptxt = (unsigned short*)(W + o_Ptxt);
    unsigned short* ftb = (unsigned short*)(W + o_ftb);
    unsigned short* qtb = (unsigned short*)(W + o_qtb);
    unsigned short* feab = (unsigned short*)(W + o_feab);
    unsigned short* qbf = (unsigned short*)(W + o_qbf);
    unsigned short* wcmb = (unsigned short*)(W + o_wcm);
    unsigned short* wcmfb = (unsigned short*)(W + o_wcmf);
    unsigned short* pbf = (unsigned short*)(W + o_pbf);
    float* gm1T = W + o_wT + 0 * 38416;
    float* gm2T = W + o_wT + 1 * 38416;
    float* e1T  = W + o_wT + 2 * 38416;
    float* e2T  = W + o_wT + 3 * 38416;

    // ---- conv prep ----
    k_wpack<<<(27 * 128 * 40 + 255) / 256, 256, 0, stream>>>(c1_w1, wp1, 320);
    k_wpack<<<(27 * 128 * 16 + 255) / 256, 256, 0, stream>>>(c1_w2, wp2, 128);
    k_xt_c<<<dim3((5 * 208 * 36 + 255) / 256, 32), 256, 0, stream>>>(x, xt1, 320, 5);

    // ---- conv1 ----
    k_convchunk4<320, 5, 4, 2><<<dim3(20, 32), 256, 0, stream>>>(xt1, wp1, part);
    k_reduceG<5><<<3136, 256, 0, stream>>>(part, W + o_A, 802816);
    k_bn_stats<<<128, 256, 0, stream>>>(W + o_A, W + o_st, 128);
    k_bn_apply_relu<<<4096, 256, 0, stream>>>(W + o_A, W + o_st, c1_g1, c1_be1,
                                              nullptr, xt2, 128);

    // ---- conv2 (BN emits fTimg at o_tr) ----
    k_convchunk4<128, 2, 2, 4><<<dim3(16, 32), 256, 0, stream>>>(xt2, wp2, part);
    k_reduceG<2><<<3136, 256, 0, stream>>>(part, W + o_B, 802816);
    k_bn_stats<<<128, 256, 0, stream>>>(W + o_B, W + o_st + 512, 128);
    k_bn_apply_relu<<<4096, 256, 0, stream>>>(W + o_B, W + o_st + 512, c1_g2, c1_be2,
                                              W + o_tr, nullptr, 128);

    // ---- conv scratch dead: CMSA weight packs + zero ftb ----
    k_w173<<<(176 * 192 + 255) / 256, 256, 0, stream>>>(cm_w, wcmb);
    k_w173<<<(176 * 192 + 255) / 256, 256, 0, stream>>>(cmf_w, wcmfb);
    k_zero4<<<(638976 / 4 + 255) / 256, 256, 0, stream>>>((float4*)(W + o_ftb), 638976 / 4);

    // ---- weight transposes ----
    P8 p8;
    p8.p[0] = gm1_w; p8.p[1] = gm2_w; p8.p[2] = e1_w; p8.p[3] = e2_w;
    k_transpose4<<<dim3(196, 4), 256, 0, stream>>>(p8, W + o_wT);

    // ---- catnum / text ----
    k_catnum<<<196, 64, 0, stream>>>(oneHot, 24, oh_w, oh_b, oh_g, oh_be, W + o_toh);
    k_catnum<<<196, 64, 0, stream>>>(num, 11, nm_w, nm_b, nm_g, nm_be, W + o_tnm);
    k_textbuild<<<32 * 45, 256, 0, stream>>>(W + o_toh, W + o_tnm, W + o_t1, W + o_tr + L);

    // ---- GCN img / txt ----
    k_gcn_dist_t<128, 4><<<dim3(32, 32), 256, 0, stream>>>(W + o_B, W + o_tr, W + o_d1);
    k_gcn_spmmfin_t<128, 4><<<dim3(32, 32), 256, 0, stream>>>(W + o_d1, W + o_B, gm1T,
                                                              gm1_b, W + o_C);
    k_gcn_dist_t<45, 3><<<dim3(15, 32), 256, 0, stream>>>(W + o_t1, W + o_tr + L, W + o_d2);
    k_gcn_spmmfin_t<45, 3><<<dim3(15, 32), 256, 0, stream>>>(W + o_d2, W + o_t1, gm2T,
                                                             gm2_b, W + o_t3);

    // ---- dists dead: zero tqT (NaN-hazard in cols 45..63) + pack Wcats ----
    k_zero4<<<(212992 / 4 + 255) / 256, 256, 0, stream>>>((float4*)(W + o_tqT),
                                                          212992 / 4);
    k_wcat<<<(208 * 448 + 255) / 256, 256, 0, stream>>>(f1_w, f3_w, wcatI);
    k_wcat<<<(208 * 448 + 255) / 256, 256, 0, stream>>>(f4_w, f2_w, wcatT);

    // ---- LN + q projections -> Kcat (pad-zeroed) / iqT / tqT ----
    k_lnlin2<128, 4, 0, 128><<<dim3(32, 32), 256, 0, stream>>>(
        W + o_C, ln1_g, ln1_b, e1T, e1_b, W + o_B, kcatb, iqTb);
    k_lnlin2<45, 3, 128, 64><<<dim3(15, 32), 256, 0, stream>>>(
        W + o_t3, ln2_g, ln2_b, e2T, e2_b, W + o_ln2, kcatb, tqTb);

    // ---- attention: scores + dual softmax -> P ----
    k_agemm<128, 8, 224, 224, 7, 5, 1, 1><<<dim3(2, 32), 256, 0, stream>>>(
        kcatb, (size_t)208 * 224, kcatb, (size_t)208 * 224,
        nullptr, nullptr, nullptr, nullptr, Pimg, 192, (size_t)128 * 192,
        nullptr, nullptr, 0);
    k_agemm<45, 3, 224, 224, 7, 5, 1, 1><<<dim3(1, 32), 256, 0, stream>>>(
        kcatb + 128 * 224, (size_t)208 * 224, kcatb, (size_t)208 * 224,
        nullptr, nullptr, nullptr, nullptr, Ptxt, 192, (size_t)48 * 192,
        nullptr, nullptr, 0);

    // ---- attention: merged PV (both halves, self-zeroing pads) ----
    k_pv<128, 8, 2><<<dim3(4, 32), 256, 0, stream>>>(
        Pimg, (size_t)128 * 192, iqTb, (size_t)208 * 128, tqTb, (size_t)208 * 64,
        Fimg, (size_t)128 * 448);
    k_pv<45, 3, 2><<<dim3(2, 32), 256, 0, stream>>>(
        Ptxt, (size_t)48 * 192, iqTb, (size_t)208 * 128, tqTb, (size_t)208 * 64,
        Ftxt, (size_t)48 * 448);

    // ---- attention: projection + residuals -> feat + ftb (N-split) ----
    k_agemm<128, 8, 448, 448, 14, 4, 0, 2><<<dim3(4, 32), 256, 0, stream>>>(
        Fimg, (size_t)128 * 448, wcatI, 0,
        f1_b, f3_b, W + o_B, W + o_C, nullptr, 0, 0, W + o_feat, ftb, 0);
    k_agemm<45, 3, 448, 448, 14, 4, 0, 2><<<dim3(2, 32), 256, 0, stream>>>(
        Ftxt, (size_t)48 * 448, wcatT, 0,
        f2_b, f4_b, W + o_ln2, W + o_t3, nullptr, 0, 0, W + o_feat, ftb, 128);

    // ---- attention buffers dead: CMSA prep ----
    k_zero4<<<(1277952 / 4 + 255) / 256, 256, 0, stream>>>((float4*)(W + o_qtb),
                                                           1277952 / 4);
    k_zero4<<<(630784 / 4 + 255) / 256, 256, 0, stream>>>((float4*)(W + o_qbf),
                                                          630784 / 4);
    k_zero4<<<(745472 / 4 + 255) / 256, 256, 0, stream>>>((float4*)(W + o_pbf),
                                                          745472 / 4);

    // ---- CMSA via MFMA GEMMs (N-split on non-softmax) ----
    k_bgemm<176, 11, 192, 6, 0, 2><<<dim3(6, 32), 256, 0, stream>>>(
        wcmb, 0, ftb, (size_t)208 * 192, cm_b, qbf, qtb, nullptr, nullptr);
    k_bgemm<208, 13, 192, 6, 1, 1><<<dim3(4, 32), 256, 0, stream>>>(
        qtb, (size_t)208 * 192, qtb, (size_t)208 * 192, nullptr, pbf, nullptr,
        nullptr, nullptr);
    k_bgemm<176, 11, 224, 7, 2, 2><<<dim3(6, 32), 256, 0, stream>>>(
        qbf, (size_t)176 * 224, pbf, (size_t)208 * 224, nullptr, feab, nullptr,
        nullptr, nullptr);
    k_bgemm<176, 11, 192, 6, 3, 2><<<dim3(6, 32), 256, 0, stream>>>(
        wcmfb, 0, feab, (size_t)208 * 192, cmf_b, nullptr, nullptr,
        W + o_feat, W + o_q);

    // ---- rowsum + final classifier ----
    k_rowsum<<<dim3(173, 32), 64, 0, stream>>>(W + o_q, W + o_rs);
    k_finale<<<32, 256, 0, stream>>>(W + o_toh, W + o_tnm, W + o_rs, cls_w, cls_b, out);
}

// Round 18
// 432.210 us; speedup vs baseline: 1.1251x; 1.0396x over previous
//
#include <hip/hip_runtime.h>
#include <hip/hip_bf16.h>

// ---------------------------------------------------------------------------
// mv3Dunet_down_text_cmsa forward. Round 18: r17 determinism fix (no float
// atomics — per-batch BN partials summed in fixed order) and GCN dist
// computed from fp32 fT (bf16 only as MFMA operands). GCN-img MFMA + fused
// BN kept.
// ---------------------------------------------------------------------------

using bf16x8 = __attribute__((ext_vector_type(8))) short;
using f32x4  = __attribute__((ext_vector_type(4))) float;

typedef const __attribute__((address_space(1))) void gas_void;
typedef __attribute__((address_space(3))) void las_void;

__device__ __forceinline__ unsigned short f2bf(float f) {
    unsigned int u = __float_as_uint(f);
    u += 0x7FFFu + ((u >> 16) & 1u);
    return (unsigned short)(u >> 16);
}

// ---------------- zero helper ----------------
__global__ void k_zero4(float4* __restrict__ p, int n4) {
    int i = blockIdx.x * 256 + threadIdx.x;
    if (i < n4) p[i] = (float4){0.f, 0.f, 0.f, 0.f};
}

// ---------------- X -> chunk-major bf16: xt[b][g][208][72] ----------------
__global__ void k_xt_c(const float* __restrict__ x, unsigned short* __restrict__ xt,
                       int IC, int G) {
    int b = blockIdx.y;
    int tot = G * 208 * 36;
    int idx = blockIdx.x * 256 + threadIdx.x;
    if (idx >= tot) return;
    int g = idx / (208 * 36); int r = idx - g * 208 * 36;
    int s = r / 36, cp = r - s * 36;
    int cc = cp * 2;
    int ic = g * 64 + cc;
    unsigned int lo = 0, hi = 0;
    if (s < 196 && cc < 64 && ic < IC)         lo = f2bf(x[((size_t)b * IC + ic) * 196 + s]);
    if (s < 196 && cc + 1 < 64 && ic + 1 < IC) hi = f2bf(x[((size_t)b * IC + ic + 1) * 196 + s]);
    ((unsigned int*)xt)[(size_t)b * tot + idx] = lo | (hi << 16);
}

// ---------------- weight pack ----------------
__global__ void k_wpack(const float* __restrict__ w, unsigned short* __restrict__ wp,
                        int IC) {
    int nc = IC >> 3;
    int idx = blockIdx.x * 256 + threadIdx.x;
    if (idx >= 27 * 128 * nc) return;
    int c = idx % nc; int r = idx / nc; int oc = r & 127; int t = r >> 7;
    const float* ws = w + ((size_t)oc * IC + c * 8) * 27 + t;
    unsigned int o0 = f2bf(ws[0])   | ((unsigned int)f2bf(ws[27])  << 16);
    unsigned int o1 = f2bf(ws[54])  | ((unsigned int)f2bf(ws[81])  << 16);
    unsigned int o2 = f2bf(ws[108]) | ((unsigned int)f2bf(ws[135]) << 16);
    unsigned int o3 = f2bf(ws[162]) | ((unsigned int)f2bf(ws[189]) << 16);
    uint4 v; v.x = o0; v.y = o1; v.z = o2; v.w = o3;
    ((uint4*)wp)[idx] = v;
}

// ---------------- pack 173x173 f32 -> [176][192] bf16 zero-padded -----------
__global__ void k_w173(const float* __restrict__ w, unsigned short* __restrict__ wb) {
    int idx = blockIdx.x * 256 + threadIdx.x;
    if (idx >= 176 * 192) return;
    int oc = idx / 192, c = idx - oc * 192;
    wb[idx] = (oc < 173 && c < 173) ? f2bf(w[(size_t)oc * 173 + c]) : (unsigned short)0;
}

// ---------------- generic pad pack [R][Cc] f32 -> [OR][OC2] bf16 -------------
__global__ void k_wpad(const float* __restrict__ w, unsigned short* __restrict__ wb,
                       int R, int Cc, int OR, int OC2) {
    int idx = blockIdx.x * 256 + threadIdx.x;
    if (idx >= OR * OC2) return;
    int r = idx / OC2, c = idx - r * OC2;
    wb[idx] = (r < R && c < Cc) ? f2bf(w[(size_t)r * Cc + c]) : (unsigned short)0;
}

// ---------------- pack Wcat[208][448]: [wA | pad | wB | pad] ----------------
__global__ void k_wcat(const float* __restrict__ wA, const float* __restrict__ wB,
                       unsigned short* __restrict__ outw) {
    int idx = blockIdx.x * 256 + threadIdx.x;
    if (idx >= 208 * 448) return;
    int n = idx / 448, k = idx - n * 448;
    unsigned short v = 0;
    if (n < 196) {
        if (k < 196) v = f2bf(wA[(size_t)n * 196 + k]);
        else if (k >= 224 && k < 420) v = f2bf(wB[(size_t)n * 196 + (k - 224)]);
    }
    outw[idx] = v;
}

// ---------------- MFMA conv (validated) ----------------
template <int IC, int G, int NT, int NH>
__global__ __launch_bounds__(256, 3) void k_convchunk4(
    const unsigned short* __restrict__ xt, const unsigned short* __restrict__ wp,
    float* __restrict__ part) {
    __shared__ unsigned short xs[208 * 72];
    __shared__ char bbuf[2][NT * 2048];
    const int tid = threadIdx.x;
    const int bx = blockIdx.x, b = blockIdx.y;
    const int mh = bx & 1;
    const int nh = (bx >> 1) % NH;
    const int g  = (bx >> 1) / NH;
    const int w = tid >> 6, l = tid & 63;

    {
        const bf16x8* s8 = (const bf16x8*)(xt + ((size_t)b * G + g) * (208 * 72));
        bf16x8* d8 = (bf16x8*)xs;
        for (int c = tid; c < 208 * 72 / 8; c += 256) d8[c] = s8[c];
    }

    const char* wslice = (const char*)wp +
                         ((size_t)(nh * NT * 16) * IC + (size_t)g * 64) * 2;
    auto stageB = [&](int t) {
        char* dst = &bbuf[t & 1][w * (NT * 512)];
        const char* wt_ = wslice + (size_t)t * 128 * IC * 2;
#pragma unroll
        for (int c = 0; c < NT / 2; ++c) {
            int q = w * (NT * 512) + c * 1024 + l * 16;
            int row = q >> 7, col = q & 127;
            int scol = col ^ ((row & 7) << 4);
            gas_void* src = (gas_void*)(wt_ + (size_t)row * IC * 2 + scol);
            __builtin_amdgcn_global_load_lds(src, (las_void*)(dst + c * 1024),
                                             16, 0, 0);
        }
    };

    const int lane = tid & 63;
    const int a = lane & 15, kg = lane >> 4;

    int md[2], mhh[2], mw[2];
#pragma unroll
    for (int i = 0; i < 2; ++i) {
        int m = (mh * 8 + (tid >> 6) * 2 + i) * 16 + a;
        md[i] = m / 49; int rr = m - md[i] * 49;
        mhh[i] = rr / 7; mw[i] = rr - mhh[i] * 7;
    }

    f32x4 acc[2][NT];
#pragma unroll
    for (int i = 0; i < 2; ++i)
#pragma unroll
        for (int nt = 0; nt < NT; ++nt) acc[i][nt] = (f32x4){0.f, 0.f, 0.f, 0.f};

    const bf16x8 zv = {0, 0, 0, 0, 0, 0, 0, 0};

    stageB(0);
    __syncthreads();

    for (int t = 0; t < 27; ++t) {
        if (t < 26) stageB(t + 1);
        const int kd = t / 9, kh = (t / 3) % 3, kw = t % 3;
        int rsrc[2]; bool ok[2];
#pragma unroll
        for (int i = 0; i < 2; ++i) {
            int d2 = md[i] + kd - 1, h2 = mhh[i] + kh - 1, w2 = mw[i] + kw - 1;
            ok[i] = ((unsigned)d2 < 4u) & ((unsigned)h2 < 7u) & ((unsigned)w2 < 7u);
            rsrc[i] = ok[i] ? (d2 * 49 + h2 * 7 + w2) : 0;
        }
        bf16x8 A[2][2];
#pragma unroll
        for (int kk = 0; kk < 2; ++kk)
#pragma unroll
            for (int i = 0; i < 2; ++i) {
                bf16x8 v = *(const bf16x8*)(xs + rsrc[i] * 72 + kk * 32 + kg * 8);
                A[kk][i] = ok[i] ? v : zv;
            }
        const char* bb = &bbuf[t & 1][0];
#pragma unroll
        for (int kk = 0; kk < 2; ++kk)
#pragma unroll
            for (int nt = 0; nt < NT; ++nt) {
                int row = nt * 16 + a;
                int cb = (kk * 64 + kg * 16) ^ ((row & 7) << 4);
                bf16x8 B = *(const bf16x8*)(bb + row * 128 + cb);
#pragma unroll
                for (int i = 0; i < 2; ++i)
                    acc[i][nt] = __builtin_amdgcn_mfma_f32_16x16x32_bf16(
                        A[kk][i], B, acc[i][nt], 0, 0, 0);
            }
        __syncthreads();
    }

    float* dst = part + ((size_t)g * 32 + b) * (128 * 196);
#pragma unroll
    for (int i = 0; i < 2; ++i) {
        int m0 = (mh * 8 + (tid >> 6) * 2 + i) * 16 + kg * 4;
        if (m0 < 196) {
#pragma unroll
            for (int nt = 0; nt < NT; ++nt) {
                int oc = nh * NT * 16 + nt * 16 + a;
                *(f32x4*)(dst + (size_t)oc * 196 + m0) = acc[i][nt];
            }
        }
    }
}

// ---------------- fused partial-reduce + BN stats (deterministic) ----------
// Writes y and per-(ch,b) partial sums to pst[(ch*32+b)*2 + {0,1}].
template <int G, int C>
__global__ void k_reduce_stats(const float* __restrict__ part, float* __restrict__ y,
                               float* __restrict__ pst) {
    const int ch = blockIdx.x, b = blockIdx.y;
    const int tid = threadIdx.x;
    __shared__ float r1[4], r2[4];
    float v = 0.f;
    if (tid < 196) {
#pragma unroll
        for (int g = 0; g < G; ++g)
            v += part[((size_t)(g * 32 + b) * C + ch) * 196 + tid];
        y[((size_t)b * C + ch) * 196 + tid] = v;
    }
    float s = v, s2 = v * v;
    for (int sh = 32; sh; sh >>= 1) { s += __shfl_xor(s, sh); s2 += __shfl_xor(s2, sh); }
    if ((tid & 63) == 0) { r1[tid >> 6] = s; r2[tid >> 6] = s2; }
    __syncthreads();
    if (tid == 0) {
        pst[(ch * 32 + b) * 2]     = r1[0] + r1[1] + r1[2] + r1[3];
        pst[(ch * 32 + b) * 2 + 1] = r2[0] + r2[1] + r2[2] + r2[3];
    }
}

// ---------------- BN apply (sums partials in fixed order) ----------------
__global__ void k_bn_apply2(float* __restrict__ y, const float* __restrict__ pst,
                            const float* __restrict__ g, const float* __restrict__ be,
                            float* __restrict__ fT, unsigned short* __restrict__ fTb,
                            unsigned short* __restrict__ xtc, int C) {
    int idx = blockIdx.x;
    int ch = idx % C, b = idx / C;
    int s = threadIdx.x;
    float S = 0.f, S2 = 0.f;
    for (int b2 = 0; b2 < 32; ++b2) {          // fixed order: deterministic
        S += pst[(ch * 32 + b2) * 2];
        S2 += pst[(ch * 32 + b2) * 2 + 1];
    }
    if (s < 196) {
        float m = S / 6272.f;
        float r = rsqrtf(S2 / 6272.f - m * m + 1e-5f);
        float v = y[(size_t)idx * 196 + s];
        float o = fmaxf((v - m) * r * g[ch] + be[ch], 0.f);
        y[(size_t)idx * 196 + s] = o;
        if (fT) fT[((size_t)b * 196 + s) * C + ch] = o;
        if (fTb) fTb[((size_t)b * 208 + s) * C + ch] = f2bf(o);
        if (xtc) {
            int G = C >> 6, gch = ch >> 6, cc = ch & 63;
            xtc[(((size_t)b * G + gch) * 208 + s) * 72 + cc] = f2bf(o);
        }
    }
}

// ---------------- CMSA/GCN batched MFMA GEMM, N-split ----------------
// EPI 0: q=relu(.+bias[row]) -> qbf + qtb ; EPI 1: row-softmax -> pbf
// EPI 2: -> feab (transposed) ; EPI 3: relu(.+bias[row])+resid -> fp32
// EPI 7: bf16 [b][128][224] row-major, zero col-pads (GCN tmp)
// EPI 8: relu(.+bias[col])+resid -> fp32 [b][128][196] (GCN out)
template <int MROWS, int MTILES, int KP, int KK, int EPI, int NS>
__global__ __launch_bounds__(256, 2) void k_bgemm(
    const unsigned short* __restrict__ Ab, size_t ABS,
    const unsigned short* __restrict__ Bb, size_t BBS,
    const float* __restrict__ bias,
    unsigned short* __restrict__ p0, unsigned short* __restrict__ p1,
    const float* __restrict__ resid, float* __restrict__ outf) {
    constexpr int KPS = KP + 8;
    __shared__ unsigned short xsA[64 * KPS];
    __shared__ char bbuf[2][208 * 64];
    const int tid = threadIdx.x, bx = blockIdx.x, b = blockIdx.y;
    const int wv = tid >> 6, lane = tid & 63, a = lane & 15, kg = lane >> 4;
    const int nh = bx % NS, mg = bx / NS;
    const int NT0 = (NS == 1) ? 0 : nh * 7;
    const int NTN = (NS == 1) ? 13 : ((nh == 0) ? 7 : 6);

    const unsigned short* Abase = Ab + (size_t)b * ABS;
    {
        const int rowu = KP / 2;
        for (int i = tid; i < 64 * rowu; i += 256) {
            int r = i / rowu, cu = i - r * rowu;
            int gr = mg * 64 + r; if (gr > MROWS - 1) gr = MROWS - 1;
            unsigned int v = ((const unsigned int*)(Abase + (size_t)gr * KP))[cu];
            *(unsigned int*)&xsA[r * KPS + cu * 2] = v;
        }
    }
    const char* Bbase = (const char*)(Bb + (size_t)b * BBS);
    auto stageB = [&](int kk) {
        char* dst0 = &bbuf[kk & 1][0];
        const int cnt = NTN * 64;
#pragma unroll
        for (int c = 0; c < 4; ++c) {
            int idx = tid + c * 256;
            if (idx < cnt) {
                int lrow = idx >> 2, u = idx & 3;
                int grow = NT0 * 16 + lrow;
                gas_void* src = (gas_void*)(Bbase + (size_t)grow * (KP * 2) +
                                            kk * 64 + u * 16);
                __builtin_amdgcn_global_load_lds(src, (las_void*)(dst0 + (size_t)idx * 16),
                                                 16, 0, 0);
            }
        }
    };

    int mt = mg * 4 + wv; if (mt > MTILES - 1) mt = MTILES - 1;
    const int arow = mt * 16 + a - mg * 64;

    f32x4 acc[13];
#pragma unroll
    for (int nt = 0; nt < 13; ++nt) acc[nt] = (f32x4){0.f, 0.f, 0.f, 0.f};

    stageB(0);
    __syncthreads();
    for (int kk = 0; kk < KK; ++kk) {
        if (kk + 1 < KK) stageB(kk + 1);
        bf16x8 Af = *(const bf16x8*)&xsA[arow * KPS + kk * 32 + kg * 8];
        const char* bb = &bbuf[kk & 1][0];
#pragma unroll
        for (int nt = 0; nt < 13; ++nt) {
            if (nt >= NT0 && nt < NT0 + NTN) {
                bf16x8 Bf = *(const bf16x8*)(bb + ((nt - NT0) * 16 + a) * 64 + kg * 16);
                acc[nt] = __builtin_amdgcn_mfma_f32_16x16x32_bf16(Af, Bf, acc[nt], 0, 0, 0);
            }
        }
        __syncthreads();
    }

    const int mbase = mt * 16 + kg * 4;
    if (EPI == 0) {
#pragma unroll
        for (int nt = 0; nt < 13; ++nt) {
            if (nt < NT0 || nt >= NT0 + NTN) continue;
            int col = nt * 16 + a;
            if (col < 196) {
#pragma unroll
                for (int j = 0; j < 4; ++j) {
                    int row = mbase + j;
                    if (row < 173) {
                        unsigned short h = f2bf(fmaxf(acc[nt][j] + bias[row], 0.f));
                        p0[((size_t)b * 176 + row) * 224 + col] = h;
                        p1[((size_t)b * 208 + col) * 192 + row] = h;
                    }
                }
            }
        }
    } else if (EPI == 1) {
#pragma unroll
        for (int j = 0; j < 4; ++j) {
            int row = mbase + j;
            float m = -3.4e38f;
#pragma unroll
            for (int nt = 0; nt < 13; ++nt) {
                int col = nt * 16 + a;
                float s = (col < 196) ? acc[nt][j] : -3.4e38f;
                m = fmaxf(m, s);
            }
            for (int msk = 1; msk < 16; msk <<= 1) m = fmaxf(m, __shfl_xor(m, msk));
            float e[13]; float sum = 0.f;
#pragma unroll
            for (int nt = 0; nt < 13; ++nt) {
                int col = nt * 16 + a;
                float v = (col < 196) ? expf(acc[nt][j] - m) : 0.f;
                e[nt] = v; sum += v;
            }
            for (int msk = 1; msk < 16; msk <<= 1) sum += __shfl_xor(sum, msk);
            float inv = 1.f / sum;
            if (row < 196) {
#pragma unroll
                for (int nt = 0; nt < 13; ++nt) {
                    int col = nt * 16 + a;
                    p0[((size_t)b * 208 + row) * 224 + col] = f2bf(e[nt] * inv);
                }
            }
        }
    } else if (EPI == 2) {
#pragma unroll
        for (int nt = 0; nt < 13; ++nt) {
            if (nt < NT0 || nt >= NT0 + NTN) continue;
            int col = nt * 16 + a;
#pragma unroll
            for (int j = 0; j < 4; ++j) {
                int row = mbase + j;
                if (row < 173)
                    p0[((size_t)b * 208 + col) * 192 + row] = f2bf(acc[nt][j]);
            }
        }
    } else if (EPI == 3) {
#pragma unroll
        for (int nt = 0; nt < 13; ++nt) {
            if (nt < NT0 || nt >= NT0 + NTN) continue;
            int col = nt * 16 + a;
            if (col < 196) {
#pragma unroll
                for (int j = 0; j < 4; ++j) {
                    int row = mbase + j;
                    if (row < 173) {
                        size_t rr = ((size_t)b * 173 + row) * 196 + col;
                        outf[rr] = fmaxf(acc[nt][j] + bias[row], 0.f) + resid[rr];
                    }
                }
            }
        }
    } else if (EPI == 7) {
#pragma unroll
        for (int nt = 0; nt < 13; ++nt) {
            if (nt < NT0 || nt >= NT0 + NTN) continue;
            int col = nt * 16 + a;
#pragma unroll
            for (int j = 0; j < 4; ++j) {
                int row = mbase + j;
                unsigned short h = (col < 196) ? f2bf(acc[nt][j]) : (unsigned short)0;
                p0[((size_t)b * 128 + row) * 224 + col] = h;
            }
        }
    } else {  // EPI == 8
#pragma unroll
        for (int nt = 0; nt < 13; ++nt) {
            if (nt < NT0 || nt >= NT0 + NTN) continue;
            int col = nt * 16 + a;
            if (col < 196) {
#pragma unroll
                for (int j = 0; j < 4; ++j) {
                    int row = mbase + j;
                    size_t rr = ((size_t)b * 128 + row) * 196 + col;
                    outf[rr] = fmaxf(acc[nt][j] + bias[col], 0.f) + resid[rr];
                }
            }
        }
    }
}

// ---------------- attention GEMM (scores EPI5 / proj EPI4), N-split --------
template <int MROWS, int MTILES, int KPA, int KPB, int KK, int EPI, int STAGEA, int NS>
__global__ __launch_bounds__(256, 2) void k_agemm(
    const unsigned short* __restrict__ Ab, size_t ABS,
    const unsigned short* __restrict__ Bb, size_t BBS,
    const float* __restrict__ biasA, const float* __restrict__ biasB,
    const float* __restrict__ lnres, const float* __restrict__ res2,
    unsigned short* __restrict__ p0, size_t p0rs, size_t p0bs,
    float* __restrict__ feat, unsigned short* __restrict__ ftb, int cbase) {
    constexpr int KPS = KPA + 8;
    __shared__ unsigned short xsA[STAGEA ? 64 * KPS : 64];
    __shared__ char bbuf[2][208 * 64];
    const int tid = threadIdx.x, bx = blockIdx.x, b = blockIdx.y;
    const int wv = tid >> 6, lane = tid & 63, a = lane & 15, kg = lane >> 4;
    const int nh = bx % NS, mg = bx / NS;
    const int NT0 = (NS == 1) ? 0 : nh * 7;
    const int NTN = (NS == 1) ? 13 : ((nh == 0) ? 7 : 6);

    const unsigned short* Abase = Ab + (size_t)b * ABS;
    if (STAGEA) {
        const int rowu = KPA / 2;
        for (int i = tid; i < 64 * rowu; i += 256) {
            int r = i / rowu, cu = i - r * rowu;
            int gr = mg * 64 + r; if (gr > MROWS - 1) gr = MROWS - 1;
            unsigned int v = ((const unsigned int*)(Abase + (size_t)gr * KPA))[cu];
            *(unsigned int*)&xsA[r * KPS + cu * 2] = v;
        }
    }
    const char* Bbase = (const char*)(Bb + (size_t)b * BBS);
    auto stageB = [&](int kk) {
        char* dst0 = &bbuf[kk & 1][0];
        const int cnt = NTN * 64;
#pragma unroll
        for (int c = 0; c < 4; ++c) {
            int idx = tid + c * 256;
            if (idx < cnt) {
                int lrow = idx >> 2, u = idx & 3;
                int grow = NT0 * 16 + lrow;
                gas_void* src = (gas_void*)(Bbase + (size_t)grow * (KPB * 2) +
                                            kk * 64 + u * 16);
                __builtin_amdgcn_global_load_lds(src, (las_void*)(dst0 + (size_t)idx * 16),
                                                 16, 0, 0);
            }
        }
    };

    int mt = mg * 4 + wv; if (mt > MTILES - 1) mt = MTILES - 1;

    f32x4 acc[13];
#pragma unroll
    for (int nt = 0; nt < 13; ++nt) acc[nt] = (f32x4){0.f, 0.f, 0.f, 0.f};

    stageB(0);
    __syncthreads();
    for (int kk = 0; kk < KK; ++kk) {
        if (kk + 1 < KK) stageB(kk + 1);
        bf16x8 Af;
        if (STAGEA) {
            int arow = mt * 16 + a - mg * 64;
            Af = *(const bf16x8*)&xsA[arow * KPS + kk * 32 + kg * 8];
        } else {
            int gr = mt * 16 + a; if (gr > MROWS - 1) gr = MROWS - 1;
            Af = *(const bf16x8*)(Abase + (size_t)gr * KPA + kk * 32 + kg * 8);
        }
        const char* bb = &bbuf[kk & 1][0];
#pragma unroll
        for (int nt = 0; nt < 13; ++nt) {
            if (nt >= NT0 && nt < NT0 + NTN) {
                bf16x8 Bf = *(const bf16x8*)(bb + ((nt - NT0) * 16 + a) * 64 + kg * 16);
                acc[nt] = __builtin_amdgcn_mfma_f32_16x16x32_bf16(Af, Bf, acc[nt], 0, 0, 0);
            }
        }
        __syncthreads();
    }

    const int mbase = mt * 16 + kg * 4;
    if (EPI == 5) {
#pragma unroll
        for (int j = 0; j < 4; ++j) {
            int row = mbase + j;
            float mA = -3.4e38f, mB = -3.4e38f;
#pragma unroll
            for (int nt = 0; nt < 8; ++nt) mA = fmaxf(mA, acc[nt][j]);
#pragma unroll
            for (int nt = 8; nt < 13; ++nt) {
                int col = nt * 16 + a;
                float s = (col < 173) ? acc[nt][j] : -3.4e38f;
                mB = fmaxf(mB, s);
            }
            for (int msk = 1; msk < 16; msk <<= 1) {
                mA = fmaxf(mA, __shfl_xor(mA, msk));
                mB = fmaxf(mB, __shfl_xor(mB, msk));
            }
            float eA[8], eB[5];
            float sA = 0.f, sB = 0.f;
#pragma unroll
            for (int nt = 0; nt < 8; ++nt) { eA[nt] = expf(acc[nt][j] - mA); sA += eA[nt]; }
#pragma unroll
            for (int nt = 8; nt < 13; ++nt) {
                int col = nt * 16 + a;
                float v = (col < 173) ? expf(acc[nt][j] - mB) : 0.f;
                eB[nt - 8] = v; sB += v;
            }
            for (int msk = 1; msk < 16; msk <<= 1) {
                sA += __shfl_xor(sA, msk);
                sB += __shfl_xor(sB, msk);
            }
            float iA = 1.f / sA, iB = 1.f / sB;
            if (row < MROWS) {
#pragma unroll
                for (int nt = 0; nt < 12; ++nt) {
                    int col = nt * 16 + a;
                    float v = (nt < 8) ? eA[nt] * iA
                                       : ((col < 173) ? eB[nt - 8] * iB : 0.f);
                    p0[(size_t)b * p0bs + (size_t)row * p0rs + col] = f2bf(v);
                }
            }
        }
    } else {  // EPI == 4
#pragma unroll
        for (int nt = 0; nt < 13; ++nt) {
            if (nt < NT0 || nt >= NT0 + NTN) continue;
            int col = nt * 16 + a;
            if (col < 196) {
#pragma unroll
                for (int j = 0; j < 4; ++j) {
                    int row = mbase + j;
                    if (row < MROWS) {
                        size_t rr = ((size_t)b * MROWS + row) * 196 + col;
                        float v = acc[nt][j] + biasA[col] + biasB[col] +
                                  lnres[rr] + res2[rr];
                        feat[((size_t)b * 173 + cbase + row) * 196 + col] = v;
                        ftb[((size_t)(b * 208 + col)) * 192 + cbase + row] = f2bf(v);
                    }
                }
            }
        }
    }
}

// ---------------- PV merged kernel: F = [P_A*V1 | P_B*V2], self-zero pads ---
template <int MROWS, int MTILES, int NS>
__global__ __launch_bounds__(256, 2) void k_pv(
    const unsigned short* __restrict__ P, size_t Pbs,
    const unsigned short* __restrict__ V1, size_t V1bs,
    const unsigned short* __restrict__ V2, size_t V2bs,
    unsigned short* __restrict__ F, size_t Fbs) {
    constexpr int KPS = 200;
    __shared__ unsigned short xsA[64 * KPS];
    __shared__ char bbuf[2][208 * 64];
    const int tid = threadIdx.x, bx = blockIdx.x, b = blockIdx.y;
    const int wv = tid >> 6, lane = tid & 63, a = lane & 15, kg = lane >> 4;
    const int nh = bx % NS, mg = bx / NS;
    const int NT0 = (NS == 1) ? 0 : nh * 7;
    const int NTN = (NS == 1) ? 13 : ((nh == 0) ? 7 : 6);

    const unsigned short* Abase = P + (size_t)b * Pbs;
    {
        for (int i = tid; i < 64 * 96; i += 256) {
            int r = i / 96, cu = i - r * 96;
            int gr = mg * 64 + r; if (gr > MROWS - 1) gr = MROWS - 1;
            unsigned int v = ((const unsigned int*)(Abase + (size_t)gr * 192))[cu];
            *(unsigned int*)&xsA[r * KPS + cu * 2] = v;
        }
    }
    int mt = mg * 4 + wv; if (mt > MTILES - 1) mt = MTILES - 1;
    const int arow = mt * 16 + a - mg * 64;
    const int mbase = mt * 16 + kg * 4;

    auto run = [&](const unsigned short* Vb, size_t Vbs_, int KPB, int KK,
                   int AOFFe, int outoff) {
        f32x4 acc[13];
#pragma unroll
        for (int nt = 0; nt < 13; ++nt) acc[nt] = (f32x4){0.f, 0.f, 0.f, 0.f};
        const char* Bbase = (const char*)(Vb + (size_t)b * Vbs_);
        auto stageB = [&](int kk) {
            char* dst0 = &bbuf[kk & 1][0];
            const int cnt = NTN * 64;
#pragma unroll
            for (int c = 0; c < 4; ++c) {
                int idx = tid + c * 256;
                if (idx < cnt) {
                    int lrow = idx >> 2, u = idx & 3;
                    int grow = NT0 * 16 + lrow;
                    gas_void* src = (gas_void*)(Bbase + (size_t)grow * (KPB * 2) +
                                                kk * 64 + u * 16);
                    __builtin_amdgcn_global_load_lds(src,
                        (las_void*)(dst0 + (size_t)idx * 16), 16, 0, 0);
                }
            }
        };
        stageB(0);
        __syncthreads();
        for (int kk = 0; kk < KK; ++kk) {
            if (kk + 1 < KK) stageB(kk + 1);
            bf16x8 Af = *(const bf16x8*)&xsA[arow * KPS + AOFFe + kk * 32 + kg * 8];
            const char* bb = &bbuf[kk & 1][0];
#pragma unroll
            for (int nt = 0; nt < 13; ++nt) {
                if (nt >= NT0 && nt < NT0 + NTN) {
                    bf16x8 Bf = *(const bf16x8*)(bb + ((nt - NT0) * 16 + a) * 64 + kg * 16);
                    acc[nt] = __builtin_amdgcn_mfma_f32_16x16x32_bf16(Af, Bf, acc[nt], 0, 0, 0);
                }
            }
            __syncthreads();
        }
#pragma unroll
        for (int nt = 0; nt < 13; ++nt) {
            if (nt < NT0 || nt >= NT0 + NTN) continue;
            int col = nt * 16 + a;
#pragma unroll
            for (int j = 0; j < 4; ++j) {
                int row = mbase + j;
                if (row < MROWS) {
                    unsigned short h = (col < 196) ? f2bf(acc[nt][j]) : (unsigned short)0;
                    F[(size_t)b * Fbs + (size_t)row * 448 + outoff + col] = h;
                }
            }
        }
        if (nh == NS - 1) {
            int col = 208 + a;
#pragma unroll
            for (int j = 0; j < 4; ++j) {
                int row = mbase + j;
                if (row < MROWS)
                    F[(size_t)b * Fbs + (size_t)row * 448 + outoff + col] = 0;
            }
        }
    };
    run(V1, V1bs, 128, 4, 0, 0);
    run(V2, V2bs, 64, 2, 128, 224);
}

// ---------------- rowsum for finale ----------------
__global__ void k_rowsum(const float* __restrict__ cms, float* __restrict__ rs) {
    int oc = blockIdx.x, b = blockIdx.y;
    int lane = threadIdx.x;
    const float* p = cms + ((size_t)b * 173 + oc) * 196;
    float s = 0.f;
    for (int j = lane; j < 196; j += 64) s += p[j];
    for (int sh = 32; sh; sh >>= 1) s += __shfl_xor(s, sh);
    if (lane == 0) rs[(size_t)b * 173 + oc] = s;
}

// ---------------- transpose of 3 [196,196] matrices ----------------
struct P8 { const float* p[4]; };
__global__ void k_transpose4(P8 ws_in, float* __restrict__ wt) {
    int i = blockIdx.x, m = blockIdx.y;
    const float* w = ws_in.p[m];
    float* o = wt + (size_t)m * 38416;
    for (int t = threadIdx.x; t < 196; t += blockDim.x)
        o[(size_t)i * 196 + t] = w[(size_t)t * 196 + i];
}

// ---------------- catnum ----------------
__global__ void k_catnum(const float* __restrict__ inp, int A,
                         const float* __restrict__ w, const float* __restrict__ bias,
                         const float* __restrict__ g, const float* __restrict__ be,
                         float* __restrict__ outv) {
    int j = blockIdx.x;
    int lane = threadIdx.x;
    float v = 0.f;
    if (lane < 32) {
        v = bias[j];
        for (int k = 0; k < A; ++k) v += inp[lane * A + k] * w[j * A + k];
    }
    float s = (lane < 32) ? v : 0.f;
    float s2 = (lane < 32) ? v * v : 0.f;
    for (int m = 16; m; m >>= 1) { s += __shfl_xor(s, m, 32); s2 += __shfl_xor(s2, m, 32); }
    if (lane < 32) {
        float mean = s / 32.f;
        float var = s2 / 32.f - mean * mean;
        float rstd = rsqrtf(var + 1e-5f);
        float t = (v - mean) * rstd * g[j] + be[j];
        t = t / (1.f + expf(-t));
        outv[lane * 196 + j] = t;
    }
}

__global__ void k_textbuild(const float* __restrict__ toh, const float* __restrict__ tnm,
                            float* __restrict__ text, float* __restrict__ textT) {
    int idx = blockIdx.x;
    int b = idx / 45, c = idx - b * 45;
    int s = threadIdx.x;
    if (s < 196) {
        float v = (c < 30) ? toh[b * 196 + s] : tnm[b * 196 + s];
        text[(size_t)idx * 196 + s] = v;
        textT[((size_t)b * 196 + s) * 45 + c] = v;
    }
}

// ---------------- GCN dist img (fp32 fT in, bf16 dist out) ----------------
template <int C, int ROWS>
__global__ void k_gcn_dist_ob(const float* __restrict__ f, const float* __restrict__ fT,
                              unsigned short* __restrict__ distb) {
    __shared__ float fi[ROWS][196];
    const int i0 = blockIdx.x * ROWS, b = blockIdx.y;
    const int tid = threadIdx.x;
    for (int idx = tid; idx < ROWS * 196; idx += 256) {
        int r = idx / 196, n = idx - r * 196;
        fi[r][n] = f[((size_t)(b * C + i0 + r)) * 196 + n];
    }
    __syncthreads();
    if (tid < C) {
        const float* ft = fT + (size_t)b * 196 * C + tid;
        float a[ROWS];
#pragma unroll
        for (int r = 0; r < ROWS; ++r) a[r] = 0.f;
#pragma unroll 4
        for (int n = 0; n < 196; ++n) {
            float v = ft[(size_t)n * C];
#pragma unroll
            for (int r = 0; r < ROWS; ++r) a[r] += fabsf(fi[r][n] - v);
        }
#pragma unroll
        for (int r = 0; r < ROWS; ++r)
            distb[((size_t)(b * C + i0 + r)) * C + tid] = f2bf(expf(-a[r]));
    }
}

// ---------------- GCN dist text (fp32, unchanged) ----------------
template <int C, int ROWS>
__global__ void k_gcn_dist_t(const float* __restrict__ f, const float* __restrict__ fT,
                             float* __restrict__ dist) {
    __shared__ float fi[ROWS][196];
    const int i0 = blockIdx.x * ROWS, b = blockIdx.y;
    const int tid = threadIdx.x;
    for (int idx = tid; idx < ROWS * 196; idx += 256) {
        int r = idx / 196, n = idx - r * 196;
        fi[r][n] = f[((size_t)(b * C + i0 + r)) * 196 + n];
    }
    __syncthreads();
    if (tid < C) {
        const float* ft = fT + (size_t)b * 196 * C + tid;
        float a[ROWS];
#pragma unroll
        for (int r = 0; r < ROWS; ++r) a[r] = 0.f;
#pragma unroll 4
        for (int n = 0; n < 196; ++n) {
            float v = ft[(size_t)n * C];
#pragma unroll
            for (int r = 0; r < ROWS; ++r) a[r] += fabsf(fi[r][n] - v);
        }
#pragma unroll
        for (int r = 0; r < ROWS; ++r)
            dist[((size_t)(b * C + i0 + r)) * C + tid] = expf(-a[r]);
    }
}

// ---------------- GCN spmm+fin text (fp32, unchanged) ----------------
template <int C, int ROWS>
__global__ void k_gcn_spmmfin_t(const float* __restrict__ dist, const float* __restrict__ f,
                                const float* __restrict__ wt, const float* __restrict__ bias,
                                float* __restrict__ outp) {
    __shared__ float ds[ROWS][C];
    __shared__ float ts[ROWS][196];
    const int i0 = blockIdx.x * ROWS, b = blockIdx.y;
    const int tid = threadIdx.x;
    for (int idx = tid; idx < ROWS * C; idx += 256) {
        int r = idx / C, j = idx - r * C;
        ds[r][j] = dist[((size_t)(b * C + i0 + r)) * C + j];
    }
    __syncthreads();
    if (tid < 196) {
        float a[ROWS];
#pragma unroll
        for (int r = 0; r < ROWS; ++r) a[r] = 0.f;
#pragma unroll 4
        for (int j = 0; j < C; ++j) {
            float v = f[((size_t)b * C + j) * 196 + tid];
#pragma unroll
            for (int r = 0; r < ROWS; ++r) a[r] += ds[r][j] * v;
        }
#pragma unroll
        for (int r = 0; r < ROWS; ++r) ts[r][tid] = a[r];
    }
    __syncthreads();
    if (tid < 196) {
        float a[ROWS];
        float bi = bias[tid];
#pragma unroll
        for (int r = 0; r < ROWS; ++r) a[r] = bi;
#pragma unroll 4
        for (int n = 0; n < 196; ++n) {
            float wv = wt[(size_t)n * 196 + tid];
#pragma unroll
            for (int r = 0; r < ROWS; ++r) a[r] += ts[r][n] * wv;
        }
#pragma unroll
        for (int r = 0; r < ROWS; ++r) {
            size_t rr = ((size_t)(b * C + i0 + r)) * 196 + tid;
            outp[rr] = fmaxf(a[r], 0.f) + f[rr];
        }
    }
}

// ---------------- LN + relu(linear), emits Kcat (pad-zeroed) + transposed ---
template <int R, int ROWS, int KOFF, int TS>
__global__ void k_lnlin2(const float* __restrict__ x, const float* __restrict__ g,
                         const float* __restrict__ be, const float* __restrict__ eT,
                         const float* __restrict__ eb, float* __restrict__ lnout,
                         unsigned short* __restrict__ kcat,
                         unsigned short* __restrict__ tbuf) {
    __shared__ float ls[ROWS][196];
    const int i0 = blockIdx.x * ROWS, b = blockIdx.y;
    const int tid = threadIdx.x;
    const int wv = tid >> 6, lane = tid & 63;
    for (int idx = tid; idx < ROWS * 196; idx += 256) {
        int r = idx / 196, n = idx - r * 196;
        ls[r][n] = x[((size_t)(b * R + i0 + r)) * 196 + n];
    }
    __syncthreads();
    for (int k = 0;; ++k) {
        int r = wv + 4 * k;
        if (r >= ROWS) break;
        float s = 0.f, s2 = 0.f;
        for (int j = lane; j < 196; j += 64) { float v = ls[r][j]; s += v; s2 += v * v; }
        for (int sh = 32; sh; sh >>= 1) { s += __shfl_xor(s, sh); s2 += __shfl_xor(s2, sh); }
        float mean = s / 196.f;
        float var = s2 / 196.f - mean * mean;
        float rstd = rsqrtf(var + 1e-6f);
        size_t rowo = ((size_t)(b * R + i0 + r)) * 196;
        for (int j = lane; j < 196; j += 64) {
            float l = (ls[r][j] - mean) * rstd * g[j] + be[j];
            ls[r][j] = l;
            lnout[rowo + j] = l;
        }
    }
    __syncthreads();
    if (tid < 224) {
        float a[ROWS];
        if (tid < 196) {
            float bi = eb[tid];
#pragma unroll
            for (int r = 0; r < ROWS; ++r) a[r] = bi;
#pragma unroll 4
            for (int n = 0; n < 196; ++n) {
                float ev = eT[(size_t)n * 196 + tid];
#pragma unroll
                for (int r = 0; r < ROWS; ++r) a[r] += ls[r][n] * ev;
            }
        }
#pragma unroll
        for (int r = 0; r < ROWS; ++r) {
            unsigned short h = 0;
            if (tid < 196) h = f2bf(fmaxf(a[r], 0.f));
            kcat[((size_t)(b * 208 + KOFF + i0 + r)) * 224 + tid] = h;
            if (tid < 196) tbuf[((size_t)(b * 208 + tid)) * TS + (i0 + r)] = h;
        }
    }
}

// ---------------- final classifier ----------------
__global__ void k_finale(const float* __restrict__ toh, const float* __restrict__ tnm,
                         const float* __restrict__ rowsum, const float* __restrict__ cls_w,
                         const float* __restrict__ cls_b, float* __restrict__ out) {
    int b = blockIdx.x;
    __shared__ float r1[4], r2[4];
    int tid = threadIdx.x;
    float a = (tid < 196) ? toh[b * 196 + tid] : 0.f;
    float c = (tid < 196) ? tnm[b * 196 + tid] : 0.f;
    for (int sh = 32; sh; sh >>= 1) { a += __shfl_xor(a, sh); c += __shfl_xor(c, sh); }
    if ((tid & 63) == 0) { r1[tid >> 6] = a; r2[tid >> 6] = c; }
    __syncthreads();
    if (tid < 2) {
        float soh = r1[0] + r1[1] + r1[2] + r1[3];
        float snm = r2[0] + r2[1] + r2[2] + r2[3];
        const float* wrow = &cls_w[tid * 218];
        float acc = cls_b[tid];
        float w1 = 0.f, w2 = 0.f;
        for (int k = 0; k < 30; ++k) w1 += wrow[k];
        for (int k = 30; k < 45; ++k) w2 += wrow[k];
        acc += soh * w1 + snm * w2;
        for (int k = 0; k < 173; ++k) acc += wrow[45 + k] * rowsum[(size_t)b * 173 + k];
        out[b * 2 + tid] = acc;
    }
}

// ---------------------------------------------------------------------------
extern "C" void kernel_launch(void* const* d_in, const int* in_sizes, int n_in,
                              void* d_out, int out_size, void* d_ws, size_t ws_size,
                              hipStream_t stream) {
    const float* x      = (const float*)d_in[0];
    const float* oneHot = (const float*)d_in[1];
    const float* num    = (const float*)d_in[2];
    const float* c1_w1  = (const float*)d_in[3];
    const float* c1_g1  = (const float*)d_in[5];
    const float* c1_be1 = (const float*)d_in[6];
    const float* c1_w2  = (const float*)d_in[7];
    const float* c1_g2  = (const float*)d_in[9];
    const float* c1_be2 = (const float*)d_in[10];
    const float* oh_w   = (const float*)d_in[11];
    const float* oh_b   = (const float*)d_in[12];
    const float* oh_g   = (const float*)d_in[13];
    const float* oh_be  = (const float*)d_in[14];
    const float* nm_w   = (const float*)d_in[15];
    const float* nm_b   = (const float*)d_in[16];
    const float* nm_g   = (const float*)d_in[17];
    const float* nm_be  = (const float*)d_in[18];
    const float* gm1_w  = (const float*)d_in[19];
    const float* gm1_b  = (const float*)d_in[20];
    const float* gm2_w  = (const float*)d_in[21];
    const float* gm2_b  = (const float*)d_in[22];
    const float* ln1_g  = (const float*)d_in[23];
    const float* ln1_b  = (const float*)d_in[24];
    const float* ln2_g  = (const float*)d_in[25];
    const float* ln2_b  = (const float*)d_in[26];
    const float* e1_w   = (const float*)d_in[27];
    const float* e1_b   = (const float*)d_in[28];
    const float* e2_w   = (const float*)d_in[29];
    const float* e2_b   = (const float*)d_in[30];
    const float* f1_w   = (const float*)d_in[31];
    const float* f1_b   = (const float*)d_in[32];
    const float* f2_w   = (const float*)d_in[33];
    const float* f2_b   = (const float*)d_in[34];
    const float* f3_w   = (const float*)d_in[35];
    const float* f3_b   = (const float*)d_in[36];
    const float* f4_w   = (const float*)d_in[37];
    const float* f4_b   = (const float*)d_in[38];
    const float* cm_w   = (const float*)d_in[39];
    const float* cm_b   = (const float*)d_in[40];
    const float* cmf_w  = (const float*)d_in[41];
    const float* cmf_b  = (const float*)d_in[42];
    const float* cls_w  = (const float*)d_in[43];
    const float* cls_b  = (const float*)d_in[44];
    float* out = (float*)d_out;
    float* W = (float*)d_ws;

    const size_t L = 802816;
    const size_t T = 282240;
    const size_t F3 = 1085056;
    // ---- layout (floats); live ranges annotated ----
    const size_t o_A    = 0;                  // conv1 out -> GCN tmpb (bf16)
    const size_t o_B    = L;                  // conv2 out -> ln1 (lnres img)
    const size_t o_C    = 2 * L;              // c5f post-gcn (res2 img)
    const size_t o_part = 3 * L;              // conv partials [3L, 8L)
    const size_t o_Kcat = 3 * L;              // bf16 [32][208][224]
    const size_t o_iqT  = o_Kcat + 745472;    // bf16 [32][208][128]
    const size_t o_t1   = 4 * L + T;
    const size_t o_t3   = 4 * L + 2 * T;
    const size_t o_ln2  = 4 * L + 3 * T;
    const size_t o_toh  = 4 * L + 4 * T;
    const size_t o_tnm  = o_toh + 6272;
    const size_t o_st   = o_tnm + 6272;       // (spare)
    const size_t o_wT   = o_st + 1024;        // 3 transposed 196x196
    const size_t o_feat = o_wT + 8 * 38416;
    const size_t o_q    = o_feat + F3;
    const size_t o_Fimg = o_q;                // bf16 [32][128][448]
    const size_t o_dd   = o_q + F3;           // 6,831,232
    const size_t o_db   = o_dd;               // distb bf16 [32][128][128] = 262,144 fl
    const size_t o_d2   = o_dd + 524288;      // text dist fp32 (64,800 fl)
    const size_t o_gm1b = o_dd + 589088;      // gm1b bf16 [208][224] = 23,296 fl
    const size_t o_fTb  = o_dd + 612384;      // fTb bf16 [32][208][128] = 425,984 fl
    const size_t o_tqT  = o_dd;               // after GCN: bf16 [32][208][64]
    const size_t o_wcI  = o_dd + 212992;
    const size_t o_wcT  = o_wcI + 46592;
    const size_t o_pbf  = o_dd;
    const size_t o_rs   = o_dd;
    const size_t o_qbf  = o_dd + 745472;
    const size_t o_Ftxt = o_qbf;
    const size_t o_wcm  = o_qbf + 630784;
    const size_t o_wcmf = o_wcm + 16896;
    const size_t o_ftb  = o_wcmf + 16896;
    const size_t o_tr   = o_ftb + 638976;     // fT fp32 (L) + textT fp32 (T)
    const size_t o_Pimg = o_tr;
    const size_t o_Ptxt = o_tr + 393216;
    const size_t o_qtb  = o_tr;
    const size_t o_feab = o_qtb + 638976;     // ends 10,158,208
    const size_t o_ps   = 10158208;           // BN partials: 2 x 8192 fl
    const size_t o_xt1 = o_dd;
    const size_t o_xt2 = o_xt1 + 1198080;
    const size_t o_wp1 = o_xt2 + 479232;
    const size_t o_wp2 = o_wp1 + 552960;

    float* part = W + o_part;
    unsigned short* xt1 = (unsigned short*)(W + o_xt1);
    unsigned short* xt2 = (unsigned short*)(W + o_xt2);
    unsigned short* wp1 = (unsigned short*)(W + o_wp1);
    unsigned short* wp2 = (unsigned short*)(W + o_wp2);
    unsigned short* kcatb = (unsigned short*)(W + o_Kcat);
    unsigned short* iqTb = (unsigned short*)(W + o_iqT);
    unsigned short* tqTb = (unsigned short*)(W + o_tqT);
    unsigned short* wcatI = (unsigned short*)(W + o_wcI);
    unsigned short* wcatT = (unsigned short*)(W + o_wcT);
    unsigned short* Fimg = (unsigned short*)(W + o_Fimg);
    unsigned short* Ftxt = (unsigned short*)(W + o_Ftxt);
    unsigned short* Pimg = (unsigned short*)(W + o_Pimg);
    unsigned short* Ptxt = (unsigned short*)(W + o_Ptxt);
    unsigned short* ftb = (unsigned short*)(W + o_ftb);
    unsigned short* qtb = (unsigned short*)(W + o_qtb);
    unsigned short* feab = (unsigned short*)(W + o_feab);
    unsigned short* qbf = (unsigned short*)(W + o_qbf);
    unsigned short* wcmb = (unsigned short*)(W + o_wcm);
    unsigned short* wcmfb = (unsigned short*)(W + o_wcmf);
    unsigned short* pbf = (unsigned short*)(W + o_pbf);
    unsigned short* distb = (unsigned short*)(W + o_db);
    unsigned short* gm1b = (unsigned short*)(W + o_gm1b);
    unsigned short* fTb = (unsigned short*)(W + o_fTb);
    unsigned short* tmpb = (unsigned short*)(W + o_A);
    float* gm2T = W + o_wT + 0 * 38416;
    float* e1T  = W + o_wT + 1 * 38416;
    float* e2T  = W + o_wT + 2 * 38416;

    // ---- conv prep ----
    k_wpack<<<(27 * 128 * 40 + 255) / 256, 256, 0, stream>>>(c1_w1, wp1, 320);
    k_wpack<<<(27 * 128 * 16 + 255) / 256, 256, 0, stream>>>(c1_w2, wp2, 128);
    k_xt_c<<<dim3((5 * 208 * 36 + 255) / 256, 32), 256, 0, stream>>>(x, xt1, 320, 5);

    // ---- conv1 + fused reduce/stats (deterministic) + BN ----
    k_convchunk4<320, 5, 4, 2><<<dim3(20, 32), 256, 0, stream>>>(xt1, wp1, part);
    k_reduce_stats<5, 128><<<dim3(128, 32), 256, 0, stream>>>(part, W + o_A, W + o_ps);
    k_bn_apply2<<<4096, 256, 0, stream>>>(W + o_A, W + o_ps, c1_g1, c1_be1,
                                          nullptr, nullptr, xt2, 128);

    // ---- conv2 + fused reduce/stats + BN (emits fT fp32 + fTb bf16) ----
    k_convchunk4<128, 2, 2, 4><<<dim3(16, 32), 256, 0, stream>>>(xt2, wp2, part);
    k_reduce_stats<2, 128><<<dim3(128, 32), 256, 0, stream>>>(part, W + o_B,
                                                              W + o_ps + 8192);
    k_bn_apply2<<<4096, 256, 0, stream>>>(W + o_B, W + o_ps + 8192, c1_g2, c1_be2,
                                          W + o_tr, fTb, nullptr, 128);

    // ---- conv scratch dead: weight packs + zero ftb ----
    k_w173<<<(176 * 192 + 255) / 256, 256, 0, stream>>>(cm_w, wcmb);
    k_w173<<<(176 * 192 + 255) / 256, 256, 0, stream>>>(cmf_w, wcmfb);
    k_wpad<<<(208 * 224 + 255) / 256, 256, 0, stream>>>(gm1_w, gm1b, 196, 196, 208, 224);
    k_zero4<<<(638976 / 4 + 255) / 256, 256, 0, stream>>>((float4*)(W + o_ftb), 638976 / 4);

    // ---- weight transposes (gm2, e1, e2) ----
    P8 p8;
    p8.p[0] = gm2_w; p8.p[1] = e1_w; p8.p[2] = e2_w; p8.p[3] = e2_w;
    k_transpose4<<<dim3(196, 3), 256, 0, stream>>>(p8, W + o_wT);

    // ---- catnum / text (textT fp32 at o_tr + L) ----
    k_catnum<<<196, 64, 0, stream>>>(oneHot, 24, oh_w, oh_b, oh_g, oh_be, W + o_toh);
    k_catnum<<<196, 64, 0, stream>>>(num, 11, nm_w, nm_b, nm_g, nm_be, W + o_tnm);
    k_textbuild<<<32 * 45, 256, 0, stream>>>(W + o_toh, W + o_tnm, W + o_t1, W + o_tr + L);

    // ---- GCN img via MFMA: dist (fp32 in, bf16 out) -> tmp -> out ----
    k_gcn_dist_ob<128, 4><<<dim3(32, 32), 256, 0, stream>>>(W + o_B, W + o_tr, distb);
    k_bgemm<128, 8, 128, 4, 7, 2><<<dim3(4, 32), 256, 0, stream>>>(
        distb, (size_t)128 * 128, fTb, (size_t)208 * 128, nullptr,
        tmpb, nullptr, nullptr, nullptr);
    k_bgemm<128, 8, 224, 7, 8, 2><<<dim3(4, 32), 256, 0, stream>>>(
        tmpb, (size_t)128 * 224, gm1b, 0, gm1_b,
        nullptr, nullptr, W + o_B, W + o_C);

    // ---- GCN text (fp32, unchanged) ----
    k_gcn_dist_t<45, 3><<<dim3(15, 32), 256, 0, stream>>>(W + o_t1, W + o_tr + L, W + o_d2);
    k_gcn_spmmfin_t<45, 3><<<dim3(15, 32), 256, 0, stream>>>(W + o_d2, W + o_t1, gm2T,
                                                             gm2_b, W + o_t3);

    // ---- GCN buffers dead: zero tqT + pack Wcats ----
    k_zero4<<<(212992 / 4 + 255) / 256, 256, 0, stream>>>((float4*)(W + o_tqT),
                                                          212992 / 4);
    k_wcat<<<(208 * 448 + 255) / 256, 256, 0, stream>>>(f1_w, f3_w, wcatI);
    k_wcat<<<(208 * 448 + 255) / 256, 256, 0, stream>>>(f4_w, f2_w, wcatT);

    // ---- LN + q projections -> Kcat (pad-zeroed) / iqT / tqT ----
    k_lnlin2<128, 4, 0, 128><<<dim3(32, 32), 256, 0, stream>>>(
        W + o_C, ln1_g, ln1_b, e1T, e1_b, W + o_B, kcatb, iqTb);
    k_lnlin2<45, 3, 128, 64><<<dim3(15, 32), 256, 0, stream>>>(
        W + o_t3, ln2_g, ln2_b, e2T, e2_b, W + o_ln2, kcatb, tqTb);

    // ---- attention: scores + dual softmax -> P ----
    k_agemm<128, 8, 224, 224, 7, 5, 1, 1><<<dim3(2, 32), 256, 0, stream>>>(
        kcatb, (size_t)208 * 224, kcatb, (size_t)208 * 224,
        nullptr, nullptr, nullptr, nullptr, Pimg, 192, (size_t)128 * 192,
        nullptr, nullptr, 0);
    k_agemm<45, 3, 224, 224, 7, 5, 1, 1><<<dim3(1, 32), 256, 0, stream>>>(
        kcatb + 128 * 224, (size_t)208 * 224, kcatb, (size_t)208 * 224,
        nullptr, nullptr, nullptr, nullptr, Ptxt, 192, (size_t)48 * 192,
        nullptr, nullptr, 0);

    // ---- attention: merged PV ----
    k_pv<128, 8, 2><<<dim3(4, 32), 256, 0, stream>>>(
        Pimg, (size_t)128 * 192, iqTb, (size_t)208 * 128, tqTb, (size_t)208 * 64,
        Fimg, (size_t)128 * 448);
    k_pv<45, 3, 2><<<dim3(2, 32), 256, 0, stream>>>(
        Ptxt, (size_t)48 * 192, iqTb, (size_t)208 * 128, tqTb, (size_t)208 * 64,
        Ftxt, (size_t)48 * 448);

    // ---- attention: projection + residuals -> feat + ftb ----
    k_agemm<128, 8, 448, 448, 14, 4, 0, 2><<<dim3(4, 32), 256, 0, stream>>>(
        Fimg, (size_t)128 * 448, wcatI, 0,
        f1_b, f3_b, W + o_B, W + o_C, nullptr, 0, 0, W + o_feat, ftb, 0);
    k_agemm<45, 3, 448, 448, 14, 4, 0, 2><<<dim3(2, 32), 256, 0, stream>>>(
        Ftxt, (size_t)48 * 448, wcatT, 0,
        f2_b, f4_b, W + o_ln2, W + o_t3, nullptr, 0, 0, W + o_feat, ftb, 128);

    // ---- attention buffers dead: CMSA prep ----
    k_zero4<<<(1277952 / 4 + 255) / 256, 256, 0, stream>>>((float4*)(W + o_qtb),
                                                           1277952 / 4);
    k_zero4<<<(630784 / 4 + 255) / 256, 256, 0, stream>>>((float4*)(W + o_qbf),
                                                          630784 / 4);
    k_zero4<<<(745472 / 4 + 255) / 256, 256, 0, stream>>>((float4*)(W + o_pbf),
                                                          745472 / 4);

    // ---- CMSA via MFMA GEMMs ----
    k_bgemm<176, 11, 192, 6, 0, 2><<<dim3(6, 32), 256, 0, stream>>>(
        wcmb, 0, ftb, (size_t)208 * 192, cm_b, qbf, qtb, nullptr, nullptr);
    k_bgemm<208, 13, 192, 6, 1, 1><<<dim3(4, 32), 256, 0, stream>>>(
        qtb, (size_t)208 * 192, qtb, (size_t)208 * 192, nullptr, pbf, nullptr,
        nullptr, nullptr);
    k_bgemm<176, 11, 224, 7, 2, 2><<<dim3(6, 32), 256, 0, stream>>>(
        qbf, (size_t)176 * 224, pbf, (size_t)208 * 224, nullptr, feab, nullptr,
        nullptr, nullptr);
    k_bgemm<176, 11, 192, 6, 3, 2><<<dim3(6, 32), 256, 0, stream>>>(
        wcmfb, 0, feab, (size_t)208 * 192, cmf_b, nullptr, nullptr,
        W + o_feat, W + o_q);

    // ---- rowsum + final classifier ----
    k_rowsum<<<dim3(173, 32), 64, 0, stream>>>(W + o_q, W + o_rs);
    k_finale<<<32, 256, 0, stream>>>(W + o_toh, W + o_tnm, W + o_rs, cls_w, cls_b, out);
}

// Round 19
// 369.931 us; speedup vs baseline: 1.3145x; 1.1684x over previous
//
#include <hip/hip_runtime.h>
#include <hip/hip_bf16.h>

// ---------------------------------------------------------------------------
// mv3Dunet_down_text_cmsa forward. Round 19: launch-count reduction — all
// independent small kernels merged into range-dispatched mega-kernels
// (42 -> 28 launches). Arithmetic identical to round 18.
// ---------------------------------------------------------------------------

using bf16x8 = __attribute__((ext_vector_type(8))) short;
using f32x4  = __attribute__((ext_vector_type(4))) float;

typedef const __attribute__((address_space(1))) void gas_void;
typedef __attribute__((address_space(3))) void las_void;

__device__ __forceinline__ unsigned short f2bf(float f) {
    unsigned int u = __float_as_uint(f);
    u += 0x7FFFu + ((u >> 16) & 1u);
    return (unsigned short)(u >> 16);
}

// ================= device helper bodies (from r18 kernels) =================
__device__ __forceinline__ void d_wpack(const float* __restrict__ w,
                                        unsigned short* __restrict__ wp,
                                        int IC, int idx) {
    int nc = IC >> 3;
    if (idx >= 27 * 128 * nc) return;
    int c = idx % nc; int r = idx / nc; int oc = r & 127; int t = r >> 7;
    const float* ws = w + ((size_t)oc * IC + c * 8) * 27 + t;
    unsigned int o0 = f2bf(ws[0])   | ((unsigned int)f2bf(ws[27])  << 16);
    unsigned int o1 = f2bf(ws[54])  | ((unsigned int)f2bf(ws[81])  << 16);
    unsigned int o2 = f2bf(ws[108]) | ((unsigned int)f2bf(ws[135]) << 16);
    unsigned int o3 = f2bf(ws[162]) | ((unsigned int)f2bf(ws[189]) << 16);
    uint4 v; v.x = o0; v.y = o1; v.z = o2; v.w = o3;
    ((uint4*)wp)[idx] = v;
}

__device__ __forceinline__ void d_w173(const float* __restrict__ w,
                                       unsigned short* __restrict__ wb, int idx) {
    if (idx >= 176 * 192) return;
    int oc = idx / 192, c = idx - oc * 192;
    wb[idx] = (oc < 173 && c < 173) ? f2bf(w[(size_t)oc * 173 + c]) : (unsigned short)0;
}

__device__ __forceinline__ void d_wcat(const float* __restrict__ wA,
                                       const float* __restrict__ wB,
                                       unsigned short* __restrict__ outw, int idx) {
    if (idx >= 208 * 448) return;
    int n = idx / 448, k = idx - n * 448;
    unsigned short v = 0;
    if (n < 196) {
        if (k < 196) v = f2bf(wA[(size_t)n * 196 + k]);
        else if (k >= 224 && k < 420) v = f2bf(wB[(size_t)n * 196 + (k - 224)]);
    }
    outw[idx] = v;
}

__device__ __forceinline__ void d_catnum(const float* __restrict__ inp, int A,
                                         const float* __restrict__ w,
                                         const float* __restrict__ bias,
                                         const float* __restrict__ g,
                                         const float* __restrict__ be,
                                         float* __restrict__ outv, int j, int lane) {
    float v = 0.f;
    if (lane < 32) {
        v = bias[j];
        for (int k = 0; k < A; ++k) v += inp[lane * A + k] * w[j * A + k];
    }
    float s = (lane < 32) ? v : 0.f;
    float s2 = (lane < 32) ? v * v : 0.f;
    for (int m = 16; m; m >>= 1) { s += __shfl_xor(s, m, 32); s2 += __shfl_xor(s2, m, 32); }
    if (lane < 32) {
        float mean = s / 32.f;
        float var = s2 / 32.f - mean * mean;
        float rstd = rsqrtf(var + 1e-5f);
        float t = (v - mean) * rstd * g[j] + be[j];
        t = t / (1.f + expf(-t));
        outv[lane * 196 + j] = t;
    }
}

// ================= merged dispatcher kernels =================
// prep1: wpack(c1_w1) | wpack(c1_w2) | xt_c(x)  — grid 5460
__global__ void k_prep1(const float* __restrict__ c1w1, unsigned short* __restrict__ wp1,
                        const float* __restrict__ c1w2, unsigned short* __restrict__ wp2,
                        const float* __restrict__ x, unsigned short* __restrict__ xt1) {
    int blk = blockIdx.x, tid = threadIdx.x;
    if (blk < 540) { d_wpack(c1w1, wp1, 320, blk * 256 + tid); return; }
    blk -= 540;
    if (blk < 216) { d_wpack(c1w2, wp2, 128, blk * 256 + tid); return; }
    blk -= 216;
    int b = blk / 147, ib = blk - b * 147;
    const int tot = 5 * 208 * 36;
    int idx = ib * 256 + tid;
    if (idx >= tot) return;
    int g = idx / (208 * 36); int r2 = idx - g * (208 * 36);
    int s = r2 / 36, cp = r2 - s * 36;
    int cc = cp * 2;
    int ic = g * 64 + cc;
    unsigned int lo = 0, hi = 0;
    if (s < 196 && cc < 64 && ic < 320)         lo = f2bf(x[((size_t)b * 320 + ic) * 196 + s]);
    if (s < 196 && cc + 1 < 64 && ic + 1 < 320) hi = f2bf(x[((size_t)b * 320 + ic + 1) * 196 + s]);
    ((unsigned int*)xt1)[(size_t)b * tot + idx] = lo | (hi << 16);
}

// prep2: w173(cm) | w173(cmf) | wpad(gm1) | zero(ftb) | transpose{gm2,e1,e2}
// grid 1658
__global__ void k_prep2(const float* __restrict__ cm_w, unsigned short* __restrict__ wcmb,
                        const float* __restrict__ cmf_w, unsigned short* __restrict__ wcmfb,
                        const float* __restrict__ gm1_w, unsigned short* __restrict__ gm1b,
                        float4* __restrict__ ftbz,
                        const float* __restrict__ gm2_w, const float* __restrict__ e1_w,
                        const float* __restrict__ e2_w, float* __restrict__ wT) {
    int blk = blockIdx.x, tid = threadIdx.x;
    if (blk < 132) { d_w173(cm_w, wcmb, blk * 256 + tid); return; }
    blk -= 132;
    if (blk < 132) { d_w173(cmf_w, wcmfb, blk * 256 + tid); return; }
    blk -= 132;
    if (blk < 182) {
        int idx = blk * 256 + tid;
        if (idx < 208 * 224) {
            int r = idx / 224, c = idx - r * 224;
            gm1b[idx] = (r < 196 && c < 196) ? f2bf(gm1_w[(size_t)r * 196 + c])
                                             : (unsigned short)0;
        }
        return;
    }
    blk -= 182;
    if (blk < 624) {
        int i = blk * 256 + tid;
        if (i < 159744) ftbz[i] = (float4){0.f, 0.f, 0.f, 0.f};
        return;
    }
    blk -= 624;
    {
        int m = blk / 196, i = blk - m * 196;
        const float* w = (m == 0) ? gm2_w : (m == 1) ? e1_w : e2_w;
        float* o = wT + (size_t)m * 38416;
        if (tid < 196) o[(size_t)i * 196 + tid] = w[(size_t)tid * 196 + i];
    }
}

// catnum merged — grid 392, 64 threads
__global__ void k_catnum2(const float* __restrict__ oneHot, const float* __restrict__ num,
                          const float* __restrict__ ohw, const float* __restrict__ ohb,
                          const float* __restrict__ ohg, const float* __restrict__ ohbe,
                          const float* __restrict__ nmw, const float* __restrict__ nmb,
                          const float* __restrict__ nmg, const float* __restrict__ nmbe,
                          float* __restrict__ toh, float* __restrict__ tnm) {
    int blk = blockIdx.x;
    if (blk < 196) d_catnum(oneHot, 24, ohw, ohb, ohg, ohbe, toh, blk, threadIdx.x);
    else           d_catnum(num, 11, nmw, nmb, nmg, nmbe, tnm, blk - 196, threadIdx.x);
}

// GCN dist img (bf16 out) body
__device__ __forceinline__ void d_dist_img(const float* __restrict__ f,
                                           const float* __restrict__ fT,
                                           unsigned short* __restrict__ distb,
                                           int bx, int b, int tid) {
    __shared__ float fi[4][196];
    const int i0 = bx * 4;
    for (int idx = tid; idx < 4 * 196; idx += 256) {
        int r = idx / 196, n = idx - r * 196;
        fi[r][n] = f[((size_t)(b * 128 + i0 + r)) * 196 + n];
    }
    __syncthreads();
    if (tid < 128) {
        const float* ft = fT + (size_t)b * 196 * 128 + tid;
        float a[4];
#pragma unroll
        for (int r = 0; r < 4; ++r) a[r] = 0.f;
#pragma unroll 4
        for (int n = 0; n < 196; ++n) {
            float v = ft[(size_t)n * 128];
#pragma unroll
            for (int r = 0; r < 4; ++r) a[r] += fabsf(fi[r][n] - v);
        }
#pragma unroll
        for (int r = 0; r < 4; ++r)
            distb[((size_t)(b * 128 + i0 + r)) * 128 + tid] = f2bf(expf(-a[r]));
    }
}

// GCN dist txt (fp32 out) body
__device__ __forceinline__ void d_dist_txt(const float* __restrict__ f,
                                           const float* __restrict__ fT,
                                           float* __restrict__ dist,
                                           int bx, int b, int tid) {
    __shared__ float fi2[3][196];
    const int i0 = bx * 3;
    for (int idx = tid; idx < 3 * 196; idx += 256) {
        int r = idx / 196, n = idx - r * 196;
        fi2[r][n] = f[((size_t)(b * 45 + i0 + r)) * 196 + n];
    }
    __syncthreads();
    if (tid < 45) {
        const float* ft = fT + (size_t)b * 196 * 45 + tid;
        float a[3];
#pragma unroll
        for (int r = 0; r < 3; ++r) a[r] = 0.f;
#pragma unroll 4
        for (int n = 0; n < 196; ++n) {
            float v = ft[(size_t)n * 45];
#pragma unroll
            for (int r = 0; r < 3; ++r) a[r] += fabsf(fi2[r][n] - v);
        }
#pragma unroll
        for (int r = 0; r < 3; ++r)
            dist[((size_t)(b * 45 + i0 + r)) * 45 + tid] = expf(-a[r]);
    }
}

// merged dist — grid 1504
__global__ void k_dist_both(const float* __restrict__ fimg, const float* __restrict__ fTimg,
                            unsigned short* __restrict__ distb,
                            const float* __restrict__ ftxt, const float* __restrict__ fTtxt,
                            float* __restrict__ dist2) {
    int blk = blockIdx.x, tid = threadIdx.x;
    if (blk < 1024) d_dist_img(fimg, fTimg, distb, blk & 31, blk >> 5, tid);
    else { int r = blk - 1024; d_dist_txt(ftxt, fTtxt, dist2, r % 15, r / 15, tid); }
}

// prep3: zero(tqT) | wcat(f1,f3) | wcat(f4,f2) — grid 936
__global__ void k_prep3(float4* __restrict__ tqz,
                        const float* __restrict__ f1w, const float* __restrict__ f3w,
                        unsigned short* __restrict__ wcI,
                        const float* __restrict__ f4w, const float* __restrict__ f2w,
                        unsigned short* __restrict__ wcT) {
    int blk = blockIdx.x, tid = threadIdx.x;
    if (blk < 208) {
        int i = blk * 256 + tid;
        if (i < 53248) tqz[i] = (float4){0.f, 0.f, 0.f, 0.f};
        return;
    }
    blk -= 208;
    if (blk < 364) { d_wcat(f1w, f3w, wcI, blk * 256 + tid); return; }
    blk -= 364;
    d_wcat(f4w, f2w, wcT, blk * 256 + tid);
}

// prep4: zero pbf+qbf (contig) | zero qtb+feab (contig) — grid 2592
__global__ void k_prep4(float4* __restrict__ zA, float4* __restrict__ zB) {
    int blk = blockIdx.x, tid = threadIdx.x;
    if (blk < 1344) {
        int i = blk * 256 + tid;
        if (i < 344064) zA[i] = (float4){0.f, 0.f, 0.f, 0.f};
        return;
    }
    blk -= 1344;
    int i = blk * 256 + tid;
    if (i < 319488) zB[i] = (float4){0.f, 0.f, 0.f, 0.f};
}

// ================= conv (validated r12) =================
template <int IC, int G, int NT, int NH>
__global__ __launch_bounds__(256, 3) void k_convchunk4(
    const unsigned short* __restrict__ xt, const unsigned short* __restrict__ wp,
    float* __restrict__ part) {
    __shared__ unsigned short xs[208 * 72];
    __shared__ char bbuf[2][NT * 2048];
    const int tid = threadIdx.x;
    const int bx = blockIdx.x, b = blockIdx.y;
    const int mh = bx & 1;
    const int nh = (bx >> 1) % NH;
    const int g  = (bx >> 1) / NH;
    const int w = tid >> 6, l = tid & 63;

    {
        const bf16x8* s8 = (const bf16x8*)(xt + ((size_t)b * G + g) * (208 * 72));
        bf16x8* d8 = (bf16x8*)xs;
        for (int c = tid; c < 208 * 72 / 8; c += 256) d8[c] = s8[c];
    }

    const char* wslice = (const char*)wp +
                         ((size_t)(nh * NT * 16) * IC + (size_t)g * 64) * 2;
    auto stageB = [&](int t) {
        char* dst = &bbuf[t & 1][w * (NT * 512)];
        const char* wt_ = wslice + (size_t)t * 128 * IC * 2;
#pragma unroll
        for (int c = 0; c < NT / 2; ++c) {
            int q = w * (NT * 512) + c * 1024 + l * 16;
            int row = q >> 7, col = q & 127;
            int scol = col ^ ((row & 7) << 4);
            gas_void* src = (gas_void*)(wt_ + (size_t)row * IC * 2 + scol);
            __builtin_amdgcn_global_load_lds(src, (las_void*)(dst + c * 1024),
                                             16, 0, 0);
        }
    };

    const int lane = tid & 63;
    const int a = lane & 15, kg = lane >> 4;

    int md[2], mhh[2], mw[2];
#pragma unroll
    for (int i = 0; i < 2; ++i) {
        int m = (mh * 8 + (tid >> 6) * 2 + i) * 16 + a;
        md[i] = m / 49; int rr = m - md[i] * 49;
        mhh[i] = rr / 7; mw[i] = rr - mhh[i] * 7;
    }

    f32x4 acc[2][NT];
#pragma unroll
    for (int i = 0; i < 2; ++i)
#pragma unroll
        for (int nt = 0; nt < NT; ++nt) acc[i][nt] = (f32x4){0.f, 0.f, 0.f, 0.f};

    const bf16x8 zv = {0, 0, 0, 0, 0, 0, 0, 0};

    stageB(0);
    __syncthreads();

    for (int t = 0; t < 27; ++t) {
        if (t < 26) stageB(t + 1);
        const int kd = t / 9, kh = (t / 3) % 3, kw = t % 3;
        int rsrc[2]; bool ok[2];
#pragma unroll
        for (int i = 0; i < 2; ++i) {
            int d2 = md[i] + kd - 1, h2 = mhh[i] + kh - 1, w2 = mw[i] + kw - 1;
            ok[i] = ((unsigned)d2 < 4u) & ((unsigned)h2 < 7u) & ((unsigned)w2 < 7u);
            rsrc[i] = ok[i] ? (d2 * 49 + h2 * 7 + w2) : 0;
        }
        bf16x8 A[2][2];
#pragma unroll
        for (int kk = 0; kk < 2; ++kk)
#pragma unroll
            for (int i = 0; i < 2; ++i) {
                bf16x8 v = *(const bf16x8*)(xs + rsrc[i] * 72 + kk * 32 + kg * 8);
                A[kk][i] = ok[i] ? v : zv;
            }
        const char* bb = &bbuf[t & 1][0];
#pragma unroll
        for (int kk = 0; kk < 2; ++kk)
#pragma unroll
            for (int nt = 0; nt < NT; ++nt) {
                int row = nt * 16 + a;
                int cb = (kk * 64 + kg * 16) ^ ((row & 7) << 4);
                bf16x8 B = *(const bf16x8*)(bb + row * 128 + cb);
#pragma unroll
                for (int i = 0; i < 2; ++i)
                    acc[i][nt] = __builtin_amdgcn_mfma_f32_16x16x32_bf16(
                        A[kk][i], B, acc[i][nt], 0, 0, 0);
            }
        __syncthreads();
    }

    float* dst = part + ((size_t)g * 32 + b) * (128 * 196);
#pragma unroll
    for (int i = 0; i < 2; ++i) {
        int m0 = (mh * 8 + (tid >> 6) * 2 + i) * 16 + kg * 4;
        if (m0 < 196) {
#pragma unroll
            for (int nt = 0; nt < NT; ++nt) {
                int oc = nh * NT * 16 + nt * 16 + a;
                *(f32x4*)(dst + (size_t)oc * 196 + m0) = acc[i][nt];
            }
        }
    }
}

// ---------------- fused partial-reduce + BN stats (deterministic) ----------
template <int G, int C>
__global__ void k_reduce_stats(const float* __restrict__ part, float* __restrict__ y,
                               float* __restrict__ pst) {
    const int ch = blockIdx.x, b = blockIdx.y;
    const int tid = threadIdx.x;
    __shared__ float r1[4], r2[4];
    float v = 0.f;
    if (tid < 196) {
#pragma unroll
        for (int g = 0; g < G; ++g)
            v += part[((size_t)(g * 32 + b) * C + ch) * 196 + tid];
        y[((size_t)b * C + ch) * 196 + tid] = v;
    }
    float s = v, s2 = v * v;
    for (int sh = 32; sh; sh >>= 1) { s += __shfl_xor(s, sh); s2 += __shfl_xor(s2, sh); }
    if ((tid & 63) == 0) { r1[tid >> 6] = s; r2[tid >> 6] = s2; }
    __syncthreads();
    if (tid == 0) {
        pst[(ch * 32 + b) * 2]     = r1[0] + r1[1] + r1[2] + r1[3];
        pst[(ch * 32 + b) * 2 + 1] = r2[0] + r2[1] + r2[2] + r2[3];
    }
}

// ---------------- BN apply (fixed-order partial sum) ----------------
__global__ void k_bn_apply2(float* __restrict__ y, const float* __restrict__ pst,
                            const float* __restrict__ g, const float* __restrict__ be,
                            float* __restrict__ fT, unsigned short* __restrict__ fTb,
                            unsigned short* __restrict__ xtc, int C) {
    int idx = blockIdx.x;
    int ch = idx % C, b = idx / C;
    int s = threadIdx.x;
    float S = 0.f, S2 = 0.f;
    for (int b2 = 0; b2 < 32; ++b2) {
        S += pst[(ch * 32 + b2) * 2];
        S2 += pst[(ch * 32 + b2) * 2 + 1];
    }
    if (s < 196) {
        float m = S / 6272.f;
        float r = rsqrtf(S2 / 6272.f - m * m + 1e-5f);
        float v = y[(size_t)idx * 196 + s];
        float o = fmaxf((v - m) * r * g[ch] + be[ch], 0.f);
        y[(size_t)idx * 196 + s] = o;
        if (fT) fT[((size_t)b * 196 + s) * C + ch] = o;
        if (fTb) fTb[((size_t)b * 208 + s) * C + ch] = f2bf(o);
        if (xtc) {
            int G = C >> 6, gch = ch >> 6, cc = ch & 63;
            xtc[(((size_t)b * G + gch) * 208 + s) * 72 + cc] = f2bf(o);
        }
    }
}

// ---------------- CMSA/GCN batched MFMA GEMM, N-split (r18) ----------------
template <int MROWS, int MTILES, int KP, int KK, int EPI, int NS>
__global__ __launch_bounds__(256, 2) void k_bgemm(
    const unsigned short* __restrict__ Ab, size_t ABS,
    const unsigned short* __restrict__ Bb, size_t BBS,
    const float* __restrict__ bias,
    unsigned short* __restrict__ p0, unsigned short* __restrict__ p1,
    const float* __restrict__ resid, float* __restrict__ outf) {
    constexpr int KPS = KP + 8;
    __shared__ unsigned short xsA[64 * KPS];
    __shared__ char bbuf[2][208 * 64];
    const int tid = threadIdx.x, bx = blockIdx.x, b = blockIdx.y;
    const int wv = tid >> 6, lane = tid & 63, a = lane & 15, kg = lane >> 4;
    const int nh = bx % NS, mg = bx / NS;
    const int NT0 = (NS == 1) ? 0 : nh * 7;
    const int NTN = (NS == 1) ? 13 : ((nh == 0) ? 7 : 6);

    const unsigned short* Abase = Ab + (size_t)b * ABS;
    {
        const int rowu = KP / 2;
        for (int i = tid; i < 64 * rowu; i += 256) {
            int r = i / rowu, cu = i - r * rowu;
            int gr = mg * 64 + r; if (gr > MROWS - 1) gr = MROWS - 1;
            unsigned int v = ((const unsigned int*)(Abase + (size_t)gr * KP))[cu];
            *(unsigned int*)&xsA[r * KPS + cu * 2] = v;
        }
    }
    const char* Bbase = (const char*)(Bb + (size_t)b * BBS);
    auto stageB = [&](int kk) {
        char* dst0 = &bbuf[kk & 1][0];
        const int cnt = NTN * 64;
#pragma unroll
        for (int c = 0; c < 4; ++c) {
            int idx = tid + c * 256;
            if (idx < cnt) {
                int lrow = idx >> 2, u = idx & 3;
                int grow = NT0 * 16 + lrow;
                gas_void* src = (gas_void*)(Bbase + (size_t)grow * (KP * 2) +
                                            kk * 64 + u * 16);
                __builtin_amdgcn_global_load_lds(src, (las_void*)(dst0 + (size_t)idx * 16),
                                                 16, 0, 0);
            }
        }
    };

    int mt = mg * 4 + wv; if (mt > MTILES - 1) mt = MTILES - 1;
    const int arow = mt * 16 + a - mg * 64;

    f32x4 acc[13];
#pragma unroll
    for (int nt = 0; nt < 13; ++nt) acc[nt] = (f32x4){0.f, 0.f, 0.f, 0.f};

    stageB(0);
    __syncthreads();
    for (int kk = 0; kk < KK; ++kk) {
        if (kk + 1 < KK) stageB(kk + 1);
        bf16x8 Af = *(const bf16x8*)&xsA[arow * KPS + kk * 32 + kg * 8];
        const char* bb = &bbuf[kk & 1][0];
#pragma unroll
        for (int nt = 0; nt < 13; ++nt) {
            if (nt >= NT0 && nt < NT0 + NTN) {
                bf16x8 Bf = *(const bf16x8*)(bb + ((nt - NT0) * 16 + a) * 64 + kg * 16);
                acc[nt] = __builtin_amdgcn_mfma_f32_16x16x32_bf16(Af, Bf, acc[nt], 0, 0, 0);
            }
        }
        __syncthreads();
    }

    const int mbase = mt * 16 + kg * 4;
    if (EPI == 0) {
#pragma unroll
        for (int nt = 0; nt < 13; ++nt) {
            if (nt < NT0 || nt >= NT0 + NTN) continue;
            int col = nt * 16 + a;
            if (col < 196) {
#pragma unroll
                for (int j = 0; j < 4; ++j) {
                    int row = mbase + j;
                    if (row < 173) {
                        unsigned short h = f2bf(fmaxf(acc[nt][j] + bias[row], 0.f));
                        p0[((size_t)b * 176 + row) * 224 + col] = h;
                        p1[((size_t)b * 208 + col) * 192 + row] = h;
                    }
                }
            }
        }
    } else if (EPI == 1) {
#pragma unroll
        for (int j = 0; j < 4; ++j) {
            int row = mbase + j;
            float m = -3.4e38f;
#pragma unroll
            for (int nt = 0; nt < 13; ++nt) {
                int col = nt * 16 + a;
                float s = (col < 196) ? acc[nt][j] : -3.4e38f;
                m = fmaxf(m, s);
            }
            for (int msk = 1; msk < 16; msk <<= 1) m = fmaxf(m, __shfl_xor(m, msk));
            float e[13]; float sum = 0.f;
#pragma unroll
            for (int nt = 0; nt < 13; ++nt) {
                int col = nt * 16 + a;
                float v = (col < 196) ? expf(acc[nt][j] - m) : 0.f;
                e[nt] = v; sum += v;
            }
            for (int msk = 1; msk < 16; msk <<= 1) sum += __shfl_xor(sum, msk);
            float inv = 1.f / sum;
            if (row < 196) {
#pragma unroll
                for (int nt = 0; nt < 13; ++nt) {
                    int col = nt * 16 + a;
                    p0[((size_t)b * 208 + row) * 224 + col] = f2bf(e[nt] * inv);
                }
            }
        }
    } else if (EPI == 2) {
#pragma unroll
        for (int nt = 0; nt < 13; ++nt) {
            if (nt < NT0 || nt >= NT0 + NTN) continue;
            int col = nt * 16 + a;
#pragma unroll
            for (int j = 0; j < 4; ++j) {
                int row = mbase + j;
                if (row < 173)
                    p0[((size_t)b * 208 + col) * 192 + row] = f2bf(acc[nt][j]);
            }
        }
    } else if (EPI == 3) {
#pragma unroll
        for (int nt = 0; nt < 13; ++nt) {
            if (nt < NT0 || nt >= NT0 + NTN) continue;
            int col = nt * 16 + a;
            if (col < 196) {
#pragma unroll
                for (int j = 0; j < 4; ++j) {
                    int row = mbase + j;
                    if (row < 173) {
                        size_t rr = ((size_t)b * 173 + row) * 196 + col;
                        outf[rr] = fmaxf(acc[nt][j] + bias[row], 0.f) + resid[rr];
                    }
                }
            }
        }
    } else if (EPI == 7) {
#pragma unroll
        for (int nt = 0; nt < 13; ++nt) {
            if (nt < NT0 || nt >= NT0 + NTN) continue;
            int col = nt * 16 + a;
#pragma unroll
            for (int j = 0; j < 4; ++j) {
                int row = mbase + j;
                unsigned short h = (col < 196) ? f2bf(acc[nt][j]) : (unsigned short)0;
                p0[((size_t)b * 128 + row) * 224 + col] = h;
            }
        }
    } else {  // EPI == 8
#pragma unroll
        for (int nt = 0; nt < 13; ++nt) {
            if (nt < NT0 || nt >= NT0 + NTN) continue;
            int col = nt * 16 + a;
            if (col < 196) {
#pragma unroll
                for (int j = 0; j < 4; ++j) {
                    int row = mbase + j;
                    size_t rr = ((size_t)b * 128 + row) * 196 + col;
                    outf[rr] = fmaxf(acc[nt][j] + bias[col], 0.f) + resid[rr];
                }
            }
        }
    }
}

// ---------------- attention GEMM (scores EPI5 / proj EPI4), N-split (r18) --
template <int MROWS, int MTILES, int KPA, int KPB, int KK, int EPI, int STAGEA, int NS>
__global__ __launch_bounds__(256, 2) void k_agemm(
    const unsigned short* __restrict__ Ab, size_t ABS,
    const unsigned short* __restrict__ Bb, size_t BBS,
    const float* __restrict__ biasA, const float* __restrict__ biasB,
    const float* __restrict__ lnres, const float* __restrict__ res2,
    unsigned short* __restrict__ p0, size_t p0rs, size_t p0bs,
    float* __restrict__ feat, unsigned short* __restrict__ ftb, int cbase) {
    constexpr int KPS = KPA + 8;
    __shared__ unsigned short xsA[STAGEA ? 64 * KPS : 64];
    __shared__ char bbuf[2][208 * 64];
    const int tid = threadIdx.x, bx = blockIdx.x, b = blockIdx.y;
    const int wv = tid >> 6, lane = tid & 63, a = lane & 15, kg = lane >> 4;
    const int nh = bx % NS, mg = bx / NS;
    const int NT0 = (NS == 1) ? 0 : nh * 7;
    const int NTN = (NS == 1) ? 13 : ((nh == 0) ? 7 : 6);

    const unsigned short* Abase = Ab + (size_t)b * ABS;
    if (STAGEA) {
        const int rowu = KPA / 2;
        for (int i = tid; i < 64 * rowu; i += 256) {
            int r = i / rowu, cu = i - r * rowu;
            int gr = mg * 64 + r; if (gr > MROWS - 1) gr = MROWS - 1;
            unsigned int v = ((const unsigned int*)(Abase + (size_t)gr * KPA))[cu];
            *(unsigned int*)&xsA[r * KPS + cu * 2] = v;
        }
    }
    const char* Bbase = (const char*)(Bb + (size_t)b * BBS);
    auto stageB = [&](int kk) {
        char* dst0 = &bbuf[kk & 1][0];
        const int cnt = NTN * 64;
#pragma unroll
        for (int c = 0; c < 4; ++c) {
            int idx = tid + c * 256;
            if (idx < cnt) {
                int lrow = idx >> 2, u = idx & 3;
                int grow = NT0 * 16 + lrow;
                gas_void* src = (gas_void*)(Bbase + (size_t)grow * (KPB * 2) +
                                            kk * 64 + u * 16);
                __builtin_amdgcn_global_load_lds(src, (las_void*)(dst0 + (size_t)idx * 16),
                                                 16, 0, 0);
            }
        }
    };

    int mt = mg * 4 + wv; if (mt > MTILES - 1) mt = MTILES - 1;

    f32x4 acc[13];
#pragma unroll
    for (int nt = 0; nt < 13; ++nt) acc[nt] = (f32x4){0.f, 0.f, 0.f, 0.f};

    stageB(0);
    __syncthreads();
    for (int kk = 0; kk < KK; ++kk) {
        if (kk + 1 < KK) stageB(kk + 1);
        bf16x8 Af;
        if (STAGEA) {
            int arow = mt * 16 + a - mg * 64;
            Af = *(const bf16x8*)&xsA[arow * KPS + kk * 32 + kg * 8];
        } else {
            int gr = mt * 16 + a; if (gr > MROWS - 1) gr = MROWS - 1;
            Af = *(const bf16x8*)(Abase + (size_t)gr * KPA + kk * 32 + kg * 8);
        }
        const char* bb = &bbuf[kk & 1][0];
#pragma unroll
        for (int nt = 0; nt < 13; ++nt) {
            if (nt >= NT0 && nt < NT0 + NTN) {
                bf16x8 Bf = *(const bf16x8*)(bb + ((nt - NT0) * 16 + a) * 64 + kg * 16);
                acc[nt] = __builtin_amdgcn_mfma_f32_16x16x32_bf16(Af, Bf, acc[nt], 0, 0, 0);
            }
        }
        __syncthreads();
    }

    const int mbase = mt * 16 + kg * 4;
    if (EPI == 5) {
#pragma unroll
        for (int j = 0; j < 4; ++j) {
            int row = mbase + j;
            float mA = -3.4e38f, mB = -3.4e38f;
#pragma unroll
            for (int nt = 0; nt < 8; ++nt) mA = fmaxf(mA, acc[nt][j]);
#pragma unroll
            for (int nt = 8; nt < 13; ++nt) {
                int col = nt * 16 + a;
                float s = (col < 173) ? acc[nt][j] : -3.4e38f;
                mB = fmaxf(mB, s);
            }
            for (int msk = 1; msk < 16; msk <<= 1) {
                mA = fmaxf(mA, __shfl_xor(mA, msk));
                mB = fmaxf(mB, __shfl_xor(mB, msk));
            }
            float eA[8], eB[5];
            float sA = 0.f, sB = 0.f;
#pragma unroll
            for (int nt = 0; nt < 8; ++nt) { eA[nt] = expf(acc[nt][j] - mA); sA += eA[nt]; }
#pragma unroll
            for (int nt = 8; nt < 13; ++nt) {
                int col = nt * 16 + a;
                float v = (col < 173) ? expf(acc[nt][j] - mB) : 0.f;
                eB[nt - 8] = v; sB += v;
            }
            for (int msk = 1; msk < 16; msk <<= 1) {
                sA += __shfl_xor(sA, msk);
                sB += __shfl_xor(sB, msk);
            }
            float iA = 1.f / sA, iB = 1.f / sB;
            if (row < MROWS) {
#pragma unroll
                for (int nt = 0; nt < 12; ++nt) {
                    int col = nt * 16 + a;
                    float v = (nt < 8) ? eA[nt] * iA
                                       : ((col < 173) ? eB[nt - 8] * iB : 0.f);
                    p0[(size_t)b * p0bs + (size_t)row * p0rs + col] = f2bf(v);
                }
            }
        }
    } else {  // EPI == 4
#pragma unroll
        for (int nt = 0; nt < 13; ++nt) {
            if (nt < NT0 || nt >= NT0 + NTN) continue;
            int col = nt * 16 + a;
            if (col < 196) {
#pragma unroll
                for (int j = 0; j < 4; ++j) {
                    int row = mbase + j;
                    if (row < MROWS) {
                        size_t rr = ((size_t)b * MROWS + row) * 196 + col;
                        float v = acc[nt][j] + biasA[col] + biasB[col] +
                                  lnres[rr] + res2[rr];
                        feat[((size_t)b * 173 + cbase + row) * 196 + col] = v;
                        ftb[((size_t)(b * 208 + col)) * 192 + cbase + row] = f2bf(v);
                    }
                }
            }
        }
    }
}

// ---------------- PV merged kernel (r18) ----------------
template <int MROWS, int MTILES, int NS>
__global__ __launch_bounds__(256, 2) void k_pv(
    const unsigned short* __restrict__ P, size_t Pbs,
    const unsigned short* __restrict__ V1, size_t V1bs,
    const unsigned short* __restrict__ V2, size_t V2bs,
    unsigned short* __restrict__ F, size_t Fbs) {
    constexpr int KPS = 200;
    __shared__ unsigned short xsA[64 * KPS];
    __shared__ char bbuf[2][208 * 64];
    const int tid = threadIdx.x, bx = blockIdx.x, b = blockIdx.y;
    const int wv = tid >> 6, lane = tid & 63, a = lane & 15, kg = lane >> 4;
    const int nh = bx % NS, mg = bx / NS;
    const int NT0 = (NS == 1) ? 0 : nh * 7;
    const int NTN = (NS == 1) ? 13 : ((nh == 0) ? 7 : 6);

    const unsigned short* Abase = P + (size_t)b * Pbs;
    {
        for (int i = tid; i < 64 * 96; i += 256) {
            int r = i / 96, cu = i - r * 96;
            int gr = mg * 64 + r; if (gr > MROWS - 1) gr = MROWS - 1;
            unsigned int v = ((const unsigned int*)(Abase + (size_t)gr * 192))[cu];
            *(unsigned int*)&xsA[r * KPS + cu * 2] = v;
        }
    }
    int mt = mg * 4 + wv; if (mt > MTILES - 1) mt = MTILES - 1;
    const int arow = mt * 16 + a - mg * 64;
    const int mbase = mt * 16 + kg * 4;

    auto run = [&](const unsigned short* Vb, size_t Vbs_, int KPB, int KK,
                   int AOFFe, int outoff) {
        f32x4 acc[13];
#pragma unroll
        for (int nt = 0; nt < 13; ++nt) acc[nt] = (f32x4){0.f, 0.f, 0.f, 0.f};
        const char* Bbase = (const char*)(Vb + (size_t)b * Vbs_);
        auto stageB = [&](int kk) {
            char* dst0 = &bbuf[kk & 1][0];
            const int cnt = NTN * 64;
#pragma unroll
            for (int c = 0; c < 4; ++c) {
                int idx = tid + c * 256;
                if (idx < cnt) {
                    int lrow = idx >> 2, u = idx & 3;
                    int grow = NT0 * 16 + lrow;
                    gas_void* src = (gas_void*)(Bbase + (size_t)grow * (KPB * 2) +
                                                kk * 64 + u * 16);
                    __builtin_amdgcn_global_load_lds(src,
                        (las_void*)(dst0 + (size_t)idx * 16), 16, 0, 0);
                }
            }
        };
        stageB(0);
        __syncthreads();
        for (int kk = 0; kk < KK; ++kk) {
            if (kk + 1 < KK) stageB(kk + 1);
            bf16x8 Af = *(const bf16x8*)&xsA[arow * KPS + AOFFe + kk * 32 + kg * 8];
            const char* bb = &bbuf[kk & 1][0];
#pragma unroll
            for (int nt = 0; nt < 13; ++nt) {
                if (nt >= NT0 && nt < NT0 + NTN) {
                    bf16x8 Bf = *(const bf16x8*)(bb + ((nt - NT0) * 16 + a) * 64 + kg * 16);
                    acc[nt] = __builtin_amdgcn_mfma_f32_16x16x32_bf16(Af, Bf, acc[nt], 0, 0, 0);
                }
            }
            __syncthreads();
        }
#pragma unroll
        for (int nt = 0; nt < 13; ++nt) {
            if (nt < NT0 || nt >= NT0 + NTN) continue;
            int col = nt * 16 + a;
#pragma unroll
            for (int j = 0; j < 4; ++j) {
                int row = mbase + j;
                if (row < MROWS) {
                    unsigned short h = (col < 196) ? f2bf(acc[nt][j]) : (unsigned short)0;
                    F[(size_t)b * Fbs + (size_t)row * 448 + outoff + col] = h;
                }
            }
        }
        if (nh == NS - 1) {
            int col = 208 + a;
#pragma unroll
            for (int j = 0; j < 4; ++j) {
                int row = mbase + j;
                if (row < MROWS)
                    F[(size_t)b * Fbs + (size_t)row * 448 + outoff + col] = 0;
            }
        }
    };
    run(V1, V1bs, 128, 4, 0, 0);
    run(V2, V2bs, 64, 2, 128, 224);
}

// ---------------- GCN spmm+fin text (fp32, r18) ----------------
template <int C, int ROWS>
__global__ void k_gcn_spmmfin_t(const float* __restrict__ dist, const float* __restrict__ f,
                                const float* __restrict__ wt, const float* __restrict__ bias,
                                float* __restrict__ outp) {
    __shared__ float ds[ROWS][C];
    __shared__ float ts[ROWS][196];
    const int i0 = blockIdx.x * ROWS, b = blockIdx.y;
    const int tid = threadIdx.x;
    for (int idx = tid; idx < ROWS * C; idx += 256) {
        int r = idx / C, j = idx - r * C;
        ds[r][j] = dist[((size_t)(b * C + i0 + r)) * C + j];
    }
    __syncthreads();
    if (tid < 196) {
        float a[ROWS];
#pragma unroll
        for (int r = 0; r < ROWS; ++r) a[r] = 0.f;
#pragma unroll 4
        for (int j = 0; j < C; ++j) {
            float v = f[((size_t)b * C + j) * 196 + tid];
#pragma unroll
            for (int r = 0; r < ROWS; ++r) a[r] += ds[r][j] * v;
        }
#pragma unroll
        for (int r = 0; r < ROWS; ++r) ts[r][tid] = a[r];
    }
    __syncthreads();
    if (tid < 196) {
        float a[ROWS];
        float bi = bias[tid];
#pragma unroll
        for (int r = 0; r < ROWS; ++r) a[r] = bi;
#pragma unroll 4
        for (int n = 0; n < 196; ++n) {
            float wv = wt[(size_t)n * 196 + tid];
#pragma unroll
            for (int r = 0; r < ROWS; ++r) a[r] += ts[r][n] * wv;
        }
#pragma unroll
        for (int r = 0; r < ROWS; ++r) {
            size_t rr = ((size_t)(b * C + i0 + r)) * 196 + tid;
            outp[rr] = fmaxf(a[r], 0.f) + f[rr];
        }
    }
}

// ---------------- textbuild (r18) ----------------
__global__ void k_textbuild(const float* __restrict__ toh, const float* __restrict__ tnm,
                            float* __restrict__ text, float* __restrict__ textT) {
    int idx = blockIdx.x;
    int b = idx / 45, c = idx - b * 45;
    int s = threadIdx.x;
    if (s < 196) {
        float v = (c < 30) ? toh[b * 196 + s] : tnm[b * 196 + s];
        text[(size_t)idx * 196 + s] = v;
        textT[((size_t)b * 196 + s) * 45 + c] = v;
    }
}

// ---------------- LN + projection body (template) ----------------
template <int R, int ROWS, int KOFF, int TS>
__device__ __forceinline__ void d_lnlin(const float* __restrict__ x,
                                        const float* __restrict__ g,
                                        const float* __restrict__ be,
                                        const float* __restrict__ eT,
                                        const float* __restrict__ eb,
                                        float* __restrict__ lnout,
                                        unsigned short* __restrict__ kcat,
                                        unsigned short* __restrict__ tbuf,
                                        int bx, int b) {
    __shared__ float ls[ROWS][196];
    const int i0 = bx * ROWS;
    const int tid = threadIdx.x;
    const int wv = tid >> 6, lane = tid & 63;
    for (int idx = tid; idx < ROWS * 196; idx += 256) {
        int r = idx / 196, n = idx - r * 196;
        ls[r][n] = x[((size_t)(b * R + i0 + r)) * 196 + n];
    }
    __syncthreads();
    for (int k = 0;; ++k) {
        int r = wv + 4 * k;
        if (r >= ROWS) break;
        float s = 0.f, s2 = 0.f;
        for (int j = lane; j < 196; j += 64) { float v = ls[r][j]; s += v; s2 += v * v; }
        for (int sh = 32; sh; sh >>= 1) { s += __shfl_xor(s, sh); s2 += __shfl_xor(s2, sh); }
        float mean = s / 196.f;
        float var = s2 / 196.f - mean * mean;
        float rstd = rsqrtf(var + 1e-6f);
        size_t rowo = ((size_t)(b * R + i0 + r)) * 196;
        for (int j = lane; j < 196; j += 64) {
            float l = (ls[r][j] - mean) * rstd * g[j] + be[j];
            ls[r][j] = l;
            lnout[rowo + j] = l;
        }
    }
    __syncthreads();
    if (tid < 224) {
        float a[ROWS];
        if (tid < 196) {
            float bi = eb[tid];
#pragma unroll
            for (int r = 0; r < ROWS; ++r) a[r] = bi;
#pragma unroll 4
            for (int n = 0; n < 196; ++n) {
                float ev = eT[(size_t)n * 196 + tid];
#pragma unroll
                for (int r = 0; r < ROWS; ++r) a[r] += ls[r][n] * ev;
            }
        }
#pragma unroll
        for (int r = 0; r < ROWS; ++r) {
            unsigned short h = 0;
            if (tid < 196) h = f2bf(fmaxf(a[r], 0.f));
            kcat[((size_t)(b * 208 + KOFF + i0 + r)) * 224 + tid] = h;
            if (tid < 196) tbuf[((size_t)(b * 208 + tid)) * TS + (i0 + r)] = h;
        }
    }
}

// merged LN kernels — grid 1504
__global__ void k_lnlin_both(const float* __restrict__ ximg, const float* __restrict__ g1,
                             const float* __restrict__ b1, const float* __restrict__ e1T,
                             const float* __restrict__ e1b, float* __restrict__ ln1out,
                             const float* __restrict__ xtxt, const float* __restrict__ g2,
                             const float* __restrict__ b2, const float* __restrict__ e2T,
                             const float* __restrict__ e2b, float* __restrict__ ln2out,
                             unsigned short* __restrict__ kcat,
                             unsigned short* __restrict__ iqT,
                             unsigned short* __restrict__ tqT) {
    int blk = blockIdx.x;
    if (blk < 1024)
        d_lnlin<128, 4, 0, 128>(ximg, g1, b1, e1T, e1b, ln1out, kcat, iqT,
                                blk & 31, blk >> 5);
    else {
        int r = blk - 1024;
        d_lnlin<45, 3, 128, 64>(xtxt, g2, b2, e2T, e2b, ln2out, kcat, tqT,
                                r % 15, r / 15);
    }
}

// ---------------- final classifier (rowsum fused) ----------------
__global__ void k_finale(const float* __restrict__ toh, const float* __restrict__ tnm,
                         const float* __restrict__ cms, const float* __restrict__ cls_w,
                         const float* __restrict__ cls_b, float* __restrict__ out) {
    int b = blockIdx.x;
    __shared__ float pcm[173];
    __shared__ float r1[4], r2[4];
    int tid = threadIdx.x;
    float a = (tid < 196) ? toh[b * 196 + tid] : 0.f;
    float c = (tid < 196) ? tnm[b * 196 + tid] : 0.f;
    for (int sh = 32; sh; sh >>= 1) { a += __shfl_xor(a, sh); c += __shfl_xor(c, sh); }
    if ((tid & 63) == 0) { r1[tid >> 6] = a; r2[tid >> 6] = c; }
    if (tid < 173) {
        float s = 0.f;
        const float* p = &cms[((size_t)b * 173 + tid) * 196];
        for (int n = 0; n < 196; ++n) s += p[n];
        pcm[tid] = s;
    }
    __syncthreads();
    if (tid < 2) {
        float soh = r1[0] + r1[1] + r1[2] + r1[3];
        float snm = r2[0] + r2[1] + r2[2] + r2[3];
        const float* wrow = &cls_w[tid * 218];
        float acc = cls_b[tid];
        float w1 = 0.f, w2 = 0.f;
        for (int k = 0; k < 30; ++k) w1 += wrow[k];
        for (int k = 30; k < 45; ++k) w2 += wrow[k];
        acc += soh * w1 + snm * w2;
        for (int k = 0; k < 173; ++k) acc += wrow[45 + k] * pcm[k];
        out[b * 2 + tid] = acc;
    }
}

// ---------------------------------------------------------------------------
extern "C" void kernel_launch(void* const* d_in, const int* in_sizes, int n_in,
                              void* d_out, int out_size, void* d_ws, size_t ws_size,
                              hipStream_t stream) {
    const float* x      = (const float*)d_in[0];
    const float* oneHot = (const float*)d_in[1];
    const float* num    = (const float*)d_in[2];
    const float* c1_w1  = (const float*)d_in[3];
    const float* c1_g1  = (const float*)d_in[5];
    const float* c1_be1 = (const float*)d_in[6];
    const float* c1_w2  = (const float*)d_in[7];
    const float* c1_g2  = (const float*)d_in[9];
    const float* c1_be2 = (const float*)d_in[10];
    const float* oh_w   = (const float*)d_in[11];
    const float* oh_b   = (const float*)d_in[12];
    const float* oh_g   = (const float*)d_in[13];
    const float* oh_be  = (const float*)d_in[14];
    const float* nm_w   = (const float*)d_in[15];
    const float* nm_b   = (const float*)d_in[16];
    const float* nm_g   = (const float*)d_in[17];
    const float* nm_be  = (const float*)d_in[18];
    const float* gm1_w  = (const float*)d_in[19];
    const float* gm1_b  = (const float*)d_in[20];
    const float* gm2_w  = (const float*)d_in[21];
    const float* gm2_b  = (const float*)d_in[22];
    const float* ln1_g  = (const float*)d_in[23];
    const float* ln1_b  = (const float*)d_in[24];
    const float* ln2_g  = (const float*)d_in[25];
    const float* ln2_b  = (const float*)d_in[26];
    const float* e1_w   = (const float*)d_in[27];
    const float* e1_b   = (const float*)d_in[28];
    const float* e2_w   = (const float*)d_in[29];
    const float* e2_b   = (const float*)d_in[30];
    const float* f1_w   = (const float*)d_in[31];
    const float* f1_b   = (const float*)d_in[32];
    const float* f2_w   = (const float*)d_in[33];
    const float* f2_b   = (const float*)d_in[34];
    const float* f3_w   = (const float*)d_in[35];
    const float* f3_b   = (const float*)d_in[36];
    const float* f4_w   = (const float*)d_in[37];
    const float* f4_b   = (const float*)d_in[38];
    const float* cm_w   = (const float*)d_in[39];
    const float* cm_b   = (const float*)d_in[40];
    const float* cmf_w  = (const float*)d_in[41];
    const float* cmf_b  = (const float*)d_in[42];
    const float* cls_w  = (const float*)d_in[43];
    const float* cls_b  = (const float*)d_in[44];
    float* out = (float*)d_out;
    float* W = (float*)d_ws;

    const size_t L = 802816;
    const size_t T = 282240;
    const size_t F3 = 1085056;
    // ---- layout (floats); identical to r18 ----
    const size_t o_A    = 0;
    const size_t o_B    = L;
    const size_t o_C    = 2 * L;
    const size_t o_part = 3 * L;
    const size_t o_Kcat = 3 * L;
    const size_t o_iqT  = o_Kcat + 745472;
    const size_t o_t1   = 4 * L + T;
    const size_t o_t3   = 4 * L + 2 * T;
    const size_t o_ln2  = 4 * L + 3 * T;
    const size_t o_toh  = 4 * L + 4 * T;
    const size_t o_tnm  = o_toh + 6272;
    const size_t o_st   = o_tnm + 6272;
    const size_t o_wT   = o_st + 1024;
    const size_t o_feat = o_wT + 8 * 38416;
    const size_t o_q    = o_feat + F3;
    const size_t o_Fimg = o_q;
    const size_t o_dd   = o_q + F3;
    const size_t o_db   = o_dd;
    const size_t o_d2   = o_dd + 524288;
    const size_t o_gm1b = o_dd + 589088;
    const size_t o_fTb  = o_dd + 612384;
    const size_t o_tqT  = o_dd;
    const size_t o_wcI  = o_dd + 212992;
    const size_t o_wcT  = o_wcI + 46592;
    const size_t o_pbf  = o_dd;
    const size_t o_rs   = o_dd;
    const size_t o_qbf  = o_dd + 745472;
    const size_t o_Ftxt = o_qbf;
    const size_t o_wcm  = o_qbf + 630784;
    const size_t o_wcmf = o_wcm + 16896;
    const size_t o_ftb  = o_wcmf + 16896;
    const size_t o_tr   = o_ftb + 638976;
    const size_t o_Pimg = o_tr;
    const size_t o_Ptxt = o_tr + 393216;
    const size_t o_qtb  = o_tr;
    const size_t o_feab = o_qtb + 638976;
    const size_t o_ps   = 10158208;
    const size_t o_xt1 = o_dd;
    const size_t o_xt2 = o_xt1 + 1198080;
    const size_t o_wp1 = o_xt2 + 479232;
    const size_t o_wp2 = o_wp1 + 552960;

    float* part = W + o_part;
    unsigned short* xt1 = (unsigned short*)(W + o_xt1);
    unsigned short* xt2 = (unsigned short*)(W + o_xt2);
    unsigned short* wp1 = (unsigned short*)(W + o_wp1);
    unsigned short* wp2 = (unsigned short*)(W + o_wp2);
    unsigned short* kcatb = (unsigned short*)(W + o_Kcat);
    unsigned short* iqTb = (unsigned short*)(W + o_iqT);
    unsigned short* tqTb = (unsigned short*)(W + o_tqT);
    unsigned short* wcatI = (unsigned short*)(W + o_wcI);
    unsigned short* wcatT = (unsigned short*)(W + o_wcT);
    unsigned short* Fimg = (unsigned short*)(W + o_Fimg);
    unsigned short* Ftxt = (unsigned short*)(W + o_Ftxt);
    unsigned short* Pimg = (unsigned short*)(W + o_Pimg);
    unsigned short* Ptxt = (unsigned short*)(W + o_Ptxt);
    unsigned short* ftb = (unsigned short*)(W + o_ftb);
    unsigned short* qtb = (unsigned short*)(W + o_qtb);
    unsigned short* feab = (unsigned short*)(W + o_feab);
    unsigned short* qbf = (unsigned short*)(W + o_qbf);
    unsigned short* wcmb = (unsigned short*)(W + o_wcm);
    unsigned short* wcmfb = (unsigned short*)(W + o_wcmf);
    unsigned short* pbf = (unsigned short*)(W + o_pbf);
    unsigned short* distb = (unsigned short*)(W + o_db);
    unsigned short* gm1b = (unsigned short*)(W + o_gm1b);
    unsigned short* fTb = (unsigned short*)(W + o_fTb);
    unsigned short* tmpb = (unsigned short*)(W + o_A);
    float* gm2T = W + o_wT + 0 * 38416;
    float* e1T  = W + o_wT + 1 * 38416;
    float* e2T  = W + o_wT + 2 * 38416;

    // 1: conv prep (wpack x2 + xt_c)
    k_prep1<<<5460, 256, 0, stream>>>(c1_w1, wp1, c1_w2, wp2, x, xt1);

    // 2-4: conv1 + reduce/stats + BN
    k_convchunk4<320, 5, 4, 2><<<dim3(20, 32), 256, 0, stream>>>(xt1, wp1, part);
    k_reduce_stats<5, 128><<<dim3(128, 32), 256, 0, stream>>>(part, W + o_A, W + o_ps);
    k_bn_apply2<<<4096, 256, 0, stream>>>(W + o_A, W + o_ps, c1_g1, c1_be1,
                                          nullptr, nullptr, xt2, 128);

    // 5-7: conv2 + reduce/stats + BN (emits fT fp32 + fTb bf16)
    k_convchunk4<128, 2, 2, 4><<<dim3(16, 32), 256, 0, stream>>>(xt2, wp2, part);
    k_reduce_stats<2, 128><<<dim3(128, 32), 256, 0, stream>>>(part, W + o_B,
                                                              W + o_ps + 8192);
    k_bn_apply2<<<4096, 256, 0, stream>>>(W + o_B, W + o_ps + 8192, c1_g2, c1_be2,
                                          W + o_tr, fTb, nullptr, 128);

    // 8: post-conv packs (w173 x2 + gm1 pad + ftb zero + transposes)
    k_prep2<<<1658, 256, 0, stream>>>(cm_w, wcmb, cmf_w, wcmfb, gm1_w, gm1b,
                                      (float4*)(W + o_ftb), gm2_w, e1_w, e2_w, W + o_wT);

    // 9-10: catnum (merged) + textbuild
    k_catnum2<<<392, 64, 0, stream>>>(oneHot, num, oh_w, oh_b, oh_g, oh_be,
                                      nm_w, nm_b, nm_g, nm_be, W + o_toh, W + o_tnm);
    k_textbuild<<<32 * 45, 256, 0, stream>>>(W + o_toh, W + o_tnm, W + o_t1, W + o_tr + L);

    // 11: merged GCN dists (img bf16 out + txt fp32 out)
    k_dist_both<<<1504, 256, 0, stream>>>(W + o_B, W + o_tr, distb,
                                          W + o_t1, W + o_tr + L, W + o_d2);

    // 12-13: GCN img via MFMA
    k_bgemm<128, 8, 128, 4, 7, 2><<<dim3(4, 32), 256, 0, stream>>>(
        distb, (size_t)128 * 128, fTb, (size_t)208 * 128, nullptr,
        tmpb, nullptr, nullptr, nullptr);
    k_bgemm<128, 8, 224, 7, 8, 2><<<dim3(4, 32), 256, 0, stream>>>(
        tmpb, (size_t)128 * 224, gm1b, 0, gm1_b,
        nullptr, nullptr, W + o_B, W + o_C);

    // 14: GCN text spmm+fin
    k_gcn_spmmfin_t<45, 3><<<dim3(15, 32), 256, 0, stream>>>(W + o_d2, W + o_t1, gm2T,
                                                             gm2_b, W + o_t3);

    // 15: zero tqT + Wcat packs
    k_prep3<<<936, 256, 0, stream>>>((float4*)(W + o_tqT), f1_w, f3_w, wcatI,
                                     f4_w, f2_w, wcatT);

    // 16: merged LN + q projections
    k_lnlin_both<<<1504, 256, 0, stream>>>(W + o_C, ln1_g, ln1_b, e1T, e1_b, W + o_B,
                                           W + o_t3, ln2_g, ln2_b, e2T, e2_b, W + o_ln2,
                                           kcatb, iqTb, tqTb);

    // 17-18: attention scores + dual softmax
    k_agemm<128, 8, 224, 224, 7, 5, 1, 1><<<dim3(2, 32), 256, 0, stream>>>(
        kcatb, (size_t)208 * 224, kcatb, (size_t)208 * 224,
        nullptr, nullptr, nullptr, nullptr, Pimg, 192, (size_t)128 * 192,
        nullptr, nullptr, 0);
    k_agemm<45, 3, 224, 224, 7, 5, 1, 1><<<dim3(1, 32), 256, 0, stream>>>(
        kcatb + 128 * 224, (size_t)208 * 224, kcatb, (size_t)208 * 224,
        nullptr, nullptr, nullptr, nullptr, Ptxt, 192, (size_t)48 * 192,
        nullptr, nullptr, 0);

    // 19-20: merged PV
    k_pv<128, 8, 2><<<dim3(4, 32), 256, 0, stream>>>(
        Pimg, (size_t)128 * 192, iqTb, (size_t)208 * 128, tqTb, (size_t)208 * 64,
        Fimg, (size_t)128 * 448);
    k_pv<45, 3, 2><<<dim3(2, 32), 256, 0, stream>>>(
        Ptxt, (size_t)48 * 192, iqTb, (size_t)208 * 128, tqTb, (size_t)208 * 64,
        Ftxt, (size_t)48 * 448);

    // 21-22: projection + residuals -> feat + ftb
    k_agemm<128, 8, 448, 448, 14, 4, 0, 2><<<dim3(4, 32), 256, 0, stream>>>(
        Fimg, (size_t)128 * 448, wcatI, 0,
        f1_b, f3_b, W + o_B, W + o_C, nullptr, 0, 0, W + o_feat, ftb, 0);
    k_agemm<45, 3, 448, 448, 14, 4, 0, 2><<<dim3(2, 32), 256, 0, stream>>>(
        Ftxt, (size_t)48 * 448, wcatT, 0,
        f2_b, f4_b, W + o_ln2, W + o_t3, nullptr, 0, 0, W + o_feat, ftb, 128);

    // 23: CMSA zeros (pbf+qbf contig, qtb+feab contig)
    k_prep4<<<2592, 256, 0, stream>>>((float4*)(W + o_pbf), (float4*)(W + o_qtb));

    // 24-27: CMSA GEMMs
    k_bgemm<176, 11, 192, 6, 0, 2><<<dim3(6, 32), 256, 0, stream>>>(
        wcmb, 0, ftb, (size_t)208 * 192, cm_b, qbf, qtb, nullptr, nullptr);
    k_bgemm<208, 13, 192, 6, 1, 1><<<dim3(4, 32), 256, 0, stream>>>(
        qtb, (size_t)208 * 192, qtb, (size_t)208 * 192, nullptr, pbf, nullptr,
        nullptr, nullptr);
    k_bgemm<176, 11, 224, 7, 2, 2><<<dim3(6, 32), 256, 0, stream>>>(
        qbf, (size_t)176 * 224, pbf, (size_t)208 * 224, nullptr, feab, nullptr,
        nullptr, nullptr);
    k_bgemm<176, 11, 192, 6, 3, 2><<<dim3(6, 32), 256, 0, stream>>>(
        wcmfb, 0, feab, (size_t)208 * 192, cmf_b, nullptr, nullptr,
        W + o_feat, W + o_q);

    // 28: final classifier (rowsum fused)
    k_finale<<<32, 256, 0, stream>>>(W + o_toh, W + o_tnm, W + o_q, cls_w, cls_b, out);
}

// Round 20
// 317.876 us; speedup vs baseline: 1.5298x; 1.1638x over previous
//
#include <hip/hip_runtime.h>
#include <hip/hip_bf16.h>

// ---------------------------------------------------------------------------
// mv3Dunet_down_text_cmsa forward. Round 20: 28 -> 23 launches.
// img+txt attention kernels unified via runtime M-params (scores/PV/proj each
// one launch), GCN img-GEMM || txt-spmmfin merged, catnum writes text directly.
// Arithmetic identical to round 19.
// ---------------------------------------------------------------------------

using bf16x8 = __attribute__((ext_vector_type(8))) short;
using f32x4  = __attribute__((ext_vector_type(4))) float;

typedef const __attribute__((address_space(1))) void gas_void;
typedef __attribute__((address_space(3))) void las_void;

__device__ __forceinline__ unsigned short f2bf(float f) {
    unsigned int u = __float_as_uint(f);
    u += 0x7FFFu + ((u >> 16) & 1u);
    return (unsigned short)(u >> 16);
}

// ================= small helpers =================
__device__ __forceinline__ void d_wpack(const float* __restrict__ w,
                                        unsigned short* __restrict__ wp,
                                        int IC, int idx) {
    int nc = IC >> 3;
    if (idx >= 27 * 128 * nc) return;
    int c = idx % nc; int r = idx / nc; int oc = r & 127; int t = r >> 7;
    const float* ws = w + ((size_t)oc * IC + c * 8) * 27 + t;
    unsigned int o0 = f2bf(ws[0])   | ((unsigned int)f2bf(ws[27])  << 16);
    unsigned int o1 = f2bf(ws[54])  | ((unsigned int)f2bf(ws[81])  << 16);
    unsigned int o2 = f2bf(ws[108]) | ((unsigned int)f2bf(ws[135]) << 16);
    unsigned int o3 = f2bf(ws[162]) | ((unsigned int)f2bf(ws[189]) << 16);
    uint4 v; v.x = o0; v.y = o1; v.z = o2; v.w = o3;
    ((uint4*)wp)[idx] = v;
}

__device__ __forceinline__ void d_w173(const float* __restrict__ w,
                                       unsigned short* __restrict__ wb, int idx) {
    if (idx >= 176 * 192) return;
    int oc = idx / 192, c = idx - oc * 192;
    wb[idx] = (oc < 173 && c < 173) ? f2bf(w[(size_t)oc * 173 + c]) : (unsigned short)0;
}

__device__ __forceinline__ void d_wcat(const float* __restrict__ wA,
                                       const float* __restrict__ wB,
                                       unsigned short* __restrict__ outw, int idx) {
    if (idx >= 208 * 448) return;
    int n = idx / 448, k = idx - n * 448;
    unsigned short v = 0;
    if (n < 196) {
        if (k < 196) v = f2bf(wA[(size_t)n * 196 + k]);
        else if (k >= 224 && k < 420) v = f2bf(wB[(size_t)n * 196 + (k - 224)]);
    }
    outw[idx] = v;
}

// ================= merged prep kernels =================
__global__ void k_prep1(const float* __restrict__ c1w1, unsigned short* __restrict__ wp1,
                        const float* __restrict__ c1w2, unsigned short* __restrict__ wp2,
                        const float* __restrict__ x, unsigned short* __restrict__ xt1) {
    int blk = blockIdx.x, tid = threadIdx.x;
    if (blk < 540) { d_wpack(c1w1, wp1, 320, blk * 256 + tid); return; }
    blk -= 540;
    if (blk < 216) { d_wpack(c1w2, wp2, 128, blk * 256 + tid); return; }
    blk -= 216;
    int b = blk / 147, ib = blk - b * 147;
    const int tot = 5 * 208 * 36;
    int idx = ib * 256 + tid;
    if (idx >= tot) return;
    int g = idx / (208 * 36); int r2 = idx - g * (208 * 36);
    int s = r2 / 36, cp = r2 - s * 36;
    int cc = cp * 2;
    int ic = g * 64 + cc;
    unsigned int lo = 0, hi = 0;
    if (s < 196 && cc < 64 && ic < 320)         lo = f2bf(x[((size_t)b * 320 + ic) * 196 + s]);
    if (s < 196 && cc + 1 < 64 && ic + 1 < 320) hi = f2bf(x[((size_t)b * 320 + ic + 1) * 196 + s]);
    ((unsigned int*)xt1)[(size_t)b * tot + idx] = lo | (hi << 16);
}

__global__ void k_prep2(const float* __restrict__ cm_w, unsigned short* __restrict__ wcmb,
                        const float* __restrict__ cmf_w, unsigned short* __restrict__ wcmfb,
                        const float* __restrict__ gm1_w, unsigned short* __restrict__ gm1b,
                        float4* __restrict__ ftbz,
                        const float* __restrict__ gm2_w, const float* __restrict__ e1_w,
                        const float* __restrict__ e2_w, float* __restrict__ wT) {
    int blk = blockIdx.x, tid = threadIdx.x;
    if (blk < 132) { d_w173(cm_w, wcmb, blk * 256 + tid); return; }
    blk -= 132;
    if (blk < 132) { d_w173(cmf_w, wcmfb, blk * 256 + tid); return; }
    blk -= 132;
    if (blk < 182) {
        int idx = blk * 256 + tid;
        if (idx < 208 * 224) {
            int r = idx / 224, c = idx - r * 224;
            gm1b[idx] = (r < 196 && c < 196) ? f2bf(gm1_w[(size_t)r * 196 + c])
                                             : (unsigned short)0;
        }
        return;
    }
    blk -= 182;
    if (blk < 624) {
        int i = blk * 256 + tid;
        if (i < 159744) ftbz[i] = (float4){0.f, 0.f, 0.f, 0.f};
        return;
    }
    blk -= 624;
    {
        int m = blk / 196, i = blk - m * 196;
        const float* w = (m == 0) ? gm2_w : (m == 1) ? e1_w : e2_w;
        float* o = wT + (size_t)m * 38416;
        if (tid < 196) o[(size_t)i * 196 + tid] = w[(size_t)tid * 196 + i];
    }
}

// catnum + direct text/textT emission — grid 392, 64 threads
__global__ void k_cattext(const float* __restrict__ oneHot, const float* __restrict__ num,
                          const float* __restrict__ ohw, const float* __restrict__ ohb,
                          const float* __restrict__ ohg, const float* __restrict__ ohbe,
                          const float* __restrict__ nmw, const float* __restrict__ nmb,
                          const float* __restrict__ nmg, const float* __restrict__ nmbe,
                          float* __restrict__ toh, float* __restrict__ tnm,
                          float* __restrict__ text, float* __restrict__ textT) {
    int blk = blockIdx.x;
    int lane = threadIdx.x;
    const int isOH = (blk < 196);
    const int j = isOH ? blk : blk - 196;
    const float* inp = isOH ? oneHot : num;
    const int A = isOH ? 24 : 11;
    const float* w = isOH ? ohw : nmw;
    const float* bias = isOH ? ohb : nmb;
    const float* g = isOH ? ohg : nmg;
    const float* be = isOH ? ohbe : nmbe;
    float v = 0.f;
    if (lane < 32) {
        v = bias[j];
        for (int k = 0; k < A; ++k) v += inp[lane * A + k] * w[j * A + k];
    }
    float s = (lane < 32) ? v : 0.f;
    float s2 = (lane < 32) ? v * v : 0.f;
    for (int m = 16; m; m >>= 1) { s += __shfl_xor(s, m, 32); s2 += __shfl_xor(s2, m, 32); }
    if (lane < 32) {
        float mean = s / 32.f;
        float var = s2 / 32.f - mean * mean;
        float rstd = rsqrtf(var + 1e-5f);
        float t = (v - mean) * rstd * g[j] + be[j];
        t = t / (1.f + expf(-t));
        int b = lane;
        if (isOH) {
            toh[b * 196 + j] = t;
            for (int c = 0; c < 30; ++c) {
                text[((size_t)(b * 45 + c)) * 196 + j] = t;
                textT[((size_t)(b * 196 + j)) * 45 + c] = t;
            }
        } else {
            tnm[b * 196 + j] = t;
            for (int c = 30; c < 45; ++c) {
                text[((size_t)(b * 45 + c)) * 196 + j] = t;
                textT[((size_t)(b * 196 + j)) * 45 + c] = t;
            }
        }
    }
}

// GCN dist bodies
__device__ __forceinline__ void d_dist_img(const float* __restrict__ f,
                                           const float* __restrict__ fT,
                                           unsigned short* __restrict__ distb,
                                           int bx, int b, int tid) {
    __shared__ float fi[4][196];
    const int i0 = bx * 4;
    for (int idx = tid; idx < 4 * 196; idx += 256) {
        int r = idx / 196, n = idx - r * 196;
        fi[r][n] = f[((size_t)(b * 128 + i0 + r)) * 196 + n];
    }
    __syncthreads();
    if (tid < 128) {
        const float* ft = fT + (size_t)b * 196 * 128 + tid;
        float a[4];
#pragma unroll
        for (int r = 0; r < 4; ++r) a[r] = 0.f;
#pragma unroll 4
        for (int n = 0; n < 196; ++n) {
            float v = ft[(size_t)n * 128];
#pragma unroll
            for (int r = 0; r < 4; ++r) a[r] += fabsf(fi[r][n] - v);
        }
#pragma unroll
        for (int r = 0; r < 4; ++r)
            distb[((size_t)(b * 128 + i0 + r)) * 128 + tid] = f2bf(expf(-a[r]));
    }
}

__device__ __forceinline__ void d_dist_txt(const float* __restrict__ f,
                                           const float* __restrict__ fT,
                                           float* __restrict__ dist,
                                           int bx, int b, int tid) {
    __shared__ float fi2[3][196];
    const int i0 = bx * 3;
    for (int idx = tid; idx < 3 * 196; idx += 256) {
        int r = idx / 196, n = idx - r * 196;
        fi2[r][n] = f[((size_t)(b * 45 + i0 + r)) * 196 + n];
    }
    __syncthreads();
    if (tid < 45) {
        const float* ft = fT + (size_t)b * 196 * 45 + tid;
        float a[3];
#pragma unroll
        for (int r = 0; r < 3; ++r) a[r] = 0.f;
#pragma unroll 4
        for (int n = 0; n < 196; ++n) {
            float v = ft[(size_t)n * 45];
#pragma unroll
            for (int r = 0; r < 3; ++r) a[r] += fabsf(fi2[r][n] - v);
        }
#pragma unroll
        for (int r = 0; r < 3; ++r)
            dist[((size_t)(b * 45 + i0 + r)) * 45 + tid] = expf(-a[r]);
    }
}

__global__ void k_dist_both(const float* __restrict__ fimg, const float* __restrict__ fTimg,
                            unsigned short* __restrict__ distb,
                            const float* __restrict__ ftxt, const float* __restrict__ fTtxt,
                            float* __restrict__ dist2) {
    int blk = blockIdx.x, tid = threadIdx.x;
    if (blk < 1024) d_dist_img(fimg, fTimg, distb, blk & 31, blk >> 5, tid);
    else { int r = blk - 1024; d_dist_txt(ftxt, fTtxt, dist2, r % 15, r / 15, tid); }
}

__global__ void k_prep3(float4* __restrict__ tqz,
                        const float* __restrict__ f1w, const float* __restrict__ f3w,
                        unsigned short* __restrict__ wcI,
                        const float* __restrict__ f4w, const float* __restrict__ f2w,
                        unsigned short* __restrict__ wcT) {
    int blk = blockIdx.x, tid = threadIdx.x;
    if (blk < 208) {
        int i = blk * 256 + tid;
        if (i < 53248) tqz[i] = (float4){0.f, 0.f, 0.f, 0.f};
        return;
    }
    blk -= 208;
    if (blk < 364) { d_wcat(f1w, f3w, wcI, blk * 256 + tid); return; }
    blk -= 364;
    d_wcat(f4w, f2w, wcT, blk * 256 + tid);
}

__global__ void k_prep4(float4* __restrict__ zA, float4* __restrict__ zB) {
    int blk = blockIdx.x, tid = threadIdx.x;
    if (blk < 1344) {
        int i = blk * 256 + tid;
        if (i < 344064) zA[i] = (float4){0.f, 0.f, 0.f, 0.f};
        return;
    }
    blk -= 1344;
    int i = blk * 256 + tid;
    if (i < 319488) zB[i] = (float4){0.f, 0.f, 0.f, 0.f};
}

// ================= conv (validated r12) =================
template <int IC, int G, int NT, int NH>
__global__ __launch_bounds__(256, 3) void k_convchunk4(
    const unsigned short* __restrict__ xt, const unsigned short* __restrict__ wp,
    float* __restrict__ part) {
    __shared__ unsigned short xs[208 * 72];
    __shared__ char bbuf[2][NT * 2048];
    const int tid = threadIdx.x;
    const int bx = blockIdx.x, b = blockIdx.y;
    const int mh = bx & 1;
    const int nh = (bx >> 1) % NH;
    const int g  = (bx >> 1) / NH;
    const int w = tid >> 6, l = tid & 63;

    {
        const bf16x8* s8 = (const bf16x8*)(xt + ((size_t)b * G + g) * (208 * 72));
        bf16x8* d8 = (bf16x8*)xs;
        for (int c = tid; c < 208 * 72 / 8; c += 256) d8[c] = s8[c];
    }

    const char* wslice = (const char*)wp +
                         ((size_t)(nh * NT * 16) * IC + (size_t)g * 64) * 2;
    auto stageB = [&](int t) {
        char* dst = &bbuf[t & 1][w * (NT * 512)];
        const char* wt_ = wslice + (size_t)t * 128 * IC * 2;
#pragma unroll
        for (int c = 0; c < NT / 2; ++c) {
            int q = w * (NT * 512) + c * 1024 + l * 16;
            int row = q >> 7, col = q & 127;
            int scol = col ^ ((row & 7) << 4);
            gas_void* src = (gas_void*)(wt_ + (size_t)row * IC * 2 + scol);
            __builtin_amdgcn_global_load_lds(src, (las_void*)(dst + c * 1024),
                                             16, 0, 0);
        }
    };

    const int lane = tid & 63;
    const int a = lane & 15, kg = lane >> 4;

    int md[2], mhh[2], mw[2];
#pragma unroll
    for (int i = 0; i < 2; ++i) {
        int m = (mh * 8 + (tid >> 6) * 2 + i) * 16 + a;
        md[i] = m / 49; int rr = m - md[i] * 49;
        mhh[i] = rr / 7; mw[i] = rr - mhh[i] * 7;
    }

    f32x4 acc[2][NT];
#pragma unroll
    for (int i = 0; i < 2; ++i)
#pragma unroll
        for (int nt = 0; nt < NT; ++nt) acc[i][nt] = (f32x4){0.f, 0.f, 0.f, 0.f};

    const bf16x8 zv = {0, 0, 0, 0, 0, 0, 0, 0};

    stageB(0);
    __syncthreads();

    for (int t = 0; t < 27; ++t) {
        if (t < 26) stageB(t + 1);
        const int kd = t / 9, kh = (t / 3) % 3, kw = t % 3;
        int rsrc[2]; bool ok[2];
#pragma unroll
        for (int i = 0; i < 2; ++i) {
            int d2 = md[i] + kd - 1, h2 = mhh[i] + kh - 1, w2 = mw[i] + kw - 1;
            ok[i] = ((unsigned)d2 < 4u) & ((unsigned)h2 < 7u) & ((unsigned)w2 < 7u);
            rsrc[i] = ok[i] ? (d2 * 49 + h2 * 7 + w2) : 0;
        }
        bf16x8 A[2][2];
#pragma unroll
        for (int kk = 0; kk < 2; ++kk)
#pragma unroll
            for (int i = 0; i < 2; ++i) {
                bf16x8 v = *(const bf16x8*)(xs + rsrc[i] * 72 + kk * 32 + kg * 8);
                A[kk][i] = ok[i] ? v : zv;
            }
        const char* bb = &bbuf[t & 1][0];
#pragma unroll
        for (int kk = 0; kk < 2; ++kk)
#pragma unroll
            for (int nt = 0; nt < NT; ++nt) {
                int row = nt * 16 + a;
                int cb = (kk * 64 + kg * 16) ^ ((row & 7) << 4);
                bf16x8 B = *(const bf16x8*)(bb + row * 128 + cb);
#pragma unroll
                for (int i = 0; i < 2; ++i)
                    acc[i][nt] = __builtin_amdgcn_mfma_f32_16x16x32_bf16(
                        A[kk][i], B, acc[i][nt], 0, 0, 0);
            }
        __syncthreads();
    }

    float* dst = part + ((size_t)g * 32 + b) * (128 * 196);
#pragma unroll
    for (int i = 0; i < 2; ++i) {
        int m0 = (mh * 8 + (tid >> 6) * 2 + i) * 16 + kg * 4;
        if (m0 < 196) {
#pragma unroll
            for (int nt = 0; nt < NT; ++nt) {
                int oc = nh * NT * 16 + nt * 16 + a;
                *(f32x4*)(dst + (size_t)oc * 196 + m0) = acc[i][nt];
            }
        }
    }
}

// ---------------- fused partial-reduce + BN stats (deterministic) ----------
template <int G, int C>
__global__ void k_reduce_stats(const float* __restrict__ part, float* __restrict__ y,
                               float* __restrict__ pst) {
    const int ch = blockIdx.x, b = blockIdx.y;
    const int tid = threadIdx.x;
    __shared__ float r1[4], r2[4];
    float v = 0.f;
    if (tid < 196) {
#pragma unroll
        for (int g = 0; g < G; ++g)
            v += part[((size_t)(g * 32 + b) * C + ch) * 196 + tid];
        y[((size_t)b * C + ch) * 196 + tid] = v;
    }
    float s = v, s2 = v * v;
    for (int sh = 32; sh; sh >>= 1) { s += __shfl_xor(s, sh); s2 += __shfl_xor(s2, sh); }
    if ((tid & 63) == 0) { r1[tid >> 6] = s; r2[tid >> 6] = s2; }
    __syncthreads();
    if (tid == 0) {
        pst[(ch * 32 + b) * 2]     = r1[0] + r1[1] + r1[2] + r1[3];
        pst[(ch * 32 + b) * 2 + 1] = r2[0] + r2[1] + r2[2] + r2[3];
    }
}

__global__ void k_bn_apply2(float* __restrict__ y, const float* __restrict__ pst,
                            const float* __restrict__ g, const float* __restrict__ be,
                            float* __restrict__ fT, unsigned short* __restrict__ fTb,
                            unsigned short* __restrict__ xtc, int C) {
    int idx = blockIdx.x;
    int ch = idx % C, b = idx / C;
    int s = threadIdx.x;
    float S = 0.f, S2 = 0.f;
    for (int b2 = 0; b2 < 32; ++b2) {
        S += pst[(ch * 32 + b2) * 2];
        S2 += pst[(ch * 32 + b2) * 2 + 1];
    }
    if (s < 196) {
        float m = S / 6272.f;
        float r = rsqrtf(S2 / 6272.f - m * m + 1e-5f);
        float v = y[(size_t)idx * 196 + s];
        float o = fmaxf((v - m) * r * g[ch] + be[ch], 0.f);
        y[(size_t)idx * 196 + s] = o;
        if (fT) fT[((size_t)b * 196 + s) * C + ch] = o;
        if (fTb) fTb[((size_t)b * 208 + s) * C + ch] = f2bf(o);
        if (xtc) {
            int G = C >> 6, gch = ch >> 6, cc = ch & 63;
            xtc[(((size_t)b * G + gch) * 208 + s) * 72 + cc] = f2bf(o);
        }
    }
}

// ---------------- CMSA/GCN batched MFMA GEMM, N-split (r18) ----------------
template <int MROWS, int MTILES, int KP, int KK, int EPI, int NS>
__global__ __launch_bounds__(256, 2) void k_bgemm(
    const unsigned short* __restrict__ Ab, size_t ABS,
    const unsigned short* __restrict__ Bb, size_t BBS,
    const float* __restrict__ bias,
    unsigned short* __restrict__ p0, unsigned short* __restrict__ p1,
    const float* __restrict__ resid, float* __restrict__ outf) {
    constexpr int KPS = KP + 8;
    __shared__ unsigned short xsA[64 * KPS];
    __shared__ char bbuf[2][208 * 64];
    const int tid = threadIdx.x, bx = blockIdx.x, b = blockIdx.y;
    const int wv = tid >> 6, lane = tid & 63, a = lane & 15, kg = lane >> 4;
    const int nh = bx % NS, mg = bx / NS;
    const int NT0 = (NS == 1) ? 0 : nh * 7;
    const int NTN = (NS == 1) ? 13 : ((nh == 0) ? 7 : 6);

    const unsigned short* Abase = Ab + (size_t)b * ABS;
    {
        const int rowu = KP / 2;
        for (int i = tid; i < 64 * rowu; i += 256) {
            int r = i / rowu, cu = i - r * rowu;
            int gr = mg * 64 + r; if (gr > MROWS - 1) gr = MROWS - 1;
            unsigned int v = ((const unsigned int*)(Abase + (size_t)gr * KP))[cu];
            *(unsigned int*)&xsA[r * KPS + cu * 2] = v;
        }
    }
    const char* Bbase = (const char*)(Bb + (size_t)b * BBS);
    auto stageB = [&](int kk) {
        char* dst0 = &bbuf[kk & 1][0];
        const int cnt = NTN * 64;
#pragma unroll
        for (int c = 0; c < 4; ++c) {
            int idx = tid + c * 256;
            if (idx < cnt) {
                int lrow = idx >> 2, u = idx & 3;
                int grow = NT0 * 16 + lrow;
                gas_void* src = (gas_void*)(Bbase + (size_t)grow * (KP * 2) +
                                            kk * 64 + u * 16);
                __builtin_amdgcn_global_load_lds(src, (las_void*)(dst0 + (size_t)idx * 16),
                                                 16, 0, 0);
            }
        }
    };

    int mt = mg * 4 + wv; if (mt > MTILES - 1) mt = MTILES - 1;
    const int arow = mt * 16 + a - mg * 64;

    f32x4 acc[13];
#pragma unroll
    for (int nt = 0; nt < 13; ++nt) acc[nt] = (f32x4){0.f, 0.f, 0.f, 0.f};

    stageB(0);
    __syncthreads();
    for (int kk = 0; kk < KK; ++kk) {
        if (kk + 1 < KK) stageB(kk + 1);
        bf16x8 Af = *(const bf16x8*)&xsA[arow * KPS + kk * 32 + kg * 8];
        const char* bb = &bbuf[kk & 1][0];
#pragma unroll
        for (int nt = 0; nt < 13; ++nt) {
            if (nt >= NT0 && nt < NT0 + NTN) {
                bf16x8 Bf = *(const bf16x8*)(bb + ((nt - NT0) * 16 + a) * 64 + kg * 16);
                acc[nt] = __builtin_amdgcn_mfma_f32_16x16x32_bf16(Af, Bf, acc[nt], 0, 0, 0);
            }
        }
        __syncthreads();
    }

    const int mbase = mt * 16 + kg * 4;
    if (EPI == 0) {
#pragma unroll
        for (int nt = 0; nt < 13; ++nt) {
            if (nt < NT0 || nt >= NT0 + NTN) continue;
            int col = nt * 16 + a;
            if (col < 196) {
#pragma unroll
                for (int j = 0; j < 4; ++j) {
                    int row = mbase + j;
                    if (row < 173) {
                        unsigned short h = f2bf(fmaxf(acc[nt][j] + bias[row], 0.f));
                        p0[((size_t)b * 176 + row) * 224 + col] = h;
                        p1[((size_t)b * 208 + col) * 192 + row] = h;
                    }
                }
            }
        }
    } else if (EPI == 1) {
#pragma unroll
        for (int j = 0; j < 4; ++j) {
            int row = mbase + j;
            float m = -3.4e38f;
#pragma unroll
            for (int nt = 0; nt < 13; ++nt) {
                int col = nt * 16 + a;
                float s = (col < 196) ? acc[nt][j] : -3.4e38f;
                m = fmaxf(m, s);
            }
            for (int msk = 1; msk < 16; msk <<= 1) m = fmaxf(m, __shfl_xor(m, msk));
            float e[13]; float sum = 0.f;
#pragma unroll
            for (int nt = 0; nt < 13; ++nt) {
                int col = nt * 16 + a;
                float v = (col < 196) ? expf(acc[nt][j] - m) : 0.f;
                e[nt] = v; sum += v;
            }
            for (int msk = 1; msk < 16; msk <<= 1) sum += __shfl_xor(sum, msk);
            float inv = 1.f / sum;
            if (row < 196) {
#pragma unroll
                for (int nt = 0; nt < 13; ++nt) {
                    int col = nt * 16 + a;
                    p0[((size_t)b * 208 + row) * 224 + col] = f2bf(e[nt] * inv);
                }
            }
        }
    } else if (EPI == 2) {
#pragma unroll
        for (int nt = 0; nt < 13; ++nt) {
            if (nt < NT0 || nt >= NT0 + NTN) continue;
            int col = nt * 16 + a;
#pragma unroll
            for (int j = 0; j < 4; ++j) {
                int row = mbase + j;
                if (row < 173)
                    p0[((size_t)b * 208 + col) * 192 + row] = f2bf(acc[nt][j]);
            }
        }
    } else if (EPI == 3) {
#pragma unroll
        for (int nt = 0; nt < 13; ++nt) {
            if (nt < NT0 || nt >= NT0 + NTN) continue;
            int col = nt * 16 + a;
            if (col < 196) {
#pragma unroll
                for (int j = 0; j < 4; ++j) {
                    int row = mbase + j;
                    if (row < 173) {
                        size_t rr = ((size_t)b * 173 + row) * 196 + col;
                        outf[rr] = fmaxf(acc[nt][j] + bias[row], 0.f) + resid[rr];
                    }
                }
            }
        }
    } else {  // EPI == 8
#pragma unroll
        for (int nt = 0; nt < 13; ++nt) {
            if (nt < NT0 || nt >= NT0 + NTN) continue;
            int col = nt * 16 + a;
            if (col < 196) {
#pragma unroll
                for (int j = 0; j < 4; ++j) {
                    int row = mbase + j;
                    size_t rr = ((size_t)b * 128 + row) * 196 + col;
                    outf[rr] = fmaxf(acc[nt][j] + bias[col], 0.f) + resid[rr];
                }
            }
        }
    }
}

// ---------------- merged GCN: img tmp-GEMM (EPI7) || txt spmmfin ------------
__global__ __launch_bounds__(256, 2) void k_gcnpair(
    const unsigned short* __restrict__ distb, const unsigned short* __restrict__ fTb,
    unsigned short* __restrict__ tmpb,
    const float* __restrict__ d2, const float* __restrict__ t1,
    const float* __restrict__ gm2T, const float* __restrict__ gm2b,
    float* __restrict__ t3) {
    __shared__ unsigned short xsA[64 * 136];
    __shared__ char bbuf[2][208 * 64];
    __shared__ float ds[3][45];
    __shared__ float ts[3][196];
    const int tid = threadIdx.x, b = blockIdx.y;
    int bx = blockIdx.x;
    if (bx < 4) {
        // bgemm<128,8,128,4,EPI7,NS=2>
        const int wv = tid >> 6, lane = tid & 63, a = lane & 15, kg = lane >> 4;
        const int nh = bx % 2, mg = bx / 2;
        const int NT0 = nh * 7, NTN = (nh == 0) ? 7 : 6;
        const unsigned short* Abase = distb + (size_t)b * 128 * 128;
        for (int i = tid; i < 64 * 64; i += 256) {
            int r = i / 64, cu = i - r * 64;
            int gr = mg * 64 + r;
            unsigned int v = ((const unsigned int*)(Abase + (size_t)gr * 128))[cu];
            *(unsigned int*)&xsA[r * 136 + cu * 2] = v;
        }
        const char* Bbase = (const char*)(fTb + (size_t)b * 208 * 128);
        auto stageB = [&](int kk) {
            char* dst0 = &bbuf[kk & 1][0];
            const int cnt = NTN * 64;
#pragma unroll
            for (int c = 0; c < 4; ++c) {
                int idx = tid + c * 256;
                if (idx < cnt) {
                    int lrow = idx >> 2, u = idx & 3;
                    int grow = NT0 * 16 + lrow;
                    gas_void* src = (gas_void*)(Bbase + (size_t)grow * 256 +
                                                kk * 64 + u * 16);
                    __builtin_amdgcn_global_load_lds(src,
                        (las_void*)(dst0 + (size_t)idx * 16), 16, 0, 0);
                }
            }
        };
        int mt = mg * 4 + wv;
        const int arow = mt * 16 + a - mg * 64;
        f32x4 acc[13];
#pragma unroll
        for (int nt = 0; nt < 13; ++nt) acc[nt] = (f32x4){0.f, 0.f, 0.f, 0.f};
        stageB(0);
        __syncthreads();
        for (int kk = 0; kk < 4; ++kk) {
            if (kk + 1 < 4) stageB(kk + 1);
            bf16x8 Af = *(const bf16x8*)&xsA[arow * 136 + kk * 32 + kg * 8];
            const char* bb = &bbuf[kk & 1][0];
#pragma unroll
            for (int nt = 0; nt < 13; ++nt) {
                if (nt >= NT0 && nt < NT0 + NTN) {
                    bf16x8 Bf = *(const bf16x8*)(bb + ((nt - NT0) * 16 + a) * 64 + kg * 16);
                    acc[nt] = __builtin_amdgcn_mfma_f32_16x16x32_bf16(Af, Bf, acc[nt], 0, 0, 0);
                }
            }
            __syncthreads();
        }
        const int mbase = mt * 16 + kg * 4;
#pragma unroll
        for (int nt = 0; nt < 13; ++nt) {
            if (nt < NT0 || nt >= NT0 + NTN) continue;
            int col = nt * 16 + a;
#pragma unroll
            for (int j = 0; j < 4; ++j) {
                int row = mbase + j;
                unsigned short h = (col < 196) ? f2bf(acc[nt][j]) : (unsigned short)0;
                tmpb[((size_t)b * 128 + row) * 224 + col] = h;
            }
        }
    } else {
        // spmmfin txt, ROWS=3, C=45
        const int i0 = (bx - 4) * 3;
        for (int idx = tid; idx < 3 * 45; idx += 256) {
            int r = idx / 45, j = idx - r * 45;
            ds[r][j] = d2[((size_t)(b * 45 + i0 + r)) * 45 + j];
        }
        __syncthreads();
        if (tid < 196) {
            float a[3];
#pragma unroll
            for (int r = 0; r < 3; ++r) a[r] = 0.f;
#pragma unroll 4
            for (int j = 0; j < 45; ++j) {
                float v = t1[((size_t)b * 45 + j) * 196 + tid];
#pragma unroll
                for (int r = 0; r < 3; ++r) a[r] += ds[r][j] * v;
            }
#pragma unroll
            for (int r = 0; r < 3; ++r) ts[r][tid] = a[r];
        }
        __syncthreads();
        if (tid < 196) {
            float a[3];
            float bi = gm2b[tid];
#pragma unroll
            for (int r = 0; r < 3; ++r) a[r] = bi;
#pragma unroll 4
            for (int n = 0; n < 196; ++n) {
                float wv = gm2T[(size_t)n * 196 + tid];
#pragma unroll
                for (int r = 0; r < 3; ++r) a[r] += ts[r][n] * wv;
            }
#pragma unroll
            for (int r = 0; r < 3; ++r) {
                size_t rr = ((size_t)(b * 45 + i0 + r)) * 196 + tid;
                t3[rr] = fmaxf(a[r], 0.f) + t1[rr];
            }
        }
    }
}

// ---------------- unified attention GEMM (runtime M-params) ----------------
struct AG {
    const unsigned short* Ab; unsigned long ABS;
    const unsigned short* Bb; unsigned long BBS;
    const float* biasA; const float* biasB;
    const float* lnres; const float* res2;
    unsigned short* p0; unsigned long p0rs, p0bs;
    float* feat; unsigned short* ftb; int cbase;
    int MROWS; int MTILES;
};

template <int KPA, int KPB, int KK, int EPI, int STAGEA, int NS>
__global__ __launch_bounds__(256, 2) void k_agemm2(AG pa, AG pc, int split) {
    constexpr int KPS = KPA + 8;
    __shared__ unsigned short xsA[STAGEA ? 64 * KPS : 64];
    __shared__ char bbuf[2][208 * 64];
    const AG P = (blockIdx.x < split) ? pa : pc;
    const int bx = (blockIdx.x < split) ? blockIdx.x : blockIdx.x - split;
    const int tid = threadIdx.x, b = blockIdx.y;
    const int wv = tid >> 6, lane = tid & 63, a = lane & 15, kg = lane >> 4;
    const int nh = bx % NS, mg = bx / NS;
    const int NT0 = (NS == 1) ? 0 : nh * 7;
    const int NTN = (NS == 1) ? 13 : ((nh == 0) ? 7 : 6);
    const int MROWS = P.MROWS, MTILES = P.MTILES;

    const unsigned short* Abase = P.Ab + (size_t)b * P.ABS;
    if (STAGEA) {
        const int rowu = KPA / 2;
        for (int i = tid; i < 64 * rowu; i += 256) {
            int r = i / rowu, cu = i - r * rowu;
            int gr = mg * 64 + r; if (gr > MROWS - 1) gr = MROWS - 1;
            unsigned int v = ((const unsigned int*)(Abase + (size_t)gr * KPA))[cu];
            *(unsigned int*)&xsA[r * KPS + cu * 2] = v;
        }
    }
    const char* Bbase = (const char*)(P.Bb + (size_t)b * P.BBS);
    auto stageB = [&](int kk) {
        char* dst0 = &bbuf[kk & 1][0];
        const int cnt = NTN * 64;
#pragma unroll
        for (int c = 0; c < 4; ++c) {
            int idx = tid + c * 256;
            if (idx < cnt) {
                int lrow = idx >> 2, u = idx & 3;
                int grow = NT0 * 16 + lrow;
                gas_void* src = (gas_void*)(Bbase + (size_t)grow * (KPB * 2) +
                                            kk * 64 + u * 16);
                __builtin_amdgcn_global_load_lds(src, (las_void*)(dst0 + (size_t)idx * 16),
                                                 16, 0, 0);
            }
        }
    };

    int mt = mg * 4 + wv; if (mt > MTILES - 1) mt = MTILES - 1;

    f32x4 acc[13];
#pragma unroll
    for (int nt = 0; nt < 13; ++nt) acc[nt] = (f32x4){0.f, 0.f, 0.f, 0.f};

    stageB(0);
    __syncthreads();
    for (int kk = 0; kk < KK; ++kk) {
        if (kk + 1 < KK) stageB(kk + 1);
        bf16x8 Af;
        if (STAGEA) {
            int arow = mt * 16 + a - mg * 64;
            Af = *(const bf16x8*)&xsA[arow * KPS + kk * 32 + kg * 8];
        } else {
            int gr = mt * 16 + a; if (gr > MROWS - 1) gr = MROWS - 1;
            Af = *(const bf16x8*)(Abase + (size_t)gr * KPA + kk * 32 + kg * 8);
        }
        const char* bb = &bbuf[kk & 1][0];
#pragma unroll
        for (int nt = 0; nt < 13; ++nt) {
            if (nt >= NT0 && nt < NT0 + NTN) {
                bf16x8 Bf = *(const bf16x8*)(bb + ((nt - NT0) * 16 + a) * 64 + kg * 16);
                acc[nt] = __builtin_amdgcn_mfma_f32_16x16x32_bf16(Af, Bf, acc[nt], 0, 0, 0);
            }
        }
        __syncthreads();
    }

    const int mbase = mt * 16 + kg * 4;
    if (EPI == 5) {
#pragma unroll
        for (int j = 0; j < 4; ++j) {
            int row = mbase + j;
            float mA = -3.4e38f, mB = -3.4e38f;
#pragma unroll
            for (int nt = 0; nt < 8; ++nt) mA = fmaxf(mA, acc[nt][j]);
#pragma unroll
            for (int nt = 8; nt < 13; ++nt) {
                int col = nt * 16 + a;
                float s = (col < 173) ? acc[nt][j] : -3.4e38f;
                mB = fmaxf(mB, s);
            }
            for (int msk = 1; msk < 16; msk <<= 1) {
                mA = fmaxf(mA, __shfl_xor(mA, msk));
                mB = fmaxf(mB, __shfl_xor(mB, msk));
            }
            float eA[8], eB[5];
            float sA = 0.f, sB = 0.f;
#pragma unroll
            for (int nt = 0; nt < 8; ++nt) { eA[nt] = expf(acc[nt][j] - mA); sA += eA[nt]; }
#pragma unroll
            for (int nt = 8; nt < 13; ++nt) {
                int col = nt * 16 + a;
                float v = (col < 173) ? expf(acc[nt][j] - mB) : 0.f;
                eB[nt - 8] = v; sB += v;
            }
            for (int msk = 1; msk < 16; msk <<= 1) {
                sA += __shfl_xor(sA, msk);
                sB += __shfl_xor(sB, msk);
            }
            float iA = 1.f / sA, iB = 1.f / sB;
            if (row < MROWS) {
#pragma unroll
                for (int nt = 0; nt < 12; ++nt) {
                    int col = nt * 16 + a;
                    float v = (nt < 8) ? eA[nt] * iA
                                       : ((col < 173) ? eB[nt - 8] * iB : 0.f);
                    P.p0[(size_t)b * P.p0bs + (size_t)row * P.p0rs + col] = f2bf(v);
                }
            }
        }
    } else {  // EPI == 4
#pragma unroll
        for (int nt = 0; nt < 13; ++nt) {
            if (nt < NT0 || nt >= NT0 + NTN) continue;
            int col = nt * 16 + a;
            if (col < 196) {
#pragma unroll
                for (int j = 0; j < 4; ++j) {
                    int row = mbase + j;
                    if (row < MROWS) {
                        size_t rr = ((size_t)b * MROWS + row) * 196 + col;
                        float v = acc[nt][j] + P.biasA[col] + P.biasB[col] +
                                  P.lnres[rr] + P.res2[rr];
                        P.feat[((size_t)b * 173 + P.cbase + row) * 196 + col] = v;
                        P.ftb[((size_t)(b * 208 + col)) * 192 + P.cbase + row] = f2bf(v);
                    }
                }
            }
        }
    }
}

// ---------------- unified PV kernel (runtime M-params) ----------------
struct PVP { const unsigned short* P; unsigned long Pbs;
             unsigned short* F; unsigned long Fbs; int MROWS; int MTILES; };

__global__ __launch_bounds__(256, 2) void k_pv2(
    PVP pa, PVP pc, int split,
    const unsigned short* __restrict__ V1, unsigned long V1bs,
    const unsigned short* __restrict__ V2, unsigned long V2bs) {
    constexpr int KPS = 200;
    __shared__ unsigned short xsA[64 * KPS];
    __shared__ char bbuf[2][208 * 64];
    const PVP P = (blockIdx.x < split) ? pa : pc;
    const int bx = (blockIdx.x < split) ? blockIdx.x : blockIdx.x - split;
    const int tid = threadIdx.x, b = blockIdx.y;
    const int wv = tid >> 6, lane = tid & 63, a = lane & 15, kg = lane >> 4;
    const int nh = bx % 2, mg = bx / 2;
    const int NT0 = nh * 7, NTN = (nh == 0) ? 7 : 6;
    const int MROWS = P.MROWS, MTILES = P.MTILES;

    const unsigned short* Abase = P.P + (size_t)b * P.Pbs;
    {
        for (int i = tid; i < 64 * 96; i += 256) {
            int r = i / 96, cu = i - r * 96;
            int gr = mg * 64 + r; if (gr > MROWS - 1) gr = MROWS - 1;
            unsigned int v = ((const unsigned int*)(Abase + (size_t)gr * 192))[cu];
            *(unsigned int*)&xsA[r * KPS + cu * 2] = v;
        }
    }
    int mt = mg * 4 + wv; if (mt > MTILES - 1) mt = MTILES - 1;
    const int arow = mt * 16 + a - mg * 64;
    const int mbase = mt * 16 + kg * 4;

    auto run = [&](const unsigned short* Vb, size_t Vbs_, int KPB, int KK,
                   int AOFFe, int outoff) {
        f32x4 acc[13];
#pragma unroll
        for (int nt = 0; nt < 13; ++nt) acc[nt] = (f32x4){0.f, 0.f, 0.f, 0.f};
        const char* Bbase = (const char*)(Vb + (size_t)b * Vbs_);
        auto stageB = [&](int kk) {
            char* dst0 = &bbuf[kk & 1][0];
            const int cnt = NTN * 64;
#pragma unroll
            for (int c = 0; c < 4; ++c) {
                int idx = tid + c * 256;
                if (idx < cnt) {
                    int lrow = idx >> 2, u = idx & 3;
                    int grow = NT0 * 16 + lrow;
                    gas_void* src = (gas_void*)(Bbase + (size_t)grow * (KPB * 2) +
                                                kk * 64 + u * 16);
                    __builtin_amdgcn_global_load_lds(src,
                        (las_void*)(dst0 + (size_t)idx * 16), 16, 0, 0);
                }
            }
        };
        stageB(0);
        __syncthreads();
        for (int kk = 0; kk < KK; ++kk) {
            if (kk + 1 < KK) stageB(kk + 1);
            bf16x8 Af = *(const bf16x8*)&xsA[arow * KPS + AOFFe + kk * 32 + kg * 8];
            const char* bb = &bbuf[kk & 1][0];
#pragma unroll
            for (int nt = 0; nt < 13; ++nt) {
                if (nt >= NT0 && nt < NT0 + NTN) {
                    bf16x8 Bf = *(const bf16x8*)(bb + ((nt - NT0) * 16 + a) * 64 + kg * 16);
                    acc[nt] = __builtin_amdgcn_mfma_f32_16x16x32_bf16(Af, Bf, acc[nt], 0, 0, 0);
                }
            }
            __syncthreads();
        }
#pragma unroll
        for (int nt = 0; nt < 13; ++nt) {
            if (nt < NT0 || nt >= NT0 + NTN) continue;
            int col = nt * 16 + a;
#pragma unroll
            for (int j = 0; j < 4; ++j) {
                int row = mbase + j;
                if (row < MROWS) {
                    unsigned short h = (col < 196) ? f2bf(acc[nt][j]) : (unsigned short)0;
                    P.F[(size_t)b * P.Fbs + (size_t)row * 448 + outoff + col] = h;
                }
            }
        }
        if (nh == 1) {
            int col = 208 + a;
#pragma unroll
            for (int j = 0; j < 4; ++j) {
                int row = mbase + j;
                if (row < MROWS)
                    P.F[(size_t)b * P.Fbs + (size_t)row * 448 + outoff + col] = 0;
            }
        }
    };
    run(V1, V1bs, 128, 4, 0, 0);
    run(V2, V2bs, 64, 2, 128, 224);
}

// ---------------- LN + projection body + merged kernel ----------------
template <int R, int ROWS, int KOFF, int TS>
__device__ __forceinline__ void d_lnlin(const float* __restrict__ x,
                                        const float* __restrict__ g,
                                        const float* __restrict__ be,
                                        const float* __restrict__ eT,
                                        const float* __restrict__ eb,
                                        float* __restrict__ lnout,
                                        unsigned short* __restrict__ kcat,
                                        unsigned short* __restrict__ tbuf,
                                        int bx, int b) {
    __shared__ float ls[ROWS][196];
    const int i0 = bx * ROWS;
    const int tid = threadIdx.x;
    const int wv = tid >> 6, lane = tid & 63;
    for (int idx = tid; idx < ROWS * 196; idx += 256) {
        int r = idx / 196, n = idx - r * 196;
        ls[r][n] = x[((size_t)(b * R + i0 + r)) * 196 + n];
    }
    __syncthreads();
    for (int k = 0;; ++k) {
        int r = wv + 4 * k;
        if (r >= ROWS) break;
        float s = 0.f, s2 = 0.f;
        for (int j = lane; j < 196; j += 64) { float v = ls[r][j]; s += v; s2 += v * v; }
        for (int sh = 32; sh; sh >>= 1) { s += __shfl_xor(s, sh); s2 += __shfl_xor(s2, sh); }
        float mean = s / 196.f;
        float var = s2 / 196.f - mean * mean;
        float rstd = rsqrtf(var + 1e-6f);
        size_t rowo = ((size_t)(b * R + i0 + r)) * 196;
        for (int j = lane; j < 196; j += 64) {
            float l = (ls[r][j] - mean) * rstd * g[j] + be[j];
            ls[r][j] = l;
            lnout[rowo + j] = l;
        }
    }
    __syncthreads();
    if (tid < 224) {
        float a[ROWS];
        if (tid < 196) {
            float bi = eb[tid];
#pragma unroll
            for (int r = 0; r < ROWS; ++r) a[r] = bi;
#pragma unroll 4
            for (int n = 0; n < 196; ++n) {
                float ev = eT[(size_t)n * 196 + tid];
#pragma unroll
                for (int r = 0; r < ROWS; ++r) a[r] += ls[r][n] * ev;
            }
        }
#pragma unroll
        for (int r = 0; r < ROWS; ++r) {
            unsigned short h = 0;
            if (tid < 196) h = f2bf(fmaxf(a[r], 0.f));
            kcat[((size_t)(b * 208 + KOFF + i0 + r)) * 224 + tid] = h;
            if (tid < 196) tbuf[((size_t)(b * 208 + tid)) * TS + (i0 + r)] = h;
        }
    }
}

__global__ void k_lnlin_both(const float* __restrict__ ximg, const float* __restrict__ g1,
                             const float* __restrict__ b1, const float* __restrict__ e1T,
                             const float* __restrict__ e1b, float* __restrict__ ln1out,
                             const float* __restrict__ xtxt, const float* __restrict__ g2,
                             const float* __restrict__ b2, const float* __restrict__ e2T,
                             const float* __restrict__ e2b, float* __restrict__ ln2out,
                             unsigned short* __restrict__ kcat,
                             unsigned short* __restrict__ iqT,
                             unsigned short* __restrict__ tqT) {
    int blk = blockIdx.x;
    if (blk < 1024)
        d_lnlin<128, 4, 0, 128>(ximg, g1, b1, e1T, e1b, ln1out, kcat, iqT,
                                blk & 31, blk >> 5);
    else {
        int r = blk - 1024;
        d_lnlin<45, 3, 128, 64>(xtxt, g2, b2, e2T, e2b, ln2out, kcat, tqT,
                                r % 15, r / 15);
    }
}

// ---------------- final classifier (rowsum fused) ----------------
__global__ void k_finale(const float* __restrict__ toh, const float* __restrict__ tnm,
                         const float* __restrict__ cms, const float* __restrict__ cls_w,
                         const float* __restrict__ cls_b, float* __restrict__ out) {
    int b = blockIdx.x;
    __shared__ float pcm[173];
    __shared__ float r1[4], r2[4];
    int tid = threadIdx.x;
    float a = (tid < 196) ? toh[b * 196 + tid] : 0.f;
    float c = (tid < 196) ? tnm[b * 196 + tid] : 0.f;
    for (int sh = 32; sh; sh >>= 1) { a += __shfl_xor(a, sh); c += __shfl_xor(c, sh); }
    if ((tid & 63) == 0) { r1[tid >> 6] = a; r2[tid >> 6] = c; }
    if (tid < 173) {
        float s = 0.f;
        const float* p = &cms[((size_t)b * 173 + tid) * 196];
        for (int n = 0; n < 196; ++n) s += p[n];
        pcm[tid] = s;
    }
    __syncthreads();
    if (tid < 2) {
        float soh = r1[0] + r1[1] + r1[2] + r1[3];
        float snm = r2[0] + r2[1] + r2[2] + r2[3];
        const float* wrow = &cls_w[tid * 218];
        float acc = cls_b[tid];
        float w1 = 0.f, w2 = 0.f;
        for (int k = 0; k < 30; ++k) w1 += wrow[k];
        for (int k = 30; k < 45; ++k) w2 += wrow[k];
        acc += soh * w1 + snm * w2;
        for (int k = 0; k < 173; ++k) acc += wrow[45 + k] * pcm[k];
        out[b * 2 + tid] = acc;
    }
}

// ---------------------------------------------------------------------------
extern "C" void kernel_launch(void* const* d_in, const int* in_sizes, int n_in,
                              void* d_out, int out_size, void* d_ws, size_t ws_size,
                              hipStream_t stream) {
    const float* x      = (const float*)d_in[0];
    const float* oneHot = (const float*)d_in[1];
    const float* num    = (const float*)d_in[2];
    const float* c1_w1  = (const float*)d_in[3];
    const float* c1_g1  = (const float*)d_in[5];
    const float* c1_be1 = (const float*)d_in[6];
    const float* c1_w2  = (const float*)d_in[7];
    const float* c1_g2  = (const float*)d_in[9];
    const float* c1_be2 = (const float*)d_in[10];
    const float* oh_w   = (const float*)d_in[11];
    const float* oh_b   = (const float*)d_in[12];
    const float* oh_g   = (const float*)d_in[13];
    const float* oh_be  = (const float*)d_in[14];
    const float* nm_w   = (const float*)d_in[15];
    const float* nm_b   = (const float*)d_in[16];
    const float* nm_g   = (const float*)d_in[17];
    const float* nm_be  = (const float*)d_in[18];
    const float* gm1_w  = (const float*)d_in[19];
    const float* gm1_b  = (const float*)d_in[20];
    const float* gm2_w  = (const float*)d_in[21];
    const float* gm2_b  = (const float*)d_in[22];
    const float* ln1_g  = (const float*)d_in[23];
    const float* ln1_b  = (const float*)d_in[24];
    const float* ln2_g  = (const float*)d_in[25];
    const float* ln2_b  = (const float*)d_in[26];
    const float* e1_w   = (const float*)d_in[27];
    const float* e1_b   = (const float*)d_in[28];
    const float* e2_w   = (const float*)d_in[29];
    const float* e2_b   = (const float*)d_in[30];
    const float* f1_w   = (const float*)d_in[31];
    const float* f1_b   = (const float*)d_in[32];
    const float* f2_w   = (const float*)d_in[33];
    const float* f2_b   = (const float*)d_in[34];
    const float* f3_w   = (const float*)d_in[35];
    const float* f3_b   = (const float*)d_in[36];
    const float* f4_w   = (const float*)d_in[37];
    const float* f4_b   = (const float*)d_in[38];
    const float* cm_w   = (const float*)d_in[39];
    const float* cm_b   = (const float*)d_in[40];
    const float* cmf_w  = (const float*)d_in[41];
    const float* cmf_b  = (const float*)d_in[42];
    const float* cls_w  = (const float*)d_in[43];
    const float* cls_b  = (const float*)d_in[44];
    float* out = (float*)d_out;
    float* W = (float*)d_ws;

    const size_t L = 802816;
    const size_t T = 282240;
    const size_t F3 = 1085056;
    // ---- layout identical to r18/r19 ----
    const size_t o_A    = 0;
    const size_t o_B    = L;
    const size_t o_C    = 2 * L;
    const size_t o_Kcat = 3 * L;
    const size_t o_iqT  = o_Kcat + 745472;
    const size_t o_t1   = 4 * L + T;
    const size_t o_t3   = 4 * L + 2 * T;
    const size_t o_ln2  = 4 * L + 3 * T;
    const size_t o_toh  = 4 * L + 4 * T;
    const size_t o_tnm  = o_toh + 6272;
    const size_t o_st   = o_tnm + 6272;
    const size_t o_wT   = o_st + 1024;
    const size_t o_feat = o_wT + 8 * 38416;
    const size_t o_q    = o_feat + F3;
    const size_t o_Fimg = o_q;
    const size_t o_dd   = o_q + F3;
    const size_t o_db   = o_dd;
    const size_t o_d2   = o_dd + 524288;
    const size_t o_gm1b = o_dd + 589088;
    const size_t o_fTb  = o_dd + 612384;
    const size_t o_tqT  = o_dd;
    const size_t o_wcI  = o_dd + 212992;
    const size_t o_wcT  = o_wcI + 46592;
    const size_t o_pbf  = o_dd;
    const size_t o_qbf  = o_dd + 745472;
    const size_t o_Ftxt = o_qbf;
    const size_t o_wcm  = o_qbf + 630784;
    const size_t o_wcmf = o_wcm + 16896;
    const size_t o_ftb  = o_wcmf + 16896;
    const size_t o_tr   = o_ftb + 638976;
    const size_t o_Pimg = o_tr;
    const size_t o_Ptxt = o_tr + 393216;
    const size_t o_qtb  = o_tr;
    const size_t o_ps   = 10158208;
    const size_t o_xt1 = o_dd;
    const size_t o_xt2 = o_xt1 + 1198080;
    const size_t o_wp1 = o_xt2 + 479232;
    const size_t o_wp2 = o_wp1 + 552960;

    float* part = W + 3 * L;
    unsigned short* xt1 = (unsigned short*)(W + o_xt1);
    unsigned short* xt2 = (unsigned short*)(W + o_xt2);
    unsigned short* wp1 = (unsigned short*)(W + o_wp1);
    unsigned short* wp2 = (unsigned short*)(W + o_wp2);
    unsigned short* kcatb = (unsigned short*)(W + o_Kcat);
    unsigned short* iqTb = (unsigned short*)(W + o_iqT);
    unsigned short* tqTb = (unsigned short*)(W + o_tqT);
    unsigned short* wcatI = (unsigned short*)(W + o_wcI);
    unsigned short* wcatT = (unsigned short*)(W + o_wcT);
    unsigned short* Fimg = (unsigned short*)(W + o_Fimg);
    unsigned short* Ftxt = (unsigned short*)(W + o_Ftxt);
    unsigned short* Pimg = (unsigned short*)(W + o_Pimg);
    unsigned short* Ptxt = (unsigned short*)(W + o_Ptxt);
    unsigned short* ftb = (unsigned short*)(W + o_ftb);
    unsigned short* qtb = (unsigned short*)(W + o_qtb);
    unsigned short* feab = (unsigned short*)(W + o_qtb + 638976);
    unsigned short* qbf = (unsigned short*)(W + o_qbf);
    unsigned short* wcmb = (unsigned short*)(W + o_wcm);
    unsigned short* wcmfb = (unsigned short*)(W + o_wcmf);
    unsigned short* pbf = (unsigned short*)(W + o_pbf);
    unsigned short* distb = (unsigned short*)(W + o_db);
    unsigned short* gm1b = (unsigned short*)(W + o_gm1b);
    unsigned short* fTb = (unsigned short*)(W + o_fTb);
    unsigned short* tmpb = (unsigned short*)(W + o_A);
    float* gm2T = W + o_wT + 0 * 38416;
    float* e1T  = W + o_wT + 1 * 38416;
    float* e2T  = W + o_wT + 2 * 38416;

    // 1: conv prep
    k_prep1<<<5460, 256, 0, stream>>>(c1_w1, wp1, c1_w2, wp2, x, xt1);

    // 2-4: conv1 + reduce/stats + BN
    k_convchunk4<320, 5, 4, 2><<<dim3(20, 32), 256, 0, stream>>>(xt1, wp1, part);
    k_reduce_stats<5, 128><<<dim3(128, 32), 256, 0, stream>>>(part, W + o_A, W + o_ps);
    k_bn_apply2<<<4096, 256, 0, stream>>>(W + o_A, W + o_ps, c1_g1, c1_be1,
                                          nullptr, nullptr, xt2, 128);

    // 5-7: conv2 + reduce/stats + BN
    k_convchunk4<128, 2, 2, 4><<<dim3(16, 32), 256, 0, stream>>>(xt2, wp2, part);
    k_reduce_stats<2, 128><<<dim3(128, 32), 256, 0, stream>>>(part, W + o_B,
                                                              W + o_ps + 8192);
    k_bn_apply2<<<4096, 256, 0, stream>>>(W + o_B, W + o_ps + 8192, c1_g2, c1_be2,
                                          W + o_tr, fTb, nullptr, 128);

    // 8: post-conv packs
    k_prep2<<<1658, 256, 0, stream>>>(cm_w, wcmb, cmf_w, wcmfb, gm1_w, gm1b,
                                      (float4*)(W + o_ftb), gm2_w, e1_w, e2_w, W + o_wT);

    // 9: catnum + direct text emission
    k_cattext<<<392, 64, 0, stream>>>(oneHot, num, oh_w, oh_b, oh_g, oh_be,
                                      nm_w, nm_b, nm_g, nm_be,
                                      W + o_toh, W + o_tnm, W + o_t1, W + o_tr + L);

    // 10: merged GCN dists
    k_dist_both<<<1504, 256, 0, stream>>>(W + o_B, W + o_tr, distb,
                                          W + o_t1, W + o_tr + L, W + o_d2);

    // 11: GCN img tmp-GEMM || GCN txt spmmfin
    k_gcnpair<<<dim3(19, 32), 256, 0, stream>>>(distb, fTb, tmpb,
                                                W + o_d2, W + o_t1, gm2T, gm2_b,
                                                W + o_t3);

    // 12: GCN img out GEMM
    k_bgemm<128, 8, 224, 7, 8, 2><<<dim3(4, 32), 256, 0, stream>>>(
        tmpb, (size_t)128 * 224, gm1b, 0, gm1_b,
        nullptr, nullptr, W + o_B, W + o_C);

    // 13: zero tqT + Wcat packs
    k_prep3<<<936, 256, 0, stream>>>((float4*)(W + o_tqT), f1_w, f3_w, wcatI,
                                     f4_w, f2_w, wcatT);

    // 14: merged LN + q projections
    k_lnlin_both<<<1504, 256, 0, stream>>>(W + o_C, ln1_g, ln1_b, e1T, e1_b, W + o_B,
                                           W + o_t3, ln2_g, ln2_b, e2T, e2_b, W + o_ln2,
                                           kcatb, iqTb, tqTb);

    // 15: attention scores (img + txt unified)
    {
        AG a{}, c{};
        a.Ab = kcatb; a.ABS = 208 * 224; a.Bb = kcatb; a.BBS = 208 * 224;
        a.p0 = Pimg; a.p0rs = 192; a.p0bs = (unsigned long)128 * 192;
        a.MROWS = 128; a.MTILES = 8;
        c = a;
        c.Ab = kcatb + 128 * 224; c.p0 = Ptxt; c.p0bs = (unsigned long)48 * 192;
        c.MROWS = 45; c.MTILES = 3;
        k_agemm2<224, 224, 7, 5, 1, 1><<<dim3(3, 32), 256, 0, stream>>>(a, c, 2);
    }

    // 16: merged PV (img + txt unified)
    {
        PVP a{Pimg, (unsigned long)128 * 192, Fimg, (unsigned long)128 * 448, 128, 8};
        PVP c{Ptxt, (unsigned long)48 * 192, Ftxt, (unsigned long)48 * 448, 45, 3};
        k_pv2<<<dim3(6, 32), 256, 0, stream>>>(a, c, 4, iqTb, (unsigned long)208 * 128,
                                               tqTb, (unsigned long)208 * 64);
    }

    // 17: projection + residuals (img + txt unified)
    {
        AG a{}, c{};
        a.Ab = Fimg; a.ABS = (unsigned long)128 * 448; a.Bb = wcatI; a.BBS = 0;
        a.biasA = f1_b; a.biasB = f3_b; a.lnres = W + o_B; a.res2 = W + o_C;
        a.feat = W + o_feat; a.ftb = ftb; a.cbase = 0; a.MROWS = 128; a.MTILES = 8;
        c = a;
        c.Ab = Ftxt; c.ABS = (unsigned long)48 * 448; c.Bb = wcatT;
        c.biasA = f2_b; c.biasB = f4_b; c.lnres = W + o_ln2; c.res2 = W + o_t3;
        c.cbase = 128; c.MROWS = 45; c.MTILES = 3;
        k_agemm2<448, 448, 14, 4, 0, 2><<<dim3(6, 32), 256, 0, stream>>>(a, c, 4);
    }

    // 18: CMSA zeros
    k_prep4<<<2592, 256, 0, stream>>>((float4*)(W + o_pbf), (float4*)(W + o_qtb));

    // 19-22: CMSA GEMMs
    k_bgemm<176, 11, 192, 6, 0, 2><<<dim3(6, 32), 256, 0, stream>>>(
        wcmb, 0, ftb, (size_t)208 * 192, cm_b, qbf, qtb, nullptr, nullptr);
    k_bgemm<208, 13, 192, 6, 1, 1><<<dim3(4, 32), 256, 0, stream>>>(
        qtb, (size_t)208 * 192, qtb, (size_t)208 * 192, nullptr, pbf, nullptr,
        nullptr, nullptr);
    k_bgemm<176, 11, 224, 7, 2, 2><<<dim3(6, 32), 256, 0, stream>>>(
        qbf, (size_t)176 * 224, pbf, (size_t)208 * 224, nullptr, feab, nullptr,
        nullptr, nullptr);
    k_bgemm<176, 11, 192, 6, 3, 2><<<dim3(6, 32), 256, 0, stream>>>(
        wcmfb, 0, feab, (size_t)208 * 192, cmf_b, nullptr, nullptr,
        W + o_feat, W + o_q);

    // 23: final classifier
    k_finale<<<32, 256, 0, stream>>>(W + o_toh, W + o_tnm, W + o_q, cls_w, cls_b, out);
}

// Round 21
// 304.957 us; speedup vs baseline: 1.5946x; 1.0424x over previous
//
#include <hip/hip_runtime.h>
#include <hip/hip_bf16.h>

// ---------------------------------------------------------------------------
// mv3Dunet_down_text_cmsa forward. Round 21: 23 -> 20 launches.
// scores+PV fused into k_attn (P kept in LDS, no HBM round-trip);
// GCN out-GEMM || prep3 merged; cattext folded into prep2.
// Arithmetic identical to round 20.
// ---------------------------------------------------------------------------

using bf16x8 = __attribute__((ext_vector_type(8))) short;
using f32x4  = __attribute__((ext_vector_type(4))) float;

typedef const __attribute__((address_space(1))) void gas_void;
typedef __attribute__((address_space(3))) void las_void;

__device__ __forceinline__ unsigned short f2bf(float f) {
    unsigned int u = __float_as_uint(f);
    u += 0x7FFFu + ((u >> 16) & 1u);
    return (unsigned short)(u >> 16);
}

// ================= small helpers =================
__device__ __forceinline__ void d_wpack(const float* __restrict__ w,
                                        unsigned short* __restrict__ wp,
                                        int IC, int idx) {
    int nc = IC >> 3;
    if (idx >= 27 * 128 * nc) return;
    int c = idx % nc; int r = idx / nc; int oc = r & 127; int t = r >> 7;
    const float* ws = w + ((size_t)oc * IC + c * 8) * 27 + t;
    unsigned int o0 = f2bf(ws[0])   | ((unsigned int)f2bf(ws[27])  << 16);
    unsigned int o1 = f2bf(ws[54])  | ((unsigned int)f2bf(ws[81])  << 16);
    unsigned int o2 = f2bf(ws[108]) | ((unsigned int)f2bf(ws[135]) << 16);
    unsigned int o3 = f2bf(ws[162]) | ((unsigned int)f2bf(ws[189]) << 16);
    uint4 v; v.x = o0; v.y = o1; v.z = o2; v.w = o3;
    ((uint4*)wp)[idx] = v;
}

__device__ __forceinline__ void d_w173(const float* __restrict__ w,
                                       unsigned short* __restrict__ wb, int idx) {
    if (idx >= 176 * 192) return;
    int oc = idx / 192, c = idx - oc * 192;
    wb[idx] = (oc < 173 && c < 173) ? f2bf(w[(size_t)oc * 173 + c]) : (unsigned short)0;
}

__device__ __forceinline__ void d_wcat(const float* __restrict__ wA,
                                       const float* __restrict__ wB,
                                       unsigned short* __restrict__ outw, int idx) {
    if (idx >= 208 * 448) return;
    int n = idx / 448, k = idx - n * 448;
    unsigned short v = 0;
    if (n < 196) {
        if (k < 196) v = f2bf(wA[(size_t)n * 196 + k]);
        else if (k >= 224 && k < 420) v = f2bf(wB[(size_t)n * 196 + (k - 224)]);
    }
    outw[idx] = v;
}

// catnum + direct text/textT emission (one 64-lane group per j-slot)
__device__ __forceinline__ void d_cattext(
    int idx, int lane,
    const float* __restrict__ oneHot, const float* __restrict__ num,
    const float* __restrict__ ohw, const float* __restrict__ ohb,
    const float* __restrict__ ohg, const float* __restrict__ ohbe,
    const float* __restrict__ nmw, const float* __restrict__ nmb,
    const float* __restrict__ nmg, const float* __restrict__ nmbe,
    float* __restrict__ toh, float* __restrict__ tnm,
    float* __restrict__ text, float* __restrict__ textT) {
    const int isOH = (idx < 196);
    const int j = isOH ? idx : idx - 196;
    const float* inp = isOH ? oneHot : num;
    const int A = isOH ? 24 : 11;
    const float* w = isOH ? ohw : nmw;
    const float* bias = isOH ? ohb : nmb;
    const float* g = isOH ? ohg : nmg;
    const float* be = isOH ? ohbe : nmbe;
    float v = 0.f;
    if (lane < 32) {
        v = bias[j];
        for (int k = 0; k < A; ++k) v += inp[lane * A + k] * w[j * A + k];
    }
    float s = (lane < 32) ? v : 0.f;
    float s2 = (lane < 32) ? v * v : 0.f;
    for (int m = 16; m; m >>= 1) { s += __shfl_xor(s, m, 32); s2 += __shfl_xor(s2, m, 32); }
    if (lane < 32) {
        float mean = s / 32.f;
        float var = s2 / 32.f - mean * mean;
        float rstd = rsqrtf(var + 1e-5f);
        float t = (v - mean) * rstd * g[j] + be[j];
        t = t / (1.f + expf(-t));
        int b = lane;
        if (isOH) {
            toh[b * 196 + j] = t;
            for (int c = 0; c < 30; ++c) {
                text[((size_t)(b * 45 + c)) * 196 + j] = t;
                textT[((size_t)(b * 196 + j)) * 45 + c] = t;
            }
        } else {
            tnm[b * 196 + j] = t;
            for (int c = 30; c < 45; ++c) {
                text[((size_t)(b * 45 + c)) * 196 + j] = t;
                textT[((size_t)(b * 196 + j)) * 45 + c] = t;
            }
        }
    }
}

// ================= merged prep kernels =================
__global__ void k_prep1(const float* __restrict__ c1w1, unsigned short* __restrict__ wp1,
                        const float* __restrict__ c1w2, unsigned short* __restrict__ wp2,
                        const float* __restrict__ x, unsigned short* __restrict__ xt1) {
    int blk = blockIdx.x, tid = threadIdx.x;
    if (blk < 540) { d_wpack(c1w1, wp1, 320, blk * 256 + tid); return; }
    blk -= 540;
    if (blk < 216) { d_wpack(c1w2, wp2, 128, blk * 256 + tid); return; }
    blk -= 216;
    int b = blk / 147, ib = blk - b * 147;
    const int tot = 5 * 208 * 36;
    int idx = ib * 256 + tid;
    if (idx >= tot) return;
    int g = idx / (208 * 36); int r2 = idx - g * (208 * 36);
    int s = r2 / 36, cp = r2 - s * 36;
    int cc = cp * 2;
    int ic = g * 64 + cc;
    unsigned int lo = 0, hi = 0;
    if (s < 196 && cc < 64 && ic < 320)         lo = f2bf(x[((size_t)b * 320 + ic) * 196 + s]);
    if (s < 196 && cc + 1 < 64 && ic + 1 < 320) hi = f2bf(x[((size_t)b * 320 + ic + 1) * 196 + s]);
    ((unsigned int*)xt1)[(size_t)b * tot + idx] = lo | (hi << 16);
}

// prep2 (+ cattext) — grid 1756
__global__ void k_prep2(const float* __restrict__ cm_w, unsigned short* __restrict__ wcmb,
                        const float* __restrict__ cmf_w, unsigned short* __restrict__ wcmfb,
                        const float* __restrict__ gm1_w, unsigned short* __restrict__ gm1b,
                        float4* __restrict__ ftbz,
                        const float* __restrict__ gm2_w, const float* __restrict__ e1_w,
                        const float* __restrict__ e2_w, float* __restrict__ wT,
                        const float* __restrict__ oneHot, const float* __restrict__ num,
                        const float* __restrict__ ohw, const float* __restrict__ ohb,
                        const float* __restrict__ ohg, const float* __restrict__ ohbe,
                        const float* __restrict__ nmw, const float* __restrict__ nmb,
                        const float* __restrict__ nmg, const float* __restrict__ nmbe,
                        float* __restrict__ toh, float* __restrict__ tnm,
                        float* __restrict__ text, float* __restrict__ textT) {
    int blk = blockIdx.x, tid = threadIdx.x;
    if (blk < 132) { d_w173(cm_w, wcmb, blk * 256 + tid); return; }
    blk -= 132;
    if (blk < 132) { d_w173(cmf_w, wcmfb, blk * 256 + tid); return; }
    blk -= 132;
    if (blk < 182) {
        int idx = blk * 256 + tid;
        if (idx < 208 * 224) {
            int r = idx / 224, c = idx - r * 224;
            gm1b[idx] = (r < 196 && c < 196) ? f2bf(gm1_w[(size_t)r * 196 + c])
                                             : (unsigned short)0;
        }
        return;
    }
    blk -= 182;
    if (blk < 624) {
        int i = blk * 256 + tid;
        if (i < 159744) ftbz[i] = (float4){0.f, 0.f, 0.f, 0.f};
        return;
    }
    blk -= 624;
    if (blk < 588) {
        int m = blk / 196, i = blk - m * 196;
        const float* w = (m == 0) ? gm2_w : (m == 1) ? e1_w : e2_w;
        float* o = wT + (size_t)m * 38416;
        if (tid < 196) o[(size_t)i * 196 + tid] = w[(size_t)tid * 196 + i];
        return;
    }
    blk -= 588;
    {
        int idx = blk * 4 + (tid >> 6);
        if (idx < 392)
            d_cattext(idx, tid & 63, oneHot, num, ohw, ohb, ohg, ohbe,
                      nmw, nmb, nmg, nmbe, toh, tnm, text, textT);
    }
}

// GCN dist bodies
__device__ __forceinline__ void d_dist_img(const float* __restrict__ f,
                                           const float* __restrict__ fT,
                                           unsigned short* __restrict__ distb,
                                           int bx, int b, int tid) {
    __shared__ float fi[4][196];
    const int i0 = bx * 4;
    for (int idx = tid; idx < 4 * 196; idx += 256) {
        int r = idx / 196, n = idx - r * 196;
        fi[r][n] = f[((size_t)(b * 128 + i0 + r)) * 196 + n];
    }
    __syncthreads();
    if (tid < 128) {
        const float* ft = fT + (size_t)b * 196 * 128 + tid;
        float a[4];
#pragma unroll
        for (int r = 0; r < 4; ++r) a[r] = 0.f;
#pragma unroll 4
        for (int n = 0; n < 196; ++n) {
            float v = ft[(size_t)n * 128];
#pragma unroll
            for (int r = 0; r < 4; ++r) a[r] += fabsf(fi[r][n] - v);
        }
#pragma unroll
        for (int r = 0; r < 4; ++r)
            distb[((size_t)(b * 128 + i0 + r)) * 128 + tid] = f2bf(expf(-a[r]));
    }
}

__device__ __forceinline__ void d_dist_txt(const float* __restrict__ f,
                                           const float* __restrict__ fT,
                                           float* __restrict__ dist,
                                           int bx, int b, int tid) {
    __shared__ float fi2[3][196];
    const int i0 = bx * 3;
    for (int idx = tid; idx < 3 * 196; idx += 256) {
        int r = idx / 196, n = idx - r * 196;
        fi2[r][n] = f[((size_t)(b * 45 + i0 + r)) * 196 + n];
    }
    __syncthreads();
    if (tid < 45) {
        const float* ft = fT + (size_t)b * 196 * 45 + tid;
        float a[3];
#pragma unroll
        for (int r = 0; r < 3; ++r) a[r] = 0.f;
#pragma unroll 4
        for (int n = 0; n < 196; ++n) {
            float v = ft[(size_t)n * 45];
#pragma unroll
            for (int r = 0; r < 3; ++r) a[r] += fabsf(fi2[r][n] - v);
        }
#pragma unroll
        for (int r = 0; r < 3; ++r)
            dist[((size_t)(b * 45 + i0 + r)) * 45 + tid] = expf(-a[r]);
    }
}

__global__ void k_dist_both(const float* __restrict__ fimg, const float* __restrict__ fTimg,
                            unsigned short* __restrict__ distb,
                            const float* __restrict__ ftxt, const float* __restrict__ fTtxt,
                            float* __restrict__ dist2) {
    int blk = blockIdx.x, tid = threadIdx.x;
    if (blk < 1024) d_dist_img(fimg, fTimg, distb, blk & 31, blk >> 5, tid);
    else { int r = blk - 1024; d_dist_txt(ftxt, fTtxt, dist2, r % 15, r / 15, tid); }
}

__global__ void k_prep4(float4* __restrict__ zA, float4* __restrict__ zB) {
    int blk = blockIdx.x, tid = threadIdx.x;
    if (blk < 1344) {
        int i = blk * 256 + tid;
        if (i < 344064) zA[i] = (float4){0.f, 0.f, 0.f, 0.f};
        return;
    }
    blk -= 1344;
    int i = blk * 256 + tid;
    if (i < 319488) zB[i] = (float4){0.f, 0.f, 0.f, 0.f};
}

// ================= conv (validated r12) =================
template <int IC, int G, int NT, int NH>
__global__ __launch_bounds__(256, 3) void k_convchunk4(
    const unsigned short* __restrict__ xt, const unsigned short* __restrict__ wp,
    float* __restrict__ part) {
    __shared__ unsigned short xs[208 * 72];
    __shared__ char bbuf[2][NT * 2048];
    const int tid = threadIdx.x;
    const int bx = blockIdx.x, b = blockIdx.y;
    const int mh = bx & 1;
    const int nh = (bx >> 1) % NH;
    const int g  = (bx >> 1) / NH;
    const int w = tid >> 6, l = tid & 63;

    {
        const bf16x8* s8 = (const bf16x8*)(xt + ((size_t)b * G + g) * (208 * 72));
        bf16x8* d8 = (bf16x8*)xs;
        for (int c = tid; c < 208 * 72 / 8; c += 256) d8[c] = s8[c];
    }

    const char* wslice = (const char*)wp +
                         ((size_t)(nh * NT * 16) * IC + (size_t)g * 64) * 2;
    auto stageB = [&](int t) {
        char* dst = &bbuf[t & 1][w * (NT * 512)];
        const char* wt_ = wslice + (size_t)t * 128 * IC * 2;
#pragma unroll
        for (int c = 0; c < NT / 2; ++c) {
            int q = w * (NT * 512) + c * 1024 + l * 16;
            int row = q >> 7, col = q & 127;
            int scol = col ^ ((row & 7) << 4);
            gas_void* src = (gas_void*)(wt_ + (size_t)row * IC * 2 + scol);
            __builtin_amdgcn_global_load_lds(src, (las_void*)(dst + c * 1024),
                                             16, 0, 0);
        }
    };

    const int lane = tid & 63;
    const int a = lane & 15, kg = lane >> 4;

    int md[2], mhh[2], mw[2];
#pragma unroll
    for (int i = 0; i < 2; ++i) {
        int m = (mh * 8 + (tid >> 6) * 2 + i) * 16 + a;
        md[i] = m / 49; int rr = m - md[i] * 49;
        mhh[i] = rr / 7; mw[i] = rr - mhh[i] * 7;
    }

    f32x4 acc[2][NT];
#pragma unroll
    for (int i = 0; i < 2; ++i)
#pragma unroll
        for (int nt = 0; nt < NT; ++nt) acc[i][nt] = (f32x4){0.f, 0.f, 0.f, 0.f};

    const bf16x8 zv = {0, 0, 0, 0, 0, 0, 0, 0};

    stageB(0);
    __syncthreads();

    for (int t = 0; t < 27; ++t) {
        if (t < 26) stageB(t + 1);
        const int kd = t / 9, kh = (t / 3) % 3, kw = t % 3;
        int rsrc[2]; bool ok[2];
#pragma unroll
        for (int i = 0; i < 2; ++i) {
            int d2 = md[i] + kd - 1, h2 = mhh[i] + kh - 1, w2 = mw[i] + kw - 1;
            ok[i] = ((unsigned)d2 < 4u) & ((unsigned)h2 < 7u) & ((unsigned)w2 < 7u);
            rsrc[i] = ok[i] ? (d2 * 49 + h2 * 7 + w2) : 0;
        }
        bf16x8 A[2][2];
#pragma unroll
        for (int kk = 0; kk < 2; ++kk)
#pragma unroll
            for (int i = 0; i < 2; ++i) {
                bf16x8 v = *(const bf16x8*)(xs + rsrc[i] * 72 + kk * 32 + kg * 8);
                A[kk][i] = ok[i] ? v : zv;
            }
        const char* bb = &bbuf[t & 1][0];
#pragma unroll
        for (int kk = 0; kk < 2; ++kk)
#pragma unroll
            for (int nt = 0; nt < NT; ++nt) {
                int row = nt * 16 + a;
                int cb = (kk * 64 + kg * 16) ^ ((row & 7) << 4);
                bf16x8 B = *(const bf16x8*)(bb + row * 128 + cb);
#pragma unroll
                for (int i = 0; i < 2; ++i)
                    acc[i][nt] = __builtin_amdgcn_mfma_f32_16x16x32_bf16(
                        A[kk][i], B, acc[i][nt], 0, 0, 0);
            }
        __syncthreads();
    }

    float* dst = part + ((size_t)g * 32 + b) * (128 * 196);
#pragma unroll
    for (int i = 0; i < 2; ++i) {
        int m0 = (mh * 8 + (tid >> 6) * 2 + i) * 16 + kg * 4;
        if (m0 < 196) {
#pragma unroll
            for (int nt = 0; nt < NT; ++nt) {
                int oc = nh * NT * 16 + nt * 16 + a;
                *(f32x4*)(dst + (size_t)oc * 196 + m0) = acc[i][nt];
            }
        }
    }
}

// ---------------- fused partial-reduce + BN stats (deterministic) ----------
template <int G, int C>
__global__ void k_reduce_stats(const float* __restrict__ part, float* __restrict__ y,
                               float* __restrict__ pst) {
    const int ch = blockIdx.x, b = blockIdx.y;
    const int tid = threadIdx.x;
    __shared__ float r1[4], r2[4];
    float v = 0.f;
    if (tid < 196) {
#pragma unroll
        for (int g = 0; g < G; ++g)
            v += part[((size_t)(g * 32 + b) * C + ch) * 196 + tid];
        y[((size_t)b * C + ch) * 196 + tid] = v;
    }
    float s = v, s2 = v * v;
    for (int sh = 32; sh; sh >>= 1) { s += __shfl_xor(s, sh); s2 += __shfl_xor(s2, sh); }
    if ((tid & 63) == 0) { r1[tid >> 6] = s; r2[tid >> 6] = s2; }
    __syncthreads();
    if (tid == 0) {
        pst[(ch * 32 + b) * 2]     = r1[0] + r1[1] + r1[2] + r1[3];
        pst[(ch * 32 + b) * 2 + 1] = r2[0] + r2[1] + r2[2] + r2[3];
    }
}

__global__ void k_bn_apply2(float* __restrict__ y, const float* __restrict__ pst,
                            const float* __restrict__ g, const float* __restrict__ be,
                            float* __restrict__ fT, unsigned short* __restrict__ fTb,
                            unsigned short* __restrict__ xtc, int C) {
    int idx = blockIdx.x;
    int ch = idx % C, b = idx / C;
    int s = threadIdx.x;
    float S = 0.f, S2 = 0.f;
    for (int b2 = 0; b2 < 32; ++b2) {
        S += pst[(ch * 32 + b2) * 2];
        S2 += pst[(ch * 32 + b2) * 2 + 1];
    }
    if (s < 196) {
        float m = S / 6272.f;
        float r = rsqrtf(S2 / 6272.f - m * m + 1e-5f);
        float v = y[(size_t)idx * 196 + s];
        float o = fmaxf((v - m) * r * g[ch] + be[ch], 0.f);
        y[(size_t)idx * 196 + s] = o;
        if (fT) fT[((size_t)b * 196 + s) * C + ch] = o;
        if (fTb) fTb[((size_t)b * 208 + s) * C + ch] = f2bf(o);
        if (xtc) {
            int G = C >> 6, gch = ch >> 6, cc = ch & 63;
            xtc[(((size_t)b * G + gch) * 208 + s) * 72 + cc] = f2bf(o);
        }
    }
}

// ---------------- CMSA batched MFMA GEMM, N-split (r18) ----------------
template <int MROWS, int MTILES, int KP, int KK, int EPI, int NS>
__global__ __launch_bounds__(256, 2) void k_bgemm(
    const unsigned short* __restrict__ Ab, size_t ABS,
    const unsigned short* __restrict__ Bb, size_t BBS,
    const float* __restrict__ bias,
    unsigned short* __restrict__ p0, unsigned short* __restrict__ p1,
    const float* __restrict__ resid, float* __restrict__ outf) {
    constexpr int KPS = KP + 8;
    __shared__ unsigned short xsA[64 * KPS];
    __shared__ char bbuf[2][208 * 64];
    const int tid = threadIdx.x, bx = blockIdx.x, b = blockIdx.y;
    const int wv = tid >> 6, lane = tid & 63, a = lane & 15, kg = lane >> 4;
    const int nh = bx % NS, mg = bx / NS;
    const int NT0 = (NS == 1) ? 0 : nh * 7;
    const int NTN = (NS == 1) ? 13 : ((nh == 0) ? 7 : 6);

    const unsigned short* Abase = Ab + (size_t)b * ABS;
    {
        const int rowu = KP / 2;
        for (int i = tid; i < 64 * rowu; i += 256) {
            int r = i / rowu, cu = i - r * rowu;
            int gr = mg * 64 + r; if (gr > MROWS - 1) gr = MROWS - 1;
            unsigned int v = ((const unsigned int*)(Abase + (size_t)gr * KP))[cu];
            *(unsigned int*)&xsA[r * KPS + cu * 2] = v;
        }
    }
    const char* Bbase = (const char*)(Bb + (size_t)b * BBS);
    auto stageB = [&](int kk) {
        char* dst0 = &bbuf[kk & 1][0];
        const int cnt = NTN * 64;
#pragma unroll
        for (int c = 0; c < 4; ++c) {
            int idx = tid + c * 256;
            if (idx < cnt) {
                int lrow = idx >> 2, u = idx & 3;
                int grow = NT0 * 16 + lrow;
                gas_void* src = (gas_void*)(Bbase + (size_t)grow * (KP * 2) +
                                            kk * 64 + u * 16);
                __builtin_amdgcn_global_load_lds(src, (las_void*)(dst0 + (size_t)idx * 16),
                                                 16, 0, 0);
            }
        }
    };

    int mt = mg * 4 + wv; if (mt > MTILES - 1) mt = MTILES - 1;
    const int arow = mt * 16 + a - mg * 64;

    f32x4 acc[13];
#pragma unroll
    for (int nt = 0; nt < 13; ++nt) acc[nt] = (f32x4){0.f, 0.f, 0.f, 0.f};

    stageB(0);
    __syncthreads();
    for (int kk = 0; kk < KK; ++kk) {
        if (kk + 1 < KK) stageB(kk + 1);
        bf16x8 Af = *(const bf16x8*)&xsA[arow * KPS + kk * 32 + kg * 8];
        const char* bb = &bbuf[kk & 1][0];
#pragma unroll
        for (int nt = 0; nt < 13; ++nt) {
            if (nt >= NT0 && nt < NT0 + NTN) {
                bf16x8 Bf = *(const bf16x8*)(bb + ((nt - NT0) * 16 + a) * 64 + kg * 16);
                acc[nt] = __builtin_amdgcn_mfma_f32_16x16x32_bf16(Af, Bf, acc[nt], 0, 0, 0);
            }
        }
        __syncthreads();
    }

    const int mbase = mt * 16 + kg * 4;
    if (EPI == 0) {
#pragma unroll
        for (int nt = 0; nt < 13; ++nt) {
            if (nt < NT0 || nt >= NT0 + NTN) continue;
            int col = nt * 16 + a;
            if (col < 196) {
#pragma unroll
                for (int j = 0; j < 4; ++j) {
                    int row = mbase + j;
                    if (row < 173) {
                        unsigned short h = f2bf(fmaxf(acc[nt][j] + bias[row], 0.f));
                        p0[((size_t)b * 176 + row) * 224 + col] = h;
                        p1[((size_t)b * 208 + col) * 192 + row] = h;
                    }
                }
            }
        }
    } else if (EPI == 1) {
#pragma unroll
        for (int j = 0; j < 4; ++j) {
            int row = mbase + j;
            float m = -3.4e38f;
#pragma unroll
            for (int nt = 0; nt < 13; ++nt) {
                int col = nt * 16 + a;
                float s = (col < 196) ? acc[nt][j] : -3.4e38f;
                m = fmaxf(m, s);
            }
            for (int msk = 1; msk < 16; msk <<= 1) m = fmaxf(m, __shfl_xor(m, msk));
            float e[13]; float sum = 0.f;
#pragma unroll
            for (int nt = 0; nt < 13; ++nt) {
                int col = nt * 16 + a;
                float v = (col < 196) ? expf(acc[nt][j] - m) : 0.f;
                e[nt] = v; sum += v;
            }
            for (int msk = 1; msk < 16; msk <<= 1) sum += __shfl_xor(sum, msk);
            float inv = 1.f / sum;
            if (row < 196) {
#pragma unroll
                for (int nt = 0; nt < 13; ++nt) {
                    int col = nt * 16 + a;
                    p0[((size_t)b * 208 + row) * 224 + col] = f2bf(e[nt] * inv);
                }
            }
        }
    } else if (EPI == 2) {
#pragma unroll
        for (int nt = 0; nt < 13; ++nt) {
            if (nt < NT0 || nt >= NT0 + NTN) continue;
            int col = nt * 16 + a;
#pragma unroll
            for (int j = 0; j < 4; ++j) {
                int row = mbase + j;
                if (row < 173)
                    p0[((size_t)b * 208 + col) * 192 + row] = f2bf(acc[nt][j]);
            }
        }
    } else {  // EPI == 3
#pragma unroll
        for (int nt = 0; nt < 13; ++nt) {
            if (nt < NT0 || nt >= NT0 + NTN) continue;
            int col = nt * 16 + a;
            if (col < 196) {
#pragma unroll
                for (int j = 0; j < 4; ++j) {
                    int row = mbase + j;
                    if (row < 173) {
                        size_t rr = ((size_t)b * 173 + row) * 196 + col;
                        outf[rr] = fmaxf(acc[nt][j] + bias[row], 0.f) + resid[rr];
                    }
                }
            }
        }
    }
}

// ---------------- merged GCN: img tmp-GEMM (EPI7) || txt spmmfin ------------
__global__ __launch_bounds__(256, 2) void k_gcnpair(
    const unsigned short* __restrict__ distb, const unsigned short* __restrict__ fTb,
    unsigned short* __restrict__ tmpb,
    const float* __restrict__ d2, const float* __restrict__ t1,
    const float* __restrict__ gm2T, const float* __restrict__ gm2b,
    float* __restrict__ t3) {
    __shared__ unsigned short xsA[64 * 136];
    __shared__ char bbuf[2][208 * 64];
    __shared__ float ds[3][45];
    __shared__ float ts[3][196];
    const int tid = threadIdx.x, b = blockIdx.y;
    int bx = blockIdx.x;
    if (bx < 4) {
        const int wv = tid >> 6, lane = tid & 63, a = lane & 15, kg = lane >> 4;
        const int nh = bx % 2, mg = bx / 2;
        const int NT0 = nh * 7, NTN = (nh == 0) ? 7 : 6;
        const unsigned short* Abase = distb + (size_t)b * 128 * 128;
        for (int i = tid; i < 64 * 64; i += 256) {
            int r = i / 64, cu = i - r * 64;
            int gr = mg * 64 + r;
            unsigned int v = ((const unsigned int*)(Abase + (size_t)gr * 128))[cu];
            *(unsigned int*)&xsA[r * 136 + cu * 2] = v;
        }
        const char* Bbase = (const char*)(fTb + (size_t)b * 208 * 128);
        auto stageB = [&](int kk) {
            char* dst0 = &bbuf[kk & 1][0];
            const int cnt = NTN * 64;
#pragma unroll
            for (int c = 0; c < 4; ++c) {
                int idx = tid + c * 256;
                if (idx < cnt) {
                    int lrow = idx >> 2, u = idx & 3;
                    int grow = NT0 * 16 + lrow;
                    gas_void* src = (gas_void*)(Bbase + (size_t)grow * 256 +
                                                kk * 64 + u * 16);
                    __builtin_amdgcn_global_load_lds(src,
                        (las_void*)(dst0 + (size_t)idx * 16), 16, 0, 0);
                }
            }
        };
        int mt = mg * 4 + wv;
        const int arow = mt * 16 + a - mg * 64;
        f32x4 acc[13];
#pragma unroll
        for (int nt = 0; nt < 13; ++nt) acc[nt] = (f32x4){0.f, 0.f, 0.f, 0.f};
        stageB(0);
        __syncthreads();
        for (int kk = 0; kk < 4; ++kk) {
            if (kk + 1 < 4) stageB(kk + 1);
            bf16x8 Af = *(const bf16x8*)&xsA[arow * 136 + kk * 32 + kg * 8];
            const char* bb = &bbuf[kk & 1][0];
#pragma unroll
            for (int nt = 0; nt < 13; ++nt) {
                if (nt >= NT0 && nt < NT0 + NTN) {
                    bf16x8 Bf = *(const bf16x8*)(bb + ((nt - NT0) * 16 + a) * 64 + kg * 16);
                    acc[nt] = __builtin_amdgcn_mfma_f32_16x16x32_bf16(Af, Bf, acc[nt], 0, 0, 0);
                }
            }
            __syncthreads();
        }
        const int mbase = mt * 16 + kg * 4;
#pragma unroll
        for (int nt = 0; nt < 13; ++nt) {
            if (nt < NT0 || nt >= NT0 + NTN) continue;
            int col = nt * 16 + a;
#pragma unroll
            for (int j = 0; j < 4; ++j) {
                int row = mbase + j;
                unsigned short h = (col < 196) ? f2bf(acc[nt][j]) : (unsigned short)0;
                tmpb[((size_t)b * 128 + row) * 224 + col] = h;
            }
        }
    } else {
        const int i0 = (bx - 4) * 3;
        for (int idx = tid; idx < 3 * 45; idx += 256) {
            int r = idx / 45, j = idx - r * 45;
            ds[r][j] = d2[((size_t)(b * 45 + i0 + r)) * 45 + j];
        }
        __syncthreads();
        if (tid < 196) {
            float a[3];
#pragma unroll
            for (int r = 0; r < 3; ++r) a[r] = 0.f;
#pragma unroll 4
            for (int j = 0; j < 45; ++j) {
                float v = t1[((size_t)b * 45 + j) * 196 + tid];
#pragma unroll
                for (int r = 0; r < 3; ++r) a[r] += ds[r][j] * v;
            }
#pragma unroll
            for (int r = 0; r < 3; ++r) ts[r][tid] = a[r];
        }
        __syncthreads();
        if (tid < 196) {
            float a[3];
            float bi = gm2b[tid];
#pragma unroll
            for (int r = 0; r < 3; ++r) a[r] = bi;
#pragma unroll 4
            for (int n = 0; n < 196; ++n) {
                float wv = gm2T[(size_t)n * 196 + tid];
#pragma unroll
                for (int r = 0; r < 3; ++r) a[r] += ts[r][n] * wv;
            }
#pragma unroll
            for (int r = 0; r < 3; ++r) {
                size_t rr = ((size_t)(b * 45 + i0 + r)) * 196 + tid;
                t3[rr] = fmaxf(a[r], 0.f) + t1[rr];
            }
        }
    }
}

// ---------------- merged: GCN img out-GEMM (EPI8) || prep3 -----------------
__global__ __launch_bounds__(256, 2) void k_gcnfin(
    const unsigned short* __restrict__ tmpb, const unsigned short* __restrict__ gm1b,
    const float* __restrict__ gm1bias, const float* __restrict__ resid,
    float* __restrict__ outf,
    float4* __restrict__ tqz,
    const float* __restrict__ f1w, const float* __restrict__ f3w,
    unsigned short* __restrict__ wcI,
    const float* __restrict__ f4w, const float* __restrict__ f2w,
    unsigned short* __restrict__ wcT) {
    __shared__ unsigned short xsA[64 * 232];
    __shared__ char bbuf[2][208 * 64];
    const int tid = threadIdx.x;
    int blk = blockIdx.x;
    if (blk < 128) {
        const int b = blk >> 2, bx = blk & 3;
        const int wv = tid >> 6, lane = tid & 63, a = lane & 15, kg = lane >> 4;
        const int nh = bx & 1, mg = bx >> 1;
        const int NT0 = nh * 7, NTN = (nh == 0) ? 7 : 6;
        const unsigned short* Abase = tmpb + (size_t)b * (128 * 224);
        for (int i = tid; i < 64 * 112; i += 256) {
            int r = i / 112, cu = i - r * 112;
            int gr = mg * 64 + r;
            unsigned int v = ((const unsigned int*)(Abase + (size_t)gr * 224))[cu];
            *(unsigned int*)&xsA[r * 232 + cu * 2] = v;
        }
        auto stageB = [&](int kk) {
            char* dst0 = &bbuf[kk & 1][0];
            const int cnt = NTN * 64;
#pragma unroll
            for (int c = 0; c < 4; ++c) {
                int idx = tid + c * 256;
                if (idx < cnt) {
                    int lrow = idx >> 2, u = idx & 3;
                    int grow = NT0 * 16 + lrow;
                    gas_void* src = (gas_void*)((const char*)gm1b + (size_t)grow * 448 +
                                                kk * 64 + u * 16);
                    __builtin_amdgcn_global_load_lds(src,
                        (las_void*)(dst0 + (size_t)idx * 16), 16, 0, 0);
                }
            }
        };
        int mt = mg * 4 + wv;
        const int arow = mt * 16 + a - mg * 64;
        f32x4 acc[13];
#pragma unroll
        for (int nt = 0; nt < 13; ++nt) acc[nt] = (f32x4){0.f, 0.f, 0.f, 0.f};
        stageB(0);
        __syncthreads();
        for (int kk = 0; kk < 7; ++kk) {
            if (kk + 1 < 7) stageB(kk + 1);
            bf16x8 Af = *(const bf16x8*)&xsA[arow * 232 + kk * 32 + kg * 8];
            const char* bb = &bbuf[kk & 1][0];
#pragma unroll
            for (int nt = 0; nt < 13; ++nt) {
                if (nt >= NT0 && nt < NT0 + NTN) {
                    bf16x8 Bf = *(const bf16x8*)(bb + ((nt - NT0) * 16 + a) * 64 + kg * 16);
                    acc[nt] = __builtin_amdgcn_mfma_f32_16x16x32_bf16(Af, Bf, acc[nt], 0, 0, 0);
                }
            }
            __syncthreads();
        }
        const int mbase = mt * 16 + kg * 4;
#pragma unroll
        for (int nt = 0; nt < 13; ++nt) {
            if (nt < NT0 || nt >= NT0 + NTN) continue;
            int col = nt * 16 + a;
            if (col < 196) {
#pragma unroll
                for (int j = 0; j < 4; ++j) {
                    int row = mbase + j;
                    size_t rr = ((size_t)b * 128 + row) * 196 + col;
                    outf[rr] = fmaxf(acc[nt][j] + gm1bias[col], 0.f) + resid[rr];
                }
            }
        }
    } else {
        blk -= 128;
        if (blk < 208) {
            int i = blk * 256 + tid;
            if (i < 53248) tqz[i] = (float4){0.f, 0.f, 0.f, 0.f};
            return;
        }
        blk -= 208;
        if (blk < 364) { d_wcat(f1w, f3w, wcI, blk * 256 + tid); return; }
        blk -= 364;
        d_wcat(f4w, f2w, wcT, blk * 256 + tid);
    }
}

// ---------------- fused attention: scores + softmax + PV (per row-tile) ----
__global__ __launch_bounds__(256, 2) void k_attn(
    const unsigned short* __restrict__ kcatb,
    const unsigned short* __restrict__ V1, const unsigned short* __restrict__ V2,
    unsigned short* __restrict__ Fimg, unsigned short* __restrict__ Ftxt) {
    __shared__ unsigned short xsA[64 * 232];   // scores A; reused as P [64][200]
    __shared__ char bbuf[2][208 * 64];
    const int tid = threadIdx.x;
    const int blk = blockIdx.x;
    const int b = blk / 3, m = blk - b * 3;
    const int isTxt = (m == 2);
    const int mg = isTxt ? 0 : m;
    const int MROWS = isTxt ? 45 : 128;
    const int MTILES = isTxt ? 3 : 8;
    const unsigned short* Abase = kcatb + (size_t)b * (208 * 224) + (isTxt ? 128 * 224 : 0);
    unsigned short* F = isTxt ? Ftxt + (size_t)b * (48 * 448)
                              : Fimg + (size_t)b * (128 * 448);
    const int wv = tid >> 6, lane = tid & 63, a = lane & 15, kg = lane >> 4;

    // stage A rows (clamped) — KPA=224, stride 232
    for (int i = tid; i < 64 * 112; i += 256) {
        int r = i / 112, cu = i - r * 112;
        int gr = mg * 64 + r; if (gr > MROWS - 1) gr = MROWS - 1;
        unsigned int v = ((const unsigned int*)(Abase + (size_t)gr * 224))[cu];
        *(unsigned int*)&xsA[r * 232 + cu * 2] = v;
    }
    const char* Bs = (const char*)(kcatb + (size_t)b * (208 * 224));
    auto stageBs = [&](int kk) {
        char* dst0 = &bbuf[kk & 1][0];
#pragma unroll
        for (int c = 0; c < 4; ++c) {
            int idx = tid + c * 256;
            if (idx < 832) {
                int lrow = idx >> 2, u = idx & 3;
                gas_void* src = (gas_void*)(Bs + (size_t)lrow * 448 + kk * 64 + u * 16);
                __builtin_amdgcn_global_load_lds(src,
                    (las_void*)(dst0 + (size_t)idx * 16), 16, 0, 0);
            }
        }
    };
    int mt = mg * 4 + wv; if (mt > MTILES - 1) mt = MTILES - 1;
    const int arow0 = mt * 16 + a - mg * 64;
    const int mbase = mt * 16 + kg * 4;

    f32x4 acc[13];
#pragma unroll
    for (int nt = 0; nt < 13; ++nt) acc[nt] = (f32x4){0.f, 0.f, 0.f, 0.f};
    stageBs(0);
    __syncthreads();
    for (int kk = 0; kk < 7; ++kk) {
        if (kk + 1 < 7) stageBs(kk + 1);
        bf16x8 Af = *(const bf16x8*)&xsA[arow0 * 232 + kk * 32 + kg * 8];
        const char* bb = &bbuf[kk & 1][0];
#pragma unroll
        for (int nt = 0; nt < 13; ++nt) {
            bf16x8 Bf = *(const bf16x8*)(bb + (nt * 16 + a) * 64 + kg * 16);
            acc[nt] = __builtin_amdgcn_mfma_f32_16x16x32_bf16(Af, Bf, acc[nt], 0, 0, 0);
        }
        __syncthreads();
    }

    // dual softmax -> P bf16 into LDS (stride 200); identical math to EPI5
    unsigned short* xsP = xsA;
#pragma unroll
    for (int j = 0; j < 4; ++j) {
        float mA = -3.4e38f, mB = -3.4e38f;
#pragma unroll
        for (int nt = 0; nt < 8; ++nt) mA = fmaxf(mA, acc[nt][j]);
#pragma unroll
        for (int nt = 8; nt < 13; ++nt) {
            int col = nt * 16 + a;
            float s = (col < 173) ? acc[nt][j] : -3.4e38f;
            mB = fmaxf(mB, s);
        }
        for (int msk = 1; msk < 16; msk <<= 1) {
            mA = fmaxf(mA, __shfl_xor(mA, msk));
            mB = fmaxf(mB, __shfl_xor(mB, msk));
        }
        float eA[8], eB[5];
        float sA = 0.f, sB = 0.f;
#pragma unroll
        for (int nt = 0; nt < 8; ++nt) { eA[nt] = expf(acc[nt][j] - mA); sA += eA[nt]; }
#pragma unroll
        for (int nt = 8; nt < 13; ++nt) {
            int col = nt * 16 + a;
            float v = (col < 173) ? expf(acc[nt][j] - mB) : 0.f;
            eB[nt - 8] = v; sB += v;
        }
        for (int msk = 1; msk < 16; msk <<= 1) {
            sA += __shfl_xor(sA, msk);
            sB += __shfl_xor(sB, msk);
        }
        float iA = 1.f / sA, iB = 1.f / sB;
        int lrow = mbase + j - mg * 64;
#pragma unroll
        for (int nt = 0; nt < 12; ++nt) {
            int col = nt * 16 + a;
            float v = (nt < 8) ? eA[nt] * iA : ((col < 173) ? eB[nt - 8] * iB : 0.f);
            xsP[lrow * 200 + col] = f2bf(v);
        }
    }
    __syncthreads();

    // PV: F = [P_A*V1 | pad | P_B*V2 | pad]
    auto runpv = [&](const unsigned short* Vb, size_t Vbs_, int KPB, int KK,
                     int AOFF, int outoff) {
        f32x4 pacc[13];
#pragma unroll
        for (int nt = 0; nt < 13; ++nt) pacc[nt] = (f32x4){0.f, 0.f, 0.f, 0.f};
        const char* Bbase = (const char*)(Vb + (size_t)b * Vbs_);
        auto stageB = [&](int kk) {
            char* dst0 = &bbuf[kk & 1][0];
#pragma unroll
            for (int c = 0; c < 4; ++c) {
                int idx = tid + c * 256;
                if (idx < 832) {
                    int lrow = idx >> 2, u = idx & 3;
                    gas_void* src = (gas_void*)(Bbase + (size_t)lrow * (KPB * 2) +
                                                kk * 64 + u * 16);
                    __builtin_amdgcn_global_load_lds(src,
                        (las_void*)(dst0 + (size_t)idx * 16), 16, 0, 0);
                }
            }
        };
        stageB(0);
        __syncthreads();
        for (int kk = 0; kk < KK; ++kk) {
            if (kk + 1 < KK) stageB(kk + 1);
            bf16x8 Af = *(const bf16x8*)&xsP[arow0 * 200 + AOFF + kk * 32 + kg * 8];
            const char* bb = &bbuf[kk & 1][0];
#pragma unroll
            for (int nt = 0; nt < 13; ++nt) {
                bf16x8 Bf = *(const bf16x8*)(bb + (nt * 16 + a) * 64 + kg * 16);
                pacc[nt] = __builtin_amdgcn_mfma_f32_16x16x32_bf16(Af, Bf, pacc[nt], 0, 0, 0);
            }
            __syncthreads();
        }
#pragma unroll
        for (int nt = 0; nt < 13; ++nt) {
            int col = nt * 16 + a;
#pragma unroll
            for (int j = 0; j < 4; ++j) {
                int row = mbase + j;
                if (row < MROWS) {
                    unsigned short h = (col < 196) ? f2bf(pacc[nt][j]) : (unsigned short)0;
                    F[(size_t)row * 448 + outoff + col] = h;
                }
            }
        }
        {
            int col = 208 + a;
#pragma unroll
            for (int j = 0; j < 4; ++j) {
                int row = mbase + j;
                if (row < MROWS) F[(size_t)row * 448 + outoff + col] = 0;
            }
        }
    };
    runpv(V1, (size_t)208 * 128, 128, 4, 0, 0);
    runpv(V2, (size_t)208 * 64, 64, 2, 128, 224);
}

// ---------------- unified attention projection GEMM ----------------
struct AG {
    const unsigned short* Ab; unsigned long ABS;
    const unsigned short* Bb; unsigned long BBS;
    const float* biasA; const float* biasB;
    const float* lnres; const float* res2;
    float* feat; unsigned short* ftb; int cbase;
    int MROWS; int MTILES;
};

template <int KPA, int KPB, int KK, int NS>
__global__ __launch_bounds__(256, 2) void k_agemm2(AG pa, AG pc, int split) {
    constexpr int KPS = KPA + 8;
    __shared__ unsigned short xsA[64];
    __shared__ char bbuf[2][208 * 64];
    (void)xsA;
    const AG P = (blockIdx.x < split) ? pa : pc;
    const int bx = (blockIdx.x < split) ? blockIdx.x : blockIdx.x - split;
    const int tid = threadIdx.x, b = blockIdx.y;
    const int wv = tid >> 6, lane = tid & 63, a = lane & 15, kg = lane >> 4;
    const int nh = bx % NS, mg = bx / NS;
    const int NT0 = (NS == 1) ? 0 : nh * 7;
    const int NTN = (NS == 1) ? 13 : ((nh == 0) ? 7 : 6);
    const int MROWS = P.MROWS, MTILES = P.MTILES;
    (void)KPS;

    const unsigned short* Abase = P.Ab + (size_t)b * P.ABS;
    const char* Bbase = (const char*)(P.Bb + (size_t)b * P.BBS);
    auto stageB = [&](int kk) {
        char* dst0 = &bbuf[kk & 1][0];
        const int cnt = NTN * 64;
#pragma unroll
        for (int c = 0; c < 4; ++c) {
            int idx = tid + c * 256;
            if (idx < cnt) {
                int lrow = idx >> 2, u = idx & 3;
                int grow = NT0 * 16 + lrow;
                gas_void* src = (gas_void*)(Bbase + (size_t)grow * (KPB * 2) +
                                            kk * 64 + u * 16);
                __builtin_amdgcn_global_load_lds(src, (las_void*)(dst0 + (size_t)idx * 16),
                                                 16, 0, 0);
            }
        }
    };

    int mt = mg * 4 + wv; if (mt > MTILES - 1) mt = MTILES - 1;

    f32x4 acc[13];
#pragma unroll
    for (int nt = 0; nt < 13; ++nt) acc[nt] = (f32x4){0.f, 0.f, 0.f, 0.f};

    stageB(0);
    __syncthreads();
    for (int kk = 0; kk < KK; ++kk) {
        if (kk + 1 < KK) stageB(kk + 1);
        int gr = mt * 16 + a; if (gr > MROWS - 1) gr = MROWS - 1;
        bf16x8 Af = *(const bf16x8*)(Abase + (size_t)gr * KPA + kk * 32 + kg * 8);
        const char* bb = &bbuf[kk & 1][0];
#pragma unroll
        for (int nt = 0; nt < 13; ++nt) {
            if (nt >= NT0 && nt < NT0 + NTN) {
                bf16x8 Bf = *(const bf16x8*)(bb + ((nt - NT0) * 16 + a) * 64 + kg * 16);
                acc[nt] = __builtin_amdgcn_mfma_f32_16x16x32_bf16(Af, Bf, acc[nt], 0, 0, 0);
            }
        }
        __syncthreads();
    }

    const int mbase = mt * 16 + kg * 4;
#pragma unroll
    for (int nt = 0; nt < 13; ++nt) {
        if (nt < NT0 || nt >= NT0 + NTN) continue;
        int col = nt * 16 + a;
        if (col < 196) {
#pragma unroll
            for (int j = 0; j < 4; ++j) {
                int row = mbase + j;
                if (row < MROWS) {
                    size_t rr = ((size_t)b * MROWS + row) * 196 + col;
                    float v = acc[nt][j] + P.biasA[col] + P.biasB[col] +
                              P.lnres[rr] + P.res2[rr];
                    P.feat[((size_t)b * 173 + P.cbase + row) * 196 + col] = v;
                    P.ftb[((size_t)(b * 208 + col)) * 192 + P.cbase + row] = f2bf(v);
                }
            }
        }
    }
}

// ---------------- LN + projection body + merged kernel ----------------
template <int R, int ROWS, int KOFF, int TS>
__device__ __forceinline__ void d_lnlin(const float* __restrict__ x,
                                        const float* __restrict__ g,
                                        const float* __restrict__ be,
                                        const float* __restrict__ eT,
                                        const float* __restrict__ eb,
                                        float* __restrict__ lnout,
                                        unsigned short* __restrict__ kcat,
                                        unsigned short* __restrict__ tbuf,
                                        int bx, int b) {
    __shared__ float ls[ROWS][196];
    const int i0 = bx * ROWS;
    const int tid = threadIdx.x;
    const int wv = tid >> 6, lane = tid & 63;
    for (int idx = tid; idx < ROWS * 196; idx += 256) {
        int r = idx / 196, n = idx - r * 196;
        ls[r][n] = x[((size_t)(b * R + i0 + r)) * 196 + n];
    }
    __syncthreads();
    for (int k = 0;; ++k) {
        int r = wv + 4 * k;
        if (r >= ROWS) break;
        float s = 0.f, s2 = 0.f;
        for (int j = lane; j < 196; j += 64) { float v = ls[r][j]; s += v; s2 += v * v; }
        for (int sh = 32; sh; sh >>= 1) { s += __shfl_xor(s, sh); s2 += __shfl_xor(s2, sh); }
        float mean = s / 196.f;
        float var = s2 / 196.f - mean * mean;
        float rstd = rsqrtf(var + 1e-6f);
        size_t rowo = ((size_t)(b * R + i0 + r)) * 196;
        for (int j = lane; j < 196; j += 64) {
            float l = (ls[r][j] - mean) * rstd * g[j] + be[j];
            ls[r][j] = l;
            lnout[rowo + j] = l;
        }
    }
    __syncthreads();
    if (tid < 224) {
        float a[ROWS];
        if (tid < 196) {
            float bi = eb[tid];
#pragma unroll
            for (int r = 0; r < ROWS; ++r) a[r] = bi;
#pragma unroll 4
            for (int n = 0; n < 196; ++n) {
                float ev = eT[(size_t)n * 196 + tid];
#pragma unroll
                for (int r = 0; r < ROWS; ++r) a[r] += ls[r][n] * ev;
            }
        }
#pragma unroll
        for (int r = 0; r < ROWS; ++r) {
            unsigned short h = 0;
            if (tid < 196) h = f2bf(fmaxf(a[r], 0.f));
            kcat[((size_t)(b * 208 + KOFF + i0 + r)) * 224 + tid] = h;
            if (tid < 196) tbuf[((size_t)(b * 208 + tid)) * TS + (i0 + r)] = h;
        }
    }
}

__global__ void k_lnlin_both(const float* __restrict__ ximg, const float* __restrict__ g1,
                             const float* __restrict__ b1, const float* __restrict__ e1T,
                             const float* __restrict__ e1b, float* __restrict__ ln1out,
                             const float* __restrict__ xtxt, const float* __restrict__ g2,
                             const float* __restrict__ b2, const float* __restrict__ e2T,
                             const float* __restrict__ e2b, float* __restrict__ ln2out,
                             unsigned short* __restrict__ kcat,
                             unsigned short* __restrict__ iqT,
                             unsigned short* __restrict__ tqT) {
    int blk = blockIdx.x;
    if (blk < 1024)
        d_lnlin<128, 4, 0, 128>(ximg, g1, b1, e1T, e1b, ln1out, kcat, iqT,
                                blk & 31, blk >> 5);
    else {
        int r = blk - 1024;
        d_lnlin<45, 3, 128, 64>(xtxt, g2, b2, e2T, e2b, ln2out, kcat, tqT,
                                r % 15, r / 15);
    }
}

// ---------------- final classifier (rowsum fused) ----------------
__global__ void k_finale(const float* __restrict__ toh, const float* __restrict__ tnm,
                         const float* __restrict__ cms, const float* __restrict__ cls_w,
                         const float* __restrict__ cls_b, float* __restrict__ out) {
    int b = blockIdx.x;
    __shared__ float pcm[173];
    __shared__ float r1[4], r2[4];
    int tid = threadIdx.x;
    float a = (tid < 196) ? toh[b * 196 + tid] : 0.f;
    float c = (tid < 196) ? tnm[b * 196 + tid] : 0.f;
    for (int sh = 32; sh; sh >>= 1) { a += __shfl_xor(a, sh); c += __shfl_xor(c, sh); }
    if ((tid & 63) == 0) { r1[tid >> 6] = a; r2[tid >> 6] = c; }
    if (tid < 173) {
        float s = 0.f;
        const float* p = &cms[((size_t)b * 173 + tid) * 196];
        for (int n = 0; n < 196; ++n) s += p[n];
        pcm[tid] = s;
    }
    __syncthreads();
    if (tid < 2) {
        float soh = r1[0] + r1[1] + r1[2] + r1[3];
        float snm = r2[0] + r2[1] + r2[2] + r2[3];
        const float* wrow = &cls_w[tid * 218];
        float acc = cls_b[tid];
        float w1 = 0.f, w2 = 0.f;
        for (int k = 0; k < 30; ++k) w1 += wrow[k];
        for (int k = 30; k < 45; ++k) w2 += wrow[k];
        acc += soh * w1 + snm * w2;
        for (int k = 0; k < 173; ++k) acc += wrow[45 + k] * pcm[k];
        out[b * 2 + tid] = acc;
    }
}

// ---------------------------------------------------------------------------
extern "C" void kernel_launch(void* const* d_in, const int* in_sizes, int n_in,
                              void* d_out, int out_size, void* d_ws, size_t ws_size,
                              hipStream_t stream) {
    const float* x      = (const float*)d_in[0];
    const float* oneHot = (const float*)d_in[1];
    const float* num    = (const float*)d_in[2];
    const float* c1_w1  = (const float*)d_in[3];
    const float* c1_g1  = (const float*)d_in[5];
    const float* c1_be1 = (const float*)d_in[6];
    const float* c1_w2  = (const float*)d_in[7];
    const float* c1_g2  = (const float*)d_in[9];
    const float* c1_be2 = (const float*)d_in[10];
    const float* oh_w   = (const float*)d_in[11];
    const float* oh_b   = (const float*)d_in[12];
    const float* oh_g   = (const float*)d_in[13];
    const float* oh_be  = (const float*)d_in[14];
    const float* nm_w   = (const float*)d_in[15];
    const float* nm_b   = (const float*)d_in[16];
    const float* nm_g   = (const float*)d_in[17];
    const float* nm_be  = (const float*)d_in[18];
    const float* gm1_w  = (const float*)d_in[19];
    const float* gm1_b  = (const float*)d_in[20];
    const float* gm2_w  = (const float*)d_in[21];
    const float* gm2_b  = (const float*)d_in[22];
    const float* ln1_g  = (const float*)d_in[23];
    const float* ln1_b  = (const float*)d_in[24];
    const float* ln2_g  = (const float*)d_in[25];
    const float* ln2_b  = (const float*)d_in[26];
    const float* e1_w   = (const float*)d_in[27];
    const float* e1_b   = (const float*)d_in[28];
    const float* e2_w   = (const float*)d_in[29];
    const float* e2_b   = (const float*)d_in[30];
    const float* f1_w   = (const float*)d_in[31];
    const float* f1_b   = (const float*)d_in[32];
    const float* f2_w   = (const float*)d_in[33];
    const float* f2_b   = (const float*)d_in[34];
    const float* f3_w   = (const float*)d_in[35];
    const float* f3_b   = (const float*)d_in[36];
    const float* f4_w   = (const float*)d_in[37];
    const float* f4_b   = (const float*)d_in[38];
    const float* cm_w   = (const float*)d_in[39];
    const float* cm_b   = (const float*)d_in[40];
    const float* cmf_w  = (const float*)d_in[41];
    const float* cmf_b  = (const float*)d_in[42];
    const float* cls_w  = (const float*)d_in[43];
    const float* cls_b  = (const float*)d_in[44];
    float* out = (float*)d_out;
    float* W = (float*)d_ws;

    const size_t L = 802816;
    const size_t T = 282240;
    const size_t F3 = 1085056;
    // ---- layout identical to r18-r20 ----
    const size_t o_A    = 0;
    const size_t o_B    = L;
    const size_t o_C    = 2 * L;
    const size_t o_Kcat = 3 * L;
    const size_t o_iqT  = o_Kcat + 745472;
    const size_t o_t1   = 4 * L + T;
    const size_t o_t3   = 4 * L + 2 * T;
    const size_t o_ln2  = 4 * L + 3 * T;
    const size_t o_toh  = 4 * L + 4 * T;
    const size_t o_tnm  = o_toh + 6272;
    const size_t o_st   = o_tnm + 6272;
    const size_t o_wT   = o_st + 1024;
    const size_t o_feat = o_wT + 8 * 38416;
    const size_t o_q    = o_feat + F3;
    const size_t o_Fimg = o_q;
    const size_t o_dd   = o_q + F3;
    const size_t o_db   = o_dd;
    const size_t o_d2   = o_dd + 524288;
    const size_t o_gm1b = o_dd + 589088;
    const size_t o_fTb  = o_dd + 612384;
    const size_t o_tqT  = o_dd;
    const size_t o_wcI  = o_dd + 212992;
    const size_t o_wcT  = o_wcI + 46592;
    const size_t o_pbf  = o_dd;
    const size_t o_qbf  = o_dd + 745472;
    const size_t o_Ftxt = o_qbf;
    const size_t o_wcm  = o_qbf + 630784;
    const size_t o_wcmf = o_wcm + 16896;
    const size_t o_ftb  = o_wcmf + 16896;
    const size_t o_tr   = o_ftb + 638976;
    const size_t o_qtb  = o_tr;
    const size_t o_ps   = 10158208;
    const size_t o_xt1 = o_dd;
    const size_t o_xt2 = o_xt1 + 1198080;
    const size_t o_wp1 = o_xt2 + 479232;
    const size_t o_wp2 = o_wp1 + 552960;

    float* part = W + 3 * L;
    unsigned short* xt1 = (unsigned short*)(W + o_xt1);
    unsigned short* xt2 = (unsigned short*)(W + o_xt2);
    unsigned short* wp1 = (unsigned short*)(W + o_wp1);
    unsigned short* wp2 = (unsigned short*)(W + o_wp2);
    unsigned short* kcatb = (unsigned short*)(W + o_Kcat);
    unsigned short* iqTb = (unsigned short*)(W + o_iqT);
    unsigned short* tqTb = (unsigned short*)(W + o_tqT);
    unsigned short* wcatI = (unsigned short*)(W + o_wcI);
    unsigned short* wcatT = (unsigned short*)(W + o_wcT);
    unsigned short* Fimg = (unsigned short*)(W + o_Fimg);
    unsigned short* Ftxt = (unsigned short*)(W + o_Ftxt);
    unsigned short* ftb = (unsigned short*)(W + o_ftb);
    unsigned short* qtb = (unsigned short*)(W + o_qtb);
    unsigned short* feab = (unsigned short*)(W + o_qtb + 638976);
    unsigned short* qbf = (unsigned short*)(W + o_qbf);
    unsigned short* wcmb = (unsigned short*)(W + o_wcm);
    unsigned short* wcmfb = (unsigned short*)(W + o_wcmf);
    unsigned short* pbf = (unsigned short*)(W + o_pbf);
    unsigned short* distb = (unsigned short*)(W + o_db);
    unsigned short* gm1b = (unsigned short*)(W + o_gm1b);
    unsigned short* fTb = (unsigned short*)(W + o_fTb);
    unsigned short* tmpb = (unsigned short*)(W + o_A);
    float* gm2T = W + o_wT + 0 * 38416;
    float* e1T  = W + o_wT + 1 * 38416;
    float* e2T  = W + o_wT + 2 * 38416;

    // 1: conv prep
    k_prep1<<<5460, 256, 0, stream>>>(c1_w1, wp1, c1_w2, wp2, x, xt1);

    // 2-4: conv1 + reduce/stats + BN
    k_convchunk4<320, 5, 4, 2><<<dim3(20, 32), 256, 0, stream>>>(xt1, wp1, part);
    k_reduce_stats<5, 128><<<dim3(128, 32), 256, 0, stream>>>(part, W + o_A, W + o_ps);
    k_bn_apply2<<<4096, 256, 0, stream>>>(W + o_A, W + o_ps, c1_g1, c1_be1,
                                          nullptr, nullptr, xt2, 128);

    // 5-7: conv2 + reduce/stats + BN
    k_convchunk4<128, 2, 2, 4><<<dim3(16, 32), 256, 0, stream>>>(xt2, wp2, part);
    k_reduce_stats<2, 128><<<dim3(128, 32), 256, 0, stream>>>(part, W + o_B,
                                                              W + o_ps + 8192);
    k_bn_apply2<<<4096, 256, 0, stream>>>(W + o_B, W + o_ps + 8192, c1_g2, c1_be2,
                                          W + o_tr, fTb, nullptr, 128);

    // 8: post-conv packs + catnum/text emission
    k_prep2<<<1756, 256, 0, stream>>>(cm_w, wcmb, cmf_w, wcmfb, gm1_w, gm1b,
                                      (float4*)(W + o_ftb), gm2_w, e1_w, e2_w, W + o_wT,
                                      oneHot, num, oh_w, oh_b, oh_g, oh_be,
                                      nm_w, nm_b, nm_g, nm_be,
                                      W + o_toh, W + o_tnm, W + o_t1, W + o_tr + L);

    // 9: merged GCN dists
    k_dist_both<<<1504, 256, 0, stream>>>(W + o_B, W + o_tr, distb,
                                          W + o_t1, W + o_tr + L, W + o_d2);

    // 10: GCN img tmp-GEMM || GCN txt spmmfin
    k_gcnpair<<<dim3(19, 32), 256, 0, stream>>>(distb, fTb, tmpb,
                                                W + o_d2, W + o_t1, gm2T, gm2_b,
                                                W + o_t3);

    // 11: GCN img out-GEMM || tqT zero + Wcat packs
    k_gcnfin<<<1064, 256, 0, stream>>>(tmpb, gm1b, gm1_b, W + o_B, W + o_C,
                                       (float4*)(W + o_tqT), f1_w, f3_w, wcatI,
                                       f4_w, f2_w, wcatT);

    // 12: merged LN + q projections
    k_lnlin_both<<<1504, 256, 0, stream>>>(W + o_C, ln1_g, ln1_b, e1T, e1_b, W + o_B,
                                           W + o_t3, ln2_g, ln2_b, e2T, e2_b, W + o_ln2,
                                           kcatb, iqTb, tqTb);

    // 13: fused attention (scores + dual softmax + PV, img + txt)
    k_attn<<<96, 256, 0, stream>>>(kcatb, iqTb, tqTb, Fimg, Ftxt);

    // 14: projection + residuals (img + txt unified)
    {
        AG a{}, c{};
        a.Ab = Fimg; a.ABS = (unsigned long)128 * 448; a.Bb = wcatI; a.BBS = 0;
        a.biasA = f1_b; a.biasB = f3_b; a.lnres = W + o_B; a.res2 = W + o_C;
        a.feat = W + o_feat; a.ftb = ftb; a.cbase = 0; a.MROWS = 128; a.MTILES = 8;
        c = a;
        c.Ab = Ftxt; c.ABS = (unsigned long)48 * 448; c.Bb = wcatT;
        c.biasA = f2_b; c.biasB = f4_b; c.lnres = W + o_ln2; c.res2 = W + o_t3;
        c.cbase = 128; c.MROWS = 45; c.MTILES = 3;
        k_agemm2<448, 448, 14, 2><<<dim3(6, 32), 256, 0, stream>>>(a, c, 4);
    }

    // 15: CMSA zeros
    k_prep4<<<2592, 256, 0, stream>>>((float4*)(W + o_pbf), (float4*)(W + o_qtb));

    // 16-19: CMSA GEMMs
    k_bgemm<176, 11, 192, 6, 0, 2><<<dim3(6, 32), 256, 0, stream>>>(
        wcmb, 0, ftb, (size_t)208 * 192, cm_b, qbf, qtb, nullptr, nullptr);
    k_bgemm<208, 13, 192, 6, 1, 1><<<dim3(4, 32), 256, 0, stream>>>(
        qtb, (size_t)208 * 192, qtb, (size_t)208 * 192, nullptr, pbf, nullptr,
        nullptr, nullptr);
    k_bgemm<176, 11, 224, 7, 2, 2><<<dim3(6, 32), 256, 0, stream>>>(
        qbf, (size_t)176 * 224, pbf, (size_t)208 * 224, nullptr, feab, nullptr,
        nullptr, nullptr);
    k_bgemm<176, 11, 192, 6, 3, 2><<<dim3(6, 32), 256, 0, stream>>>(
        wcmfb, 0, feab, (size_t)208 * 192, cmf_b, nullptr, nullptr,
        W + o_feat, W + o_q);

    // 20: final classifier
    k_finale<<<32, 256, 0, stream>>>(W + o_toh, W + o_tnm, W + o_q, cls_w, cls_b, out);
}